// Round 9
// baseline (336.328 us; speedup 1.0000x reference)
//
#include <hip/hip_runtime.h>

typedef unsigned short u16;
typedef unsigned int   u32;
typedef __attribute__((ext_vector_type(8)))  short short8;
typedef __attribute__((ext_vector_type(4)))  float f32x4v;

#define DEVI __device__ __forceinline__

constexpr int   Bb = 32, Nn = 4096, Dd = 256, Kk = 8, SDd = 64, HDd = 128;
constexpr float EPSc = 1e-8f, LNEPS = 1e-5f, SCALEc = 0.125f;  // SD^-0.5

DEVI u16 f2b(float f) {            // f32 -> bf16 RNE
  u32 u = __builtin_bit_cast(u32, f);
  return (u16)((u + 0x7fffu + ((u >> 16) & 1u)) >> 16);
}
DEVI float b2f(u16 s) { return __builtin_bit_cast(float, ((u32)s) << 16); }
DEVI float sigmoidf_(float x) { return 1.f / (1.f + __expf(-x)); }

DEVI void gll16(const void* g, void* l) {   // async 16B/lane global->LDS
  __builtin_amdgcn_global_load_lds(
      (const __attribute__((address_space(1))) u32*)g,
      (__attribute__((address_space(3))) u32*)l, 16, 0, 0);
}

DEVI float dot64(const float* __restrict__ a, const float* __restrict__ w) {
  float s = 0.f;
  #pragma unroll
  for (int i = 0; i < 16; ++i) {
    float4 av = *(const float4*)(a + i * 4);
    float4 wv = *(const float4*)(w + i * 4);
    s += av.x * wv.x + av.y * wv.y + av.z * wv.z + av.w * wv.w;
  }
  return s;
}
// dot of 64 f32 (LDS) with bf16 LDS row j of a 64-col XOR-swizzled image
DEVI float dotL64(const float* __restrict__ x, const u16* __restrict__ wl, int j) {
  float s = 0.f;
  #pragma unroll
  for (int i = 0; i < 8; ++i) {
    short8 wv8 = *(const short8*)((const char*)wl + ((j * 128 + 16 * i) ^ ((j & 7) << 4)));
    #pragma unroll
    for (int e = 0; e < 8; ++e) s += x[i * 8 + e] * b2f((u16)wv8[e]);
  }
  return s;
}
// dot of 128 f32 (LDS) with bf16 LDS row j of a 128-col XOR-swizzled image
DEVI float dotL128(const float* __restrict__ x, const u16* __restrict__ wl, int j) {
  float s = 0.f;
  #pragma unroll
  for (int i = 0; i < 16; ++i) {
    short8 wv8 = *(const short8*)((const char*)wl + ((j * 256 + 16 * i) ^ ((j & 7) << 4)));
    #pragma unroll
    for (int e = 0; e < 8; ++e) s += x[i * 8 + e] * b2f((u16)wv8[e]);
  }
  return s;
}

// LayerNorm of 8 rows x 64 cols living in LDS (256 threads).
DEVI void ln8(const float* src, float* dst, const float* __restrict__ g,
              const float* __restrict__ b, int t) {
  int l = t & 63, w = t >> 6;
  int r = w * 2 + (l >> 5), c = l & 31;
  float x0 = src[r * 64 + c], x1 = src[r * 64 + c + 32];
  float s = x0 + x1, q2 = x0 * x0 + x1 * x1;
  #pragma unroll
  for (int m = 1; m < 32; m <<= 1) { s += __shfl_xor(s, m); q2 += __shfl_xor(q2, m); }
  float mean = s * (1.f / 64.f);
  float rs = rsqrtf(q2 * (1.f / 64.f) - mean * mean + LNEPS);
  dst[r * 64 + c]      = (x0 - mean) * rs * g[c]      + b[c];
  dst[r * 64 + c + 32] = (x1 - mean) * rs * g[c + 32] + b[c + 32];
}

// ---------------------------------------------------------------------------
// K0: blocks 0..271: ALL weights -> bf16 XOR-swizzled images.
//     blocks 272..303: initial slots -> LN -> q into q_ws.
// ---------------------------------------------------------------------------
__global__ __launch_bounds__(256) void k_prep(
    const float* __restrict__ Wp, const float* __restrict__ Wk,
    const float* __restrict__ Wv, const float* __restrict__ W_ih,
    const float* __restrict__ W_hh, const float* __restrict__ W1,
    const float* __restrict__ W2, const float* __restrict__ Wq,
    u16* __restrict__ wp_sw, u16* __restrict__ wk_sw, u16* __restrict__ wv_sw,
    u16* __restrict__ wupd_sw,
    const float* __restrict__ noise, const float* __restrict__ mu,
    const float* __restrict__ ls, const float* __restrict__ gs,
    const float* __restrict__ bs, float* __restrict__ q_ws) {
  const int t = threadIdx.x;
  if (blockIdx.x < 272) {
    int i = blockIdx.x * 256 + t;
    if (i < 16384) {
      wp_sw[i ^ (((i >> 8) & 7) << 3)] = f2b(Wp[i]);
    } else if (i < 20480) {
      int j = i - 16384; wk_sw[j ^ (((j >> 6) & 7) << 3)] = f2b(Wk[j]);
    } else if (i < 24576) {
      int j = i - 20480; wv_sw[j ^ (((j >> 6) & 7) << 3)] = f2b(Wv[j]);
    } else if (i < 36864) {
      int j = i - 24576; wupd_sw[j ^ (((j >> 6) & 7) << 3)] = f2b(W_ih[j]);
    } else if (i < 49152) {
      int j = i - 36864; wupd_sw[12288 + (j ^ (((j >> 6) & 7) << 3))] = f2b(W_hh[j]);
    } else if (i < 57344) {
      int j = i - 49152; wupd_sw[24576 + (j ^ (((j >> 6) & 7) << 3))] = f2b(W1[j]);
    } else if (i < 65536) {
      int j = i - 57344; wupd_sw[32768 + (j ^ (((j >> 7) & 7) << 3))] = f2b(W2[j]);
    } else if (i < 69632) {
      int j = i - 65536; wupd_sw[40960 + (j ^ (((j >> 6) & 7) << 3))] = f2b(Wq[j]);
    }
    return;
  }
  const int b = blockIdx.x - 272;
  __shared__ float sl[512], snl[512];
  for (int i = t; i < 512; i += 256) {
    int d = i & 63;
    sl[i] = mu[d] + __expf(ls[d]) * noise[b * 512 + i];
  }
  __syncthreads();
  ln8(sl, snl, gs, bs, t);
  __syncthreads();
  for (int i = t; i < 512; i += 256)
    q_ws[b * 512 + i] = SCALEc * dot64(snl + (i >> 6) * 64, Wq + (i & 63) * 64);
}

// ---------------------------------------------------------------------------
// K1 (proj v4): LN(256)->proj->LN(64)->k,v. Grid 512, 256 thr.
// Weights staged ONCE to LDS via gll16 (B-frags = conflict-floor ds_read);
// 4 sequential 64-row tiles per block; zero barriers after staging
// (xn region is per-wave). k img: per-128-row swizzle tiles; v linear.
// ---------------------------------------------------------------------------
__global__ void k_proj_kv(
    const float* __restrict__ in, const float* __restrict__ gpro,
    const float* __restrict__ bpro, const u16* __restrict__ wp_sw,
    const float* __restrict__ bproj, const float* __restrict__ gin,
    const float* __restrict__ bin, const u16* __restrict__ wk_sw,
    const u16* __restrict__ wv_sw, u16* __restrict__ k_ws,
    u16* __restrict__ v_ws) {
  __shared__ __align__(16) u16 wp_lds[64 * 256];    // 32KB
  __shared__ __align__(16) u16 wk_lds[64 * 64];     // 8KB
  __shared__ __align__(16) u16 wv_lds[64 * 64];     // 8KB
  __shared__ __align__(16) u16 xn_lds[64 * 64];     // 8KB
  __shared__ float gp_l[256], bp_l[256];

  const int t = threadIdx.x, l = t & 63, w = t >> 6;
  const int r16 = l & 15, q4 = l >> 4;

  {  // one-time weight staging
    #pragma unroll
    for (int i = 0; i < 8; ++i) {
      int off = w * 8192 + i * 1024 + l * 16;
      gll16((const char*)wp_sw + off, (char*)wp_lds + off);
    }
    #pragma unroll
    for (int i = 0; i < 2; ++i) {
      int off = w * 2048 + i * 1024 + l * 16;
      gll16((const char*)wk_sw + off, (char*)wk_lds + off);
      gll16((const char*)wv_sw + off, (char*)wv_lds + off);
    }
  }
  gp_l[t] = gpro[t];
  bp_l[t] = bpro[t];

  float bj4[4], gn4[4], bn4[4];
  #pragma unroll
  for (int nt = 0; nt < 4; ++nt) {
    int col = nt * 16 + r16;
    bj4[nt] = bproj[col]; gn4[nt] = gin[col]; bn4[nt] = bin[col];
  }
  __syncthreads();   // staging + smalls complete (only barrier)

  #pragma unroll 1
  for (int tt = 0; tt < 4; ++tt) {
    const long rowbase = (long)blockIdx.x * 256 + tt * 64 + w * 16;
    const float* rp = in + (rowbase + r16) * 256;

    float4 x0[8], x1[8];
    #pragma unroll
    for (int ks = 0; ks < 8; ++ks) {
      x0[ks] = *(const float4*)(rp + ks * 32 + q4 * 8);
      x1[ks] = *(const float4*)(rp + ks * 32 + q4 * 8 + 4);
    }
    float sum = 0.f, sq = 0.f;
    #pragma unroll
    for (int ks = 0; ks < 8; ++ks) {
      sum += x0[ks].x + x0[ks].y + x0[ks].z + x0[ks].w +
             x1[ks].x + x1[ks].y + x1[ks].z + x1[ks].w;
      sq += x0[ks].x * x0[ks].x + x0[ks].y * x0[ks].y + x0[ks].z * x0[ks].z +
            x0[ks].w * x0[ks].w + x1[ks].x * x1[ks].x + x1[ks].y * x1[ks].y +
            x1[ks].z * x1[ks].z + x1[ks].w * x1[ks].w;
    }
    sum += __shfl_xor(sum, 16); sum += __shfl_xor(sum, 32);
    sq  += __shfl_xor(sq, 16);  sq  += __shfl_xor(sq, 32);
    float mean = sum * (1.f / 256.f);
    float rs = rsqrtf(sq * (1.f / 256.f) - mean * mean + LNEPS);

    short8 a[8];
    #pragma unroll
    for (int ks = 0; ks < 8; ++ks) {
      int kb = ks * 32 + q4 * 8;
      a[ks][0] = (short)f2b((x0[ks].x - mean) * rs * gp_l[kb + 0] + bp_l[kb + 0]);
      a[ks][1] = (short)f2b((x0[ks].y - mean) * rs * gp_l[kb + 1] + bp_l[kb + 1]);
      a[ks][2] = (short)f2b((x0[ks].z - mean) * rs * gp_l[kb + 2] + bp_l[kb + 2]);
      a[ks][3] = (short)f2b((x0[ks].w - mean) * rs * gp_l[kb + 3] + bp_l[kb + 3]);
      a[ks][4] = (short)f2b((x1[ks].x - mean) * rs * gp_l[kb + 4] + bp_l[kb + 4]);
      a[ks][5] = (short)f2b((x1[ks].y - mean) * rs * gp_l[kb + 5] + bp_l[kb + 5]);
      a[ks][6] = (short)f2b((x1[ks].z - mean) * rs * gp_l[kb + 6] + bp_l[kb + 6]);
      a[ks][7] = (short)f2b((x1[ks].w - mean) * rs * gp_l[kb + 7] + bp_l[kb + 7]);
    }

    f32x4v acc[4];
    #pragma unroll
    for (int nt = 0; nt < 4; ++nt)
      #pragma unroll
      for (int i = 0; i < 4; ++i) acc[nt][i] = 0.f;
    #pragma unroll
    for (int ks = 0; ks < 8; ++ks) {
      #pragma unroll
      for (int nt = 0; nt < 4; ++nt) {
        int n = nt * 16 + r16;
        short8 bf = *(const short8*)((const char*)wp_lds +
                     ((n * 512 + 64 * ks + 16 * q4) ^ ((n & 7) << 4)));
        acc[nt] = __builtin_amdgcn_mfma_f32_16x16x32_bf16(a[ks], bf, acc[nt], 0, 0, 0);
      }
    }
    #pragma unroll
    for (int nt = 0; nt < 4; ++nt)
      #pragma unroll
      for (int reg = 0; reg < 4; ++reg) acc[nt][reg] += bj4[nt];

    #pragma unroll
    for (int reg = 0; reg < 4; ++reg) {
      float s = acc[0][reg] + acc[1][reg] + acc[2][reg] + acc[3][reg];
      float q2 = acc[0][reg] * acc[0][reg] + acc[1][reg] * acc[1][reg] +
                 acc[2][reg] * acc[2][reg] + acc[3][reg] * acc[3][reg];
      #pragma unroll
      for (int m = 1; m < 16; m <<= 1) { s += __shfl_xor(s, m); q2 += __shfl_xor(q2, m); }
      float mn = s * (1.f / 64.f);
      float rr = rsqrtf(q2 * (1.f / 64.f) - mn * mn + LNEPS);
      int row = q4 * 4 + reg;
      int rowg = w * 16 + row;
      #pragma unroll
      for (int nt = 0; nt < 4; ++nt) {
        int col = nt * 16 + r16;
        float y = (acc[nt][reg] - mn) * rr * gn4[nt] + bn4[nt];
        int byte = (rowg * 128 + 2 * col) ^ ((row & 7) << 4);
        *(u16*)((char*)xn_lds + byte) = f2b(y);
      }
    }

    f32x4v kacc[4], vacc[4];
    #pragma unroll
    for (int nt = 0; nt < 4; ++nt)
      #pragma unroll
      for (int i = 0; i < 4; ++i) { kacc[nt][i] = 0.f; vacc[nt][i] = 0.f; }
    #pragma unroll
    for (int ks = 0; ks < 2; ++ks) {
      int rowg2 = w * 16 + r16;
      short8 af = *(const short8*)((const char*)xn_lds +
                   ((rowg2 * 128 + 64 * ks + 16 * q4) ^ ((r16 & 7) << 4)));
      #pragma unroll
      for (int nt = 0; nt < 4; ++nt) {
        int n = nt * 16 + r16;
        int wb = (n * 128 + 64 * ks + 16 * q4) ^ ((n & 7) << 4);
        short8 bk = *(const short8*)((const char*)wk_lds + wb);
        short8 bv = *(const short8*)((const char*)wv_lds + wb);
        kacc[nt] = __builtin_amdgcn_mfma_f32_16x16x32_bf16(af, bk, kacc[nt], 0, 0, 0);
        vacc[nt] = __builtin_amdgcn_mfma_f32_16x16x32_bf16(af, bv, vacc[nt], 0, 0, 0);
      }
    }
    #pragma unroll
    for (int nt = 0; nt < 4; ++nt) {
      #pragma unroll
      for (int reg = 0; reg < 4; ++reg) {
        int row = q4 * 4 + reg;
        long gr = rowbase + row;
        int col = nt * 16 + r16;
        long tile = gr >> 7;               // k: per-128-row swizzle image
        int  r    = (int)(gr & 127);
        long ko = tile * 8192 + ((r * 64 + col) ^ ((r & 7) << 3));
        k_ws[ko] = f2b(kacc[nt][reg]);
        v_ws[gr * 64 + col] = f2b(vacc[nt][reg]);
      }
    }
  }
}

// ---------------------------------------------------------------------------
// K2: pure attention stream. grid (32,32), 128 thr. (unchanged from R8)
// ---------------------------------------------------------------------------
__global__ __launch_bounds__(128) void k_attn(
    const float* __restrict__ q_ws, const u16* __restrict__ k_img,
    const u16* __restrict__ v_ws, float* __restrict__ S_part,
    float* __restrict__ U_part) {
  const int bx = blockIdx.x, by = blockIdx.y, t = threadIdx.x;
  const int l = t & 63, w = t >> 6;
  __shared__ __align__(16) u16 k_l[8192];        // 16KB swizzle tile
  __shared__ float ql[512];
  __shared__ __align__(16) float attn_l[1024];   // reused as ured
  __shared__ float sred[16];

  {
    const char* gsrc = (const char*)(k_img + ((long)(by * 32 + bx)) * 8192);
    #pragma unroll
    for (int i = 0; i < 8; ++i) {
      int off = i * 2048 + t * 16;
      gll16(gsrc + off, (char*)k_l + off);
    }
  }
  for (int i = t; i < 512; i += 128) ql[i] = q_ws[by * 512 + i];
  __syncthreads();

  short8 kw8[8];
  #pragma unroll
  for (int j = 0; j < 8; ++j)
    kw8[j] = *(const short8*)((const char*)k_l + ((t * 128 + 16 * j) ^ ((t & 7) << 4)));
  float lg[8];
  #pragma unroll
  for (int i = 0; i < 8; ++i) lg[i] = 0.f;
  #pragma unroll
  for (int c4 = 0; c4 < 16; ++c4) {
    int j = c4 >> 1, e0 = (c4 & 1) * 4;
    float f0 = b2f((u16)kw8[j][e0]);
    float f1 = b2f((u16)kw8[j][e0 + 1]);
    float f2v = b2f((u16)kw8[j][e0 + 2]);
    float f3 = b2f((u16)kw8[j][e0 + 3]);
    #pragma unroll
    for (int kk = 0; kk < 8; ++kk) {
      float4 qv = *(const float4*)(ql + kk * 64 + c4 * 4);
      lg[kk] += qv.x * f0 + qv.y * f1 + qv.z * f2v + qv.w * f3;
    }
  }
  float mx = lg[0];
  #pragma unroll
  for (int kk = 1; kk < 8; ++kk) mx = fmaxf(mx, lg[kk]);
  float e[8], ss = 0.f;
  #pragma unroll
  for (int kk = 0; kk < 8; ++kk) { e[kk] = __expf(lg[kk] - mx); ss += e[kk]; }
  float inv = 1.f / ss;
  #pragma unroll
  for (int kk = 0; kk < 8; ++kk) e[kk] *= inv;
  float4 A0 = {e[0], e[1], e[2], e[3]}, A1 = {e[4], e[5], e[6], e[7]};
  *(float4*)(attn_l + t * 8) = A0;
  *(float4*)(attn_l + t * 8 + 4) = A1;
  __syncthreads();

  float au[8][2];
  #pragma unroll
  for (int i = 0; i < 8; ++i) { au[i][0] = 0.f; au[i][1] = 0.f; }
  const int p = l & 31, g = l >> 5;
  const u32* vw = (const u32*)(v_ws + ((long)by * Nn + bx * 128 + w * 64) * 64);
  #pragma unroll 8
  for (int nn = 0; nn < 32; ++nn) {
    int n = nn * 2 + g;
    float4 a0 = *(const float4*)(attn_l + (w * 64 + n) * 8);
    float4 a1 = *(const float4*)(attn_l + (w * 64 + n) * 8 + 4);
    u32 vv = vw[n * 32 + p];
    float vlo = b2f((u16)(vv & 0xffff)), vhi = b2f((u16)(vv >> 16));
    au[0][0] += a0.x * vlo; au[0][1] += a0.x * vhi;
    au[1][0] += a0.y * vlo; au[1][1] += a0.y * vhi;
    au[2][0] += a0.z * vlo; au[2][1] += a0.z * vhi;
    au[3][0] += a0.w * vlo; au[3][1] += a0.w * vhi;
    au[4][0] += a1.x * vlo; au[4][1] += a1.x * vhi;
    au[5][0] += a1.y * vlo; au[5][1] += a1.y * vhi;
    au[6][0] += a1.z * vlo; au[6][1] += a1.z * vhi;
    au[7][0] += a1.w * vlo; au[7][1] += a1.w * vhi;
  }
  #pragma unroll
  for (int kk = 0; kk < 8; ++kk) {
    au[kk][0] += __shfl_xor(au[kk][0], 32);
    au[kk][1] += __shfl_xor(au[kk][1], 32);
  }
  float s8[8];
  #pragma unroll
  for (int kk = 0; kk < 8; ++kk) {
    s8[kk] = e[kk];
    #pragma unroll
    for (int m = 1; m < 64; m <<= 1) s8[kk] += __shfl_xor(s8[kk], m);
  }
  __syncthreads();
  float* ured = attn_l;
  if (l < 32) {
    #pragma unroll
    for (int kk = 0; kk < 8; ++kk) {
      ured[w * 512 + kk * 64 + 2 * p]     = au[kk][0];
      ured[w * 512 + kk * 64 + 2 * p + 1] = au[kk][1];
    }
  }
  if (l == 0) {
    #pragma unroll
    for (int kk = 0; kk < 8; ++kk) sred[w * 8 + kk] = s8[kk];
  }
  __syncthreads();
  for (int i = t; i < 512; i += 128)
    U_part[((long)(by * 32 + bx)) * 512 + i] = ured[i] + ured[512 + i];
  if (t < 8)
    S_part[(by * 32 + bx) * 8 + t] = sred[t] + sred[8 + t];
}

// ---------------------------------------------------------------------------
// K3: reduce partials, GRU, MLP -> slots; LN+q -> q_ws. All weight matmuls
// read bf16 XOR-swizzled LDS images staged via gll16 (no global gathers).
// ---------------------------------------------------------------------------
__global__ __launch_bounds__(256) void k_update(
    const float* __restrict__ S_part, const float* __restrict__ U_part,
    const float* __restrict__ slots_in, int init_slots,
    const float* __restrict__ noise, const float* __restrict__ mu,
    const float* __restrict__ ls, const u16* __restrict__ wupd_sw,
    const float* __restrict__ b_ih, const float* __restrict__ b_hh,
    const float* __restrict__ gm, const float* __restrict__ bm,
    const float* __restrict__ b1, const float* __restrict__ b2,
    const float* __restrict__ gs, const float* __restrict__ bs,
    float* __restrict__ slots_out, float* __restrict__ q_ws,
    float* __restrict__ out_slots, int write_out) {
  const int b = blockIdx.x, t = threadIdx.x;
  __shared__ __align__(16) u16 wupd[45056];   // 88KB: wih|whh|w1|w2|wq
  __shared__ float u_l[512], sp[512], gi[1536], gh[1536], sn2[512], mi[512],
      h1[1024], Ssum[8];
  const u16* wih_l = wupd;
  const u16* whh_l = wupd + 12288;
  const u16* w1_l  = wupd + 24576;
  const u16* w2_l  = wupd + 32768;
  const u16* wq_l  = wupd + 40960;

  {  // stage all update weights: 90112 B = 22 chunks x 256 thr x 16 B
    #pragma unroll
    for (int c = 0; c < 22; ++c) {
      int off = c * 4096 + t * 16;
      gll16((const char*)wupd_sw + off, (char*)wupd + off);
    }
  }
  if (t < 8) {
    float s = 0.f;
    #pragma unroll
    for (int ch = 0; ch < 32; ++ch) s += S_part[(b * 32 + ch) * 8 + t];
    Ssum[t] = s;
  }
  for (int i = t; i < 512; i += 256) {
    float v;
    if (init_slots) { int d = i & 63; v = mu[d] + __expf(ls[d]) * noise[b * 512 + i]; }
    else v = slots_in[b * 512 + i];
    sp[i] = v;
  }
  __syncthreads();   // staging (vmcnt) + smalls
  for (int i = t; i < 512; i += 256) {
    float s = 0.f;
    #pragma unroll
    for (int ch = 0; ch < 32; ++ch) s += U_part[((long)(b * 32 + ch)) * 512 + i];
    u_l[i] = s / (Ssum[i >> 6] + EPSc);
  }
  __syncthreads();
  for (int i = t; i < 1536; i += 256) {
    int kk = i / 192, j = i - kk * 192;
    gi[i] = b_ih[j] + dotL64(u_l + kk * 64, wih_l, j);
    gh[i] = b_hh[j] + dotL64(sp + kk * 64, whh_l, j);
  }
  __syncthreads();
  for (int i = t; i < 512; i += 256) {
    int kk = i >> 6, d = i & 63, base = kk * 192;
    float r = sigmoidf_(gi[base + d] + gh[base + d]);
    float z = sigmoidf_(gi[base + 64 + d] + gh[base + 64 + d]);
    float nn = tanhf(gi[base + 128 + d] + r * gh[base + 128 + d]);
    sn2[i] = (1.f - z) * nn + z * sp[i];
  }
  __syncthreads();
  ln8(sn2, mi, gm, bm, t);
  __syncthreads();
  for (int i = t; i < 1024; i += 256) {
    int kk = i >> 7, j = i & 127;
    h1[i] = fmaxf(b1[j] + dotL64(mi + kk * 64, w1_l, j), 0.f);
  }
  __syncthreads();
  for (int i = t; i < 512; i += 256) {
    int kk = i >> 6, d = i & 63;
    float s = sn2[i] + b2[d] + dotL128(h1 + kk * 128, w2_l, d);
    slots_out[b * 512 + i] = s;
    if (write_out) out_slots[b * 512 + i] = s;
    u_l[i] = s;
  }
  __syncthreads();
  ln8(u_l, mi, gs, bs, t);
  __syncthreads();
  for (int i = t; i < 512; i += 256)
    q_ws[b * 512 + i] = SCALEc * dotL64(mi + (i >> 6) * 64, wq_l, i & 63);
}

// ---------------------------------------------------------------------------
// K4: final attention map. grid (32,32), 128 thr. (unchanged from R8)
// ---------------------------------------------------------------------------
__global__ __launch_bounds__(128) void k_final(
    const float* __restrict__ q_ws, const u16* __restrict__ k_img,
    float* __restrict__ outA) {
  const int bx = blockIdx.x, by = blockIdx.y, t = threadIdx.x;
  __shared__ __align__(16) u16 k_l[8192];
  __shared__ float ql[512];
  {
    const char* gsrc = (const char*)(k_img + ((long)(by * 32 + bx)) * 8192);
    #pragma unroll
    for (int i = 0; i < 8; ++i) {
      int off = i * 2048 + t * 16;
      gll16(gsrc + off, (char*)k_l + off);
    }
  }
  for (int i = t; i < 512; i += 128) ql[i] = q_ws[by * 512 + i];
  __syncthreads();
  short8 kw8[8];
  #pragma unroll
  for (int j = 0; j < 8; ++j)
    kw8[j] = *(const short8*)((const char*)k_l + ((t * 128 + 16 * j) ^ ((t & 7) << 4)));
  float lg[8];
  #pragma unroll
  for (int i = 0; i < 8; ++i) lg[i] = 0.f;
  #pragma unroll
  for (int c4 = 0; c4 < 16; ++c4) {
    int j = c4 >> 1, e0 = (c4 & 1) * 4;
    float f0 = b2f((u16)kw8[j][e0]);
    float f1 = b2f((u16)kw8[j][e0 + 1]);
    float f2v = b2f((u16)kw8[j][e0 + 2]);
    float f3 = b2f((u16)kw8[j][e0 + 3]);
    #pragma unroll
    for (int kk = 0; kk < 8; ++kk) {
      float4 qv = *(const float4*)(ql + kk * 64 + c4 * 4);
      lg[kk] += qv.x * f0 + qv.y * f1 + qv.z * f2v + qv.w * f3;
    }
  }
  float mx = lg[0];
  #pragma unroll
  for (int kk = 1; kk < 8; ++kk) mx = fmaxf(mx, lg[kk]);
  float e[8], ss = 0.f;
  #pragma unroll
  for (int kk = 0; kk < 8; ++kk) { e[kk] = __expf(lg[kk] - mx); ss += e[kk]; }
  float inv = 1.f / ss;
  int n = bx * 128 + t;
  #pragma unroll
  for (int kk = 0; kk < 8; ++kk)
    outA[((long)by * 8 + kk) * 4096 + n] = e[kk] * inv;
}

extern "C" void kernel_launch(void* const* d_in, const int* in_sizes, int n_in,
                              void* d_out, int out_size, void* d_ws, size_t ws_size,
                              hipStream_t stream) {
  (void)in_sizes; (void)n_in; (void)out_size; (void)ws_size;
  const float* in    = (const float*)d_in[0];
  const float* noise = (const float*)d_in[1];
  const float* mu    = (const float*)d_in[2];
  const float* ls    = (const float*)d_in[3];
  const float* gpro  = (const float*)d_in[4];
  const float* bpro  = (const float*)d_in[5];
  const float* Wp    = (const float*)d_in[6];
  const float* bproj = (const float*)d_in[7];
  const float* Wq    = (const float*)d_in[8];
  const float* Wk    = (const float*)d_in[9];
  const float* Wv    = (const float*)d_in[10];
  const float* W_ih  = (const float*)d_in[11];
  const float* W_hh  = (const float*)d_in[12];
  const float* b_ih  = (const float*)d_in[13];
  const float* b_hh  = (const float*)d_in[14];
  const float* W1    = (const float*)d_in[15];
  const float* b1    = (const float*)d_in[16];
  const float* W2    = (const float*)d_in[17];
  const float* b2    = (const float*)d_in[18];
  const float* gin   = (const float*)d_in[19];
  const float* bin   = (const float*)d_in[20];
  const float* gs    = (const float*)d_in[21];
  const float* bs    = (const float*)d_in[22];
  const float* gm    = (const float*)d_in[23];
  const float* bm    = (const float*)d_in[24];

  char* ws = (char*)d_ws;
  u16* k_ws      = (u16*)ws;                                   // 16 MiB swizzle image
  u16* v_ws      = (u16*)(ws + 16777216);                      // 16 MiB linear
  float* S_part  = (float*)(ws + 33554432);                    // 32 KiB
  float* U_part  = (float*)(ws + 33554432 + 32768);            // 2 MiB
  float* slots_a = (float*)(ws + 33554432 + 32768 + 2097152);  // 64 KiB
  float* slots_b = (float*)(ws + 33554432 + 32768 + 2097152 + 65536);
  float* q_ws    = (float*)(ws + 33554432 + 32768 + 2097152 + 131072);
  u16* wp_sw     = (u16*)(ws + 33554432 + 32768 + 2097152 + 131072 + 65536);
  u16* wk_sw     = wp_sw + 16384;
  u16* wv_sw     = wk_sw + 4096;
  u16* wupd_sw   = wv_sw + 4096;                               // 45056 u16
  float* out = (float*)d_out;

  k_prep<<<dim3(304), dim3(256), 0, stream>>>(Wp, Wk, Wv, W_ih, W_hh, W1, W2, Wq,
                                              wp_sw, wk_sw, wv_sw, wupd_sw,
                                              noise, mu, ls, gs, bs, q_ws);
  k_proj_kv<<<dim3(512), dim3(256), 0, stream>>>(in, gpro, bpro, wp_sw, bproj,
                                                 gin, bin, wk_sw, wv_sw, k_ws, v_ws);
  dim3 ga(32, 32), ba(128);
  // iter 0
  k_attn<<<ga, ba, 0, stream>>>(q_ws, k_ws, v_ws, S_part, U_part);
  k_update<<<dim3(32), dim3(256), 0, stream>>>(S_part, U_part, slots_a, 1, noise,
                                               mu, ls, wupd_sw, b_ih, b_hh, gm, bm,
                                               b1, b2, gs, bs, slots_a, q_ws, out, 0);
  // iter 1
  k_attn<<<ga, ba, 0, stream>>>(q_ws, k_ws, v_ws, S_part, U_part);
  k_update<<<dim3(32), dim3(256), 0, stream>>>(S_part, U_part, slots_a, 0, noise,
                                               mu, ls, wupd_sw, b_ih, b_hh, gm, bm,
                                               b1, b2, gs, bs, slots_b, q_ws, out, 0);
  // iter 2 (slots -> d_out)
  k_attn<<<ga, ba, 0, stream>>>(q_ws, k_ws, v_ws, S_part, U_part);
  k_update<<<dim3(32), dim3(256), 0, stream>>>(S_part, U_part, slots_b, 0, noise,
                                               mu, ls, wupd_sw, b_ih, b_hh, gm, bm,
                                               b1, b2, gs, bs, slots_a, q_ws, out, 1);
  // final attention map
  k_final<<<ga, ba, 0, stream>>>(q_ws, k_ws, out + 16384);
}

// Round 10
// 179.590 us; speedup vs baseline: 1.8728x; 1.8728x over previous
//
#include <hip/hip_runtime.h>

typedef unsigned short u16;
typedef unsigned int   u32;
typedef __attribute__((ext_vector_type(8)))  short short8;
typedef __attribute__((ext_vector_type(4)))  float f32x4v;

#define DEVI __device__ __forceinline__

constexpr int   Bb = 32, Nn = 4096, Dd = 256, Kk = 8, SDd = 64, HDd = 128;
constexpr float EPSc = 1e-8f, LNEPS = 1e-5f, SCALEc = 0.125f;  // SD^-0.5

DEVI u16 f2b(float f) {            // f32 -> bf16 RNE
  u32 u = __builtin_bit_cast(u32, f);
  return (u16)((u + 0x7fffu + ((u >> 16) & 1u)) >> 16);
}
DEVI float b2f(u16 s) { return __builtin_bit_cast(float, ((u32)s) << 16); }
DEVI float sigmoidf_(float x) { return 1.f / (1.f + __expf(-x)); }

DEVI void gll16(const void* g, void* l) {   // async 16B/lane global->LDS
  __builtin_amdgcn_global_load_lds(
      (const __attribute__((address_space(1))) u32*)g,
      (__attribute__((address_space(3))) u32*)l, 16, 0, 0);
}

DEVI float dot64(const float* __restrict__ a, const float* __restrict__ w) {
  float s = 0.f;
  #pragma unroll
  for (int i = 0; i < 16; ++i) {
    float4 av = *(const float4*)(a + i * 4);
    float4 wv = *(const float4*)(w + i * 4);
    s += av.x * wv.x + av.y * wv.y + av.z * wv.z + av.w * wv.w;
  }
  return s;
}
// dot of 64 f32 (LDS) with bf16 LDS row j of a 64-col XOR-swizzled image
DEVI float dotL64(const float* __restrict__ x, const u16* __restrict__ wl, int j) {
  float s = 0.f;
  #pragma unroll
  for (int i = 0; i < 8; ++i) {
    short8 wv8 = *(const short8*)((const char*)wl + ((j * 128 + 16 * i) ^ ((j & 7) << 4)));
    #pragma unroll
    for (int e = 0; e < 8; ++e) s += x[i * 8 + e] * b2f((u16)wv8[e]);
  }
  return s;
}
// dot of 128 f32 (LDS) with bf16 LDS row j of a 128-col XOR-swizzled image
DEVI float dotL128(const float* __restrict__ x, const u16* __restrict__ wl, int j) {
  float s = 0.f;
  #pragma unroll
  for (int i = 0; i < 16; ++i) {
    short8 wv8 = *(const short8*)((const char*)wl + ((j * 256 + 16 * i) ^ ((j & 7) << 4)));
    #pragma unroll
    for (int e = 0; e < 8; ++e) s += x[i * 8 + e] * b2f((u16)wv8[e]);
  }
  return s;
}

// LayerNorm of 8 rows x 64 cols living in LDS (256 threads).
DEVI void ln8(const float* src, float* dst, const float* __restrict__ g,
              const float* __restrict__ b, int t) {
  int l = t & 63, w = t >> 6;
  int r = w * 2 + (l >> 5), c = l & 31;
  float x0 = src[r * 64 + c], x1 = src[r * 64 + c + 32];
  float s = x0 + x1, q2 = x0 * x0 + x1 * x1;
  #pragma unroll
  for (int m = 1; m < 32; m <<= 1) { s += __shfl_xor(s, m); q2 += __shfl_xor(q2, m); }
  float mean = s * (1.f / 64.f);
  float rs = rsqrtf(q2 * (1.f / 64.f) - mean * mean + LNEPS);
  dst[r * 64 + c]      = (x0 - mean) * rs * g[c]      + b[c];
  dst[r * 64 + c + 32] = (x1 - mean) * rs * g[c + 32] + b[c + 32];
}

// ---------------------------------------------------------------------------
// K0: blocks 0..271: ALL weights -> bf16 XOR-swizzled images.
//     blocks 272..303: initial slots -> LN -> q into q_ws.
// ---------------------------------------------------------------------------
__global__ __launch_bounds__(256) void k_prep(
    const float* __restrict__ Wp, const float* __restrict__ Wk,
    const float* __restrict__ Wv, const float* __restrict__ W_ih,
    const float* __restrict__ W_hh, const float* __restrict__ W1,
    const float* __restrict__ W2, const float* __restrict__ Wq,
    u16* __restrict__ wp_sw, u16* __restrict__ wk_sw, u16* __restrict__ wv_sw,
    u16* __restrict__ wupd_sw,
    const float* __restrict__ noise, const float* __restrict__ mu,
    const float* __restrict__ ls, const float* __restrict__ gs,
    const float* __restrict__ bs, float* __restrict__ q_ws) {
  const int t = threadIdx.x;
  if (blockIdx.x < 272) {
    int i = blockIdx.x * 256 + t;
    if (i < 16384) {
      wp_sw[i ^ (((i >> 8) & 7) << 3)] = f2b(Wp[i]);
    } else if (i < 20480) {
      int j = i - 16384; wk_sw[j ^ (((j >> 6) & 7) << 3)] = f2b(Wk[j]);
    } else if (i < 24576) {
      int j = i - 20480; wv_sw[j ^ (((j >> 6) & 7) << 3)] = f2b(Wv[j]);
    } else if (i < 36864) {
      int j = i - 24576; wupd_sw[j ^ (((j >> 6) & 7) << 3)] = f2b(W_ih[j]);
    } else if (i < 49152) {
      int j = i - 36864; wupd_sw[12288 + (j ^ (((j >> 6) & 7) << 3))] = f2b(W_hh[j]);
    } else if (i < 57344) {
      int j = i - 49152; wupd_sw[24576 + (j ^ (((j >> 6) & 7) << 3))] = f2b(W1[j]);
    } else if (i < 65536) {
      int j = i - 57344; wupd_sw[32768 + (j ^ (((j >> 7) & 7) << 3))] = f2b(W2[j]);
    } else if (i < 69632) {
      int j = i - 65536; wupd_sw[40960 + (j ^ (((j >> 6) & 7) << 3))] = f2b(Wq[j]);
    }
    return;
  }
  const int b = blockIdx.x - 272;
  __shared__ float sl[512], snl[512];
  for (int i = t; i < 512; i += 256) {
    int d = i & 63;
    sl[i] = mu[d] + __expf(ls[d]) * noise[b * 512 + i];
  }
  __syncthreads();
  ln8(sl, snl, gs, bs, t);
  __syncthreads();
  for (int i = t; i < 512; i += 256)
    q_ws[b * 512 + i] = SCALEc * dot64(snl + (i >> 6) * 64, Wq + (i & 63) * 64);
}

// ---------------------------------------------------------------------------
// K1: R2-style proj (best measured; ~40us inferred from R3 accounting).
// 64 rows/block, 2048 blocks, 4 waves x 16 rows. Weights staged to LDS via
// gll16 from swizzle images; A-frags per-lane strided; MFMA B from LDS.
// k_ws: per-128-row swizzle image; v_ws linear.
// ---------------------------------------------------------------------------
__global__ __launch_bounds__(256) void k_proj_kv(
    const float* __restrict__ in, const float* __restrict__ gpro,
    const float* __restrict__ bpro, const u16* __restrict__ wp_sw,
    const float* __restrict__ bproj, const float* __restrict__ gin,
    const float* __restrict__ bin, const u16* __restrict__ wk_sw,
    const u16* __restrict__ wv_sw, u16* __restrict__ k_ws,
    u16* __restrict__ v_ws) {
  __shared__ __align__(16) u16 wp_lds[64 * 256];
  __shared__ __align__(16) u16 wk_lds[64 * 64];
  __shared__ __align__(16) u16 wv_lds[64 * 64];
  __shared__ __align__(16) u16 xn_lds[64 * 64];
  __shared__ float gp_l[256], bp_l[256], bj_l[64], gn_l[64], bn_l[64];

  const int t = threadIdx.x;
  const int l = t & 63, w = t >> 6;

  {
    #pragma unroll
    for (int i = 0; i < 8; ++i) {
      int off = w * 8192 + i * 1024 + l * 16;
      gll16((const char*)wp_sw + off, (char*)wp_lds + off);
    }
    #pragma unroll
    for (int i = 0; i < 2; ++i) {
      int off = w * 2048 + i * 1024 + l * 16;
      gll16((const char*)wk_sw + off, (char*)wk_lds + off);
      gll16((const char*)wv_sw + off, (char*)wv_lds + off);
    }
  }
  gp_l[t] = gpro[t];
  bp_l[t] = bpro[t];
  if (t < 64) { bj_l[t] = bproj[t]; gn_l[t] = gin[t]; bn_l[t] = bin[t]; }

  const int r16 = l & 15, q4 = l >> 4;
  const long rowbase = (long)blockIdx.x * 64 + w * 16;
  const long grow = rowbase + r16;
  const float* rp = in + grow * 256;

  short8 a[8];
  float sum = 0.f, sq = 0.f;
  #pragma unroll
  for (int ks = 0; ks < 8; ++ks) {
    float4 L0 = *(const float4*)(rp + ks * 32 + q4 * 8);
    float4 L1 = *(const float4*)(rp + ks * 32 + q4 * 8 + 4);
    sum += L0.x + L0.y + L0.z + L0.w + L1.x + L1.y + L1.z + L1.w;
    sq += L0.x * L0.x + L0.y * L0.y + L0.z * L0.z + L0.w * L0.w +
          L1.x * L1.x + L1.y * L1.y + L1.z * L1.z + L1.w * L1.w;
    a[ks][0] = (short)f2b(L0.x); a[ks][1] = (short)f2b(L0.y);
    a[ks][2] = (short)f2b(L0.z); a[ks][3] = (short)f2b(L0.w);
    a[ks][4] = (short)f2b(L1.x); a[ks][5] = (short)f2b(L1.y);
    a[ks][6] = (short)f2b(L1.z); a[ks][7] = (short)f2b(L1.w);
  }
  __syncthreads();  // staging (vmcnt) + smalls complete

  sum += __shfl_xor(sum, 16); sum += __shfl_xor(sum, 32);
  sq  += __shfl_xor(sq, 16);  sq  += __shfl_xor(sq, 32);
  float mean = sum * (1.f / 256.f);
  float rs = rsqrtf(sq * (1.f / 256.f) - mean * mean + LNEPS);
  #pragma unroll
  for (int ks = 0; ks < 8; ++ks) {
    #pragma unroll
    for (int j = 0; j < 8; ++j) {
      int kidx = ks * 32 + q4 * 8 + j;
      float x = b2f((u16)a[ks][j]);
      a[ks][j] = (short)f2b((x - mean) * rs * gp_l[kidx] + bp_l[kidx]);
    }
  }

  f32x4v acc[4];
  #pragma unroll
  for (int nt = 0; nt < 4; ++nt)
    #pragma unroll
    for (int i = 0; i < 4; ++i) acc[nt][i] = 0.f;
  #pragma unroll
  for (int ks = 0; ks < 8; ++ks) {
    #pragma unroll
    for (int nt = 0; nt < 4; ++nt) {
      int n = nt * 16 + r16;
      int byte = (n * 512 + 64 * ks + 16 * q4) ^ ((n & 7) << 4);
      short8 bf = *(const short8*)((const char*)wp_lds + byte);
      acc[nt] = __builtin_amdgcn_mfma_f32_16x16x32_bf16(a[ks], bf, acc[nt], 0, 0, 0);
    }
  }
  #pragma unroll
  for (int nt = 0; nt < 4; ++nt) {
    float bb = bj_l[nt * 16 + r16];
    #pragma unroll
    for (int reg = 0; reg < 4; ++reg) acc[nt][reg] += bb;
  }
  #pragma unroll
  for (int reg = 0; reg < 4; ++reg) {
    float s = acc[0][reg] + acc[1][reg] + acc[2][reg] + acc[3][reg];
    float q2 = acc[0][reg] * acc[0][reg] + acc[1][reg] * acc[1][reg] +
               acc[2][reg] * acc[2][reg] + acc[3][reg] * acc[3][reg];
    #pragma unroll
    for (int m = 1; m < 16; m <<= 1) { s += __shfl_xor(s, m); q2 += __shfl_xor(q2, m); }
    float mn = s * (1.f / 64.f);
    float rr = rsqrtf(q2 * (1.f / 64.f) - mn * mn + LNEPS);
    int row = q4 * 4 + reg;
    int rowg = w * 16 + row;
    #pragma unroll
    for (int nt = 0; nt < 4; ++nt) {
      int col = nt * 16 + r16;
      float y = (acc[nt][reg] - mn) * rr * gn_l[col] + bn_l[col];
      int byte = (rowg * 128 + 2 * col) ^ ((row & 7) << 4);
      *(u16*)((char*)xn_lds + byte) = f2b(y);
    }
  }
  __syncthreads();

  f32x4v kacc[4], vacc[4];
  #pragma unroll
  for (int nt = 0; nt < 4; ++nt)
    #pragma unroll
    for (int i = 0; i < 4; ++i) { kacc[nt][i] = 0.f; vacc[nt][i] = 0.f; }
  #pragma unroll
  for (int ks = 0; ks < 2; ++ks) {
    int rowg2 = w * 16 + r16;
    int abyte = (rowg2 * 128 + 64 * ks + 16 * q4) ^ ((r16 & 7) << 4);
    short8 af = *(const short8*)((const char*)xn_lds + abyte);
    #pragma unroll
    for (int nt = 0; nt < 4; ++nt) {
      int n = nt * 16 + r16;
      int bbyte = (n * 128 + 64 * ks + 16 * q4) ^ ((n & 7) << 4);
      short8 bk = *(const short8*)((const char*)wk_lds + bbyte);
      short8 bv = *(const short8*)((const char*)wv_lds + bbyte);
      kacc[nt] = __builtin_amdgcn_mfma_f32_16x16x32_bf16(af, bk, kacc[nt], 0, 0, 0);
      vacc[nt] = __builtin_amdgcn_mfma_f32_16x16x32_bf16(af, bv, vacc[nt], 0, 0, 0);
    }
  }
  #pragma unroll
  for (int nt = 0; nt < 4; ++nt) {
    #pragma unroll
    for (int reg = 0; reg < 4; ++reg) {
      int row = q4 * 4 + reg;
      long gr = rowbase + row;
      int col = nt * 16 + r16;
      long tile = gr >> 7;               // k: per-128-row swizzle image
      int  r    = (int)(gr & 127);
      long ko = tile * 8192 + ((r * 64 + col) ^ ((r & 7) << 3));
      k_ws[ko] = f2b(kacc[nt][reg]);
      v_ws[gr * 64 + col] = f2b(vacc[nt][reg]);
    }
  }
}

// ---------------------------------------------------------------------------
// K2: pure attention stream. grid (32,32), 128 thr.
// ---------------------------------------------------------------------------
__global__ __launch_bounds__(128) void k_attn(
    const float* __restrict__ q_ws, const u16* __restrict__ k_img,
    const u16* __restrict__ v_ws, float* __restrict__ S_part,
    float* __restrict__ U_part) {
  const int bx = blockIdx.x, by = blockIdx.y, t = threadIdx.x;
  const int l = t & 63, w = t >> 6;
  __shared__ __align__(16) u16 k_l[8192];
  __shared__ float ql[512];
  __shared__ __align__(16) float attn_l[1024];
  __shared__ float sred[16];

  {
    const char* gsrc = (const char*)(k_img + ((long)(by * 32 + bx)) * 8192);
    #pragma unroll
    for (int i = 0; i < 8; ++i) {
      int off = i * 2048 + t * 16;
      gll16(gsrc + off, (char*)k_l + off);
    }
  }
  for (int i = t; i < 512; i += 128) ql[i] = q_ws[by * 512 + i];
  __syncthreads();

  short8 kw8[8];
  #pragma unroll
  for (int j = 0; j < 8; ++j)
    kw8[j] = *(const short8*)((const char*)k_l + ((t * 128 + 16 * j) ^ ((t & 7) << 4)));
  float lg[8];
  #pragma unroll
  for (int i = 0; i < 8; ++i) lg[i] = 0.f;
  #pragma unroll
  for (int c4 = 0; c4 < 16; ++c4) {
    int j = c4 >> 1, e0 = (c4 & 1) * 4;
    float f0 = b2f((u16)kw8[j][e0]);
    float f1 = b2f((u16)kw8[j][e0 + 1]);
    float f2v = b2f((u16)kw8[j][e0 + 2]);
    float f3 = b2f((u16)kw8[j][e0 + 3]);
    #pragma unroll
    for (int kk = 0; kk < 8; ++kk) {
      float4 qv = *(const float4*)(ql + kk * 64 + c4 * 4);
      lg[kk] += qv.x * f0 + qv.y * f1 + qv.z * f2v + qv.w * f3;
    }
  }
  float mx = lg[0];
  #pragma unroll
  for (int kk = 1; kk < 8; ++kk) mx = fmaxf(mx, lg[kk]);
  float e[8], ss = 0.f;
  #pragma unroll
  for (int kk = 0; kk < 8; ++kk) { e[kk] = __expf(lg[kk] - mx); ss += e[kk]; }
  float inv = 1.f / ss;
  #pragma unroll
  for (int kk = 0; kk < 8; ++kk) e[kk] *= inv;
  float4 A0 = {e[0], e[1], e[2], e[3]}, A1 = {e[4], e[5], e[6], e[7]};
  *(float4*)(attn_l + t * 8) = A0;
  *(float4*)(attn_l + t * 8 + 4) = A1;
  __syncthreads();

  float au[8][2];
  #pragma unroll
  for (int i = 0; i < 8; ++i) { au[i][0] = 0.f; au[i][1] = 0.f; }
  const int p = l & 31, g = l >> 5;
  const u32* vw = (const u32*)(v_ws + ((long)by * Nn + bx * 128 + w * 64) * 64);
  #pragma unroll 8
  for (int nn = 0; nn < 32; ++nn) {
    int n = nn * 2 + g;
    float4 a0 = *(const float4*)(attn_l + (w * 64 + n) * 8);
    float4 a1 = *(const float4*)(attn_l + (w * 64 + n) * 8 + 4);
    u32 vv = vw[n * 32 + p];
    float vlo = b2f((u16)(vv & 0xffff)), vhi = b2f((u16)(vv >> 16));
    au[0][0] += a0.x * vlo; au[0][1] += a0.x * vhi;
    au[1][0] += a0.y * vlo; au[1][1] += a0.y * vhi;
    au[2][0] += a0.z * vlo; au[2][1] += a0.z * vhi;
    au[3][0] += a0.w * vlo; au[3][1] += a0.w * vhi;
    au[4][0] += a1.x * vlo; au[4][1] += a1.x * vhi;
    au[5][0] += a1.y * vlo; au[5][1] += a1.y * vhi;
    au[6][0] += a1.z * vlo; au[6][1] += a1.z * vhi;
    au[7][0] += a1.w * vlo; au[7][1] += a1.w * vhi;
  }
  #pragma unroll
  for (int kk = 0; kk < 8; ++kk) {
    au[kk][0] += __shfl_xor(au[kk][0], 32);
    au[kk][1] += __shfl_xor(au[kk][1], 32);
  }
  float s8[8];
  #pragma unroll
  for (int kk = 0; kk < 8; ++kk) {
    s8[kk] = e[kk];
    #pragma unroll
    for (int m = 1; m < 64; m <<= 1) s8[kk] += __shfl_xor(s8[kk], m);
  }
  __syncthreads();
  float* ured = attn_l;
  if (l < 32) {
    #pragma unroll
    for (int kk = 0; kk < 8; ++kk) {
      ured[w * 512 + kk * 64 + 2 * p]     = au[kk][0];
      ured[w * 512 + kk * 64 + 2 * p + 1] = au[kk][1];
    }
  }
  if (l == 0) {
    #pragma unroll
    for (int kk = 0; kk < 8; ++kk) sred[w * 8 + kk] = s8[kk];
  }
  __syncthreads();
  for (int i = t; i < 512; i += 128)
    U_part[((long)(by * 32 + bx)) * 512 + i] = ured[i] + ured[512 + i];
  if (t < 8)
    S_part[(by * 32 + bx) * 8 + t] = sred[t] + sred[8 + t];
}

// ---------------------------------------------------------------------------
// K3: reduce partials, GRU, MLP -> slots; LN+q -> q_ws. Weight matmuls read
// bf16 XOR-swizzled LDS images staged via gll16 (no global gathers).
// ---------------------------------------------------------------------------
__global__ __launch_bounds__(256) void k_update(
    const float* __restrict__ S_part, const float* __restrict__ U_part,
    const float* __restrict__ slots_in, int init_slots,
    const float* __restrict__ noise, const float* __restrict__ mu,
    const float* __restrict__ ls, const u16* __restrict__ wupd_sw,
    const float* __restrict__ b_ih, const float* __restrict__ b_hh,
    const float* __restrict__ gm, const float* __restrict__ bm,
    const float* __restrict__ b1, const float* __restrict__ b2,
    const float* __restrict__ gs, const float* __restrict__ bs,
    float* __restrict__ slots_out, float* __restrict__ q_ws,
    float* __restrict__ out_slots, int write_out) {
  const int b = blockIdx.x, t = threadIdx.x;
  __shared__ __align__(16) u16 wupd[45056];
  __shared__ float u_l[512], sp[512], gi[1536], gh[1536], sn2[512], mi[512],
      h1[1024], Ssum[8];
  const u16* wih_l = wupd;
  const u16* whh_l = wupd + 12288;
  const u16* w1_l  = wupd + 24576;
  const u16* w2_l  = wupd + 32768;
  const u16* wq_l  = wupd + 40960;

  {
    #pragma unroll
    for (int c = 0; c < 22; ++c) {
      int off = c * 4096 + t * 16;
      gll16((const char*)wupd_sw + off, (char*)wupd + off);
    }
  }
  if (t < 8) {
    float s = 0.f;
    #pragma unroll
    for (int ch = 0; ch < 32; ++ch) s += S_part[(b * 32 + ch) * 8 + t];
    Ssum[t] = s;
  }
  for (int i = t; i < 512; i += 256) {
    float v;
    if (init_slots) { int d = i & 63; v = mu[d] + __expf(ls[d]) * noise[b * 512 + i]; }
    else v = slots_in[b * 512 + i];
    sp[i] = v;
  }
  __syncthreads();
  for (int i = t; i < 512; i += 256) {
    float s = 0.f;
    #pragma unroll
    for (int ch = 0; ch < 32; ++ch) s += U_part[((long)(b * 32 + ch)) * 512 + i];
    u_l[i] = s / (Ssum[i >> 6] + EPSc);
  }
  __syncthreads();
  for (int i = t; i < 1536; i += 256) {
    int kk = i / 192, j = i - kk * 192;
    gi[i] = b_ih[j] + dotL64(u_l + kk * 64, wih_l, j);
    gh[i] = b_hh[j] + dotL64(sp + kk * 64, whh_l, j);
  }
  __syncthreads();
  for (int i = t; i < 512; i += 256) {
    int kk = i >> 6, d = i & 63, base = kk * 192;
    float r = sigmoidf_(gi[base + d] + gh[base + d]);
    float z = sigmoidf_(gi[base + 64 + d] + gh[base + 64 + d]);
    float nn = tanhf(gi[base + 128 + d] + r * gh[base + 128 + d]);
    sn2[i] = (1.f - z) * nn + z * sp[i];
  }
  __syncthreads();
  ln8(sn2, mi, gm, bm, t);
  __syncthreads();
  for (int i = t; i < 1024; i += 256) {
    int kk = i >> 7, j = i & 127;
    h1[i] = fmaxf(b1[j] + dotL64(mi + kk * 64, w1_l, j), 0.f);
  }
  __syncthreads();
  for (int i = t; i < 512; i += 256) {
    int kk = i >> 6, d = i & 63;
    float s = sn2[i] + b2[d] + dotL128(h1 + kk * 128, w2_l, d);
    slots_out[b * 512 + i] = s;
    if (write_out) out_slots[b * 512 + i] = s;
    u_l[i] = s;
  }
  __syncthreads();
  ln8(u_l, mi, gs, bs, t);
  __syncthreads();
  for (int i = t; i < 512; i += 256)
    q_ws[b * 512 + i] = SCALEc * dotL64(mi + (i >> 6) * 64, wq_l, i & 63);
}

// ---------------------------------------------------------------------------
// K4: final attention map. grid (32,32), 128 thr.
// ---------------------------------------------------------------------------
__global__ __launch_bounds__(128) void k_final(
    const float* __restrict__ q_ws, const u16* __restrict__ k_img,
    float* __restrict__ outA) {
  const int bx = blockIdx.x, by = blockIdx.y, t = threadIdx.x;
  __shared__ __align__(16) u16 k_l[8192];
  __shared__ float ql[512];
  {
    const char* gsrc = (const char*)(k_img + ((long)(by * 32 + bx)) * 8192);
    #pragma unroll
    for (int i = 0; i < 8; ++i) {
      int off = i * 2048 + t * 16;
      gll16(gsrc + off, (char*)k_l + off);
    }
  }
  for (int i = t; i < 512; i += 128) ql[i] = q_ws[by * 512 + i];
  __syncthreads();
  short8 kw8[8];
  #pragma unroll
  for (int j = 0; j < 8; ++j)
    kw8[j] = *(const short8*)((const char*)k_l + ((t * 128 + 16 * j) ^ ((t & 7) << 4)));
  float lg[8];
  #pragma unroll
  for (int i = 0; i < 8; ++i) lg[i] = 0.f;
  #pragma unroll
  for (int c4 = 0; c4 < 16; ++c4) {
    int j = c4 >> 1, e0 = (c4 & 1) * 4;
    float f0 = b2f((u16)kw8[j][e0]);
    float f1 = b2f((u16)kw8[j][e0 + 1]);
    float f2v = b2f((u16)kw8[j][e0 + 2]);
    float f3 = b2f((u16)kw8[j][e0 + 3]);
    #pragma unroll
    for (int kk = 0; kk < 8; ++kk) {
      float4 qv = *(const float4*)(ql + kk * 64 + c4 * 4);
      lg[kk] += qv.x * f0 + qv.y * f1 + qv.z * f2v + qv.w * f3;
    }
  }
  float mx = lg[0];
  #pragma unroll
  for (int kk = 1; kk < 8; ++kk) mx = fmaxf(mx, lg[kk]);
  float e[8], ss = 0.f;
  #pragma unroll
  for (int kk = 0; kk < 8; ++kk) { e[kk] = __expf(lg[kk] - mx); ss += e[kk]; }
  float inv = 1.f / ss;
  int n = bx * 128 + t;
  #pragma unroll
  for (int kk = 0; kk < 8; ++kk)
    outA[((long)by * 8 + kk) * 4096 + n] = e[kk] * inv;
}

extern "C" void kernel_launch(void* const* d_in, const int* in_sizes, int n_in,
                              void* d_out, int out_size, void* d_ws, size_t ws_size,
                              hipStream_t stream) {
  (void)in_sizes; (void)n_in; (void)out_size; (void)ws_size;
  const float* in    = (const float*)d_in[0];
  const float* noise = (const float*)d_in[1];
  const float* mu    = (const float*)d_in[2];
  const float* ls    = (const float*)d_in[3];
  const float* gpro  = (const float*)d_in[4];
  const float* bpro  = (const float*)d_in[5];
  const float* Wp    = (const float*)d_in[6];
  const float* bproj = (const float*)d_in[7];
  const float* Wq    = (const float*)d_in[8];
  const float* Wk    = (const float*)d_in[9];
  const float* Wv    = (const float*)d_in[10];
  const float* W_ih  = (const float*)d_in[11];
  const float* W_hh  = (const float*)d_in[12];
  const float* b_ih  = (const float*)d_in[13];
  const float* b_hh  = (const float*)d_in[14];
  const float* W1    = (const float*)d_in[15];
  const float* b1    = (const float*)d_in[16];
  const float* W2    = (const float*)d_in[17];
  const float* b2    = (const float*)d_in[18];
  const float* gin   = (const float*)d_in[19];
  const float* bin   = (const float*)d_in[20];
  const float* gs    = (const float*)d_in[21];
  const float* bs    = (const float*)d_in[22];
  const float* gm    = (const float*)d_in[23];
  const float* bm    = (const float*)d_in[24];

  char* ws = (char*)d_ws;
  u16* k_ws      = (u16*)ws;                                   // 16 MiB swizzle image
  u16* v_ws      = (u16*)(ws + 16777216);                      // 16 MiB linear
  float* S_part  = (float*)(ws + 33554432);                    // 32 KiB
  float* U_part  = (float*)(ws + 33554432 + 32768);            // 2 MiB
  float* slots_a = (float*)(ws + 33554432 + 32768 + 2097152);  // 64 KiB
  float* slots_b = (float*)(ws + 33554432 + 32768 + 2097152 + 65536);
  float* q_ws    = (float*)(ws + 33554432 + 32768 + 2097152 + 131072);
  u16* wp_sw     = (u16*)(ws + 33554432 + 32768 + 2097152 + 131072 + 65536);
  u16* wk_sw     = wp_sw + 16384;
  u16* wv_sw     = wk_sw + 4096;
  u16* wupd_sw   = wv_sw + 4096;                               // 45056 u16
  float* out = (float*)d_out;

  k_prep<<<dim3(304), dim3(256), 0, stream>>>(Wp, Wk, Wv, W_ih, W_hh, W1, W2, Wq,
                                              wp_sw, wk_sw, wv_sw, wupd_sw,
                                              noise, mu, ls, gs, bs, q_ws);
  k_proj_kv<<<dim3(2048), dim3(256), 0, stream>>>(in, gpro, bpro, wp_sw, bproj,
                                                  gin, bin, wk_sw, wv_sw, k_ws, v_ws);
  dim3 ga(32, 32), ba(128);
  // iter 0
  k_attn<<<ga, ba, 0, stream>>>(q_ws, k_ws, v_ws, S_part, U_part);
  k_update<<<dim3(32), dim3(256), 0, stream>>>(S_part, U_part, slots_a, 1, noise,
                                               mu, ls, wupd_sw, b_ih, b_hh, gm, bm,
                                               b1, b2, gs, bs, slots_a, q_ws, out, 0);
  // iter 1
  k_attn<<<ga, ba, 0, stream>>>(q_ws, k_ws, v_ws, S_part, U_part);
  k_update<<<dim3(32), dim3(256), 0, stream>>>(S_part, U_part, slots_a, 0, noise,
                                               mu, ls, wupd_sw, b_ih, b_hh, gm, bm,
                                               b1, b2, gs, bs, slots_b, q_ws, out, 0);
  // iter 2 (slots -> d_out)
  k_attn<<<ga, ba, 0, stream>>>(q_ws, k_ws, v_ws, S_part, U_part);
  k_update<<<dim3(32), dim3(256), 0, stream>>>(S_part, U_part, slots_b, 0, noise,
                                               mu, ls, wupd_sw, b_ih, b_hh, gm, bm,
                                               b1, b2, gs, bs, slots_a, q_ws, out, 1);
  // final attention map
  k_final<<<ga, ba, 0, stream>>>(q_ws, k_ws, out + 16384);
}

// Round 11
// 176.268 us; speedup vs baseline: 1.9080x; 1.0188x over previous
//
#include <hip/hip_runtime.h>

typedef unsigned short u16;
typedef unsigned int   u32;
typedef __attribute__((ext_vector_type(8)))  short short8;
typedef __attribute__((ext_vector_type(4)))  float f32x4v;

#define DEVI __device__ __forceinline__

constexpr int   Bb = 32, Nn = 4096, Dd = 256, Kk = 8, SDd = 64, HDd = 128;
constexpr float EPSc = 1e-8f, LNEPS = 1e-5f, SCALEc = 0.125f;  // SD^-0.5

DEVI u16 f2b(float f) {            // f32 -> bf16 RNE
  u32 u = __builtin_bit_cast(u32, f);
  return (u16)((u + 0x7fffu + ((u >> 16) & 1u)) >> 16);
}
DEVI float b2f(u16 s) { return __builtin_bit_cast(float, ((u32)s) << 16); }
DEVI float sigmoidf_(float x) { return 1.f / (1.f + __expf(-x)); }

DEVI void gll16(const void* g, void* l) {   // async 16B/lane global->LDS
  __builtin_amdgcn_global_load_lds(
      (const __attribute__((address_space(1))) u32*)g,
      (__attribute__((address_space(3))) u32*)l, 16, 0, 0);
}

DEVI float dot64(const float* __restrict__ a, const float* __restrict__ w) {
  float s = 0.f;
  #pragma unroll
  for (int i = 0; i < 16; ++i) {
    float4 av = *(const float4*)(a + i * 4);
    float4 wv = *(const float4*)(w + i * 4);
    s += av.x * wv.x + av.y * wv.y + av.z * wv.z + av.w * wv.w;
  }
  return s;
}
// dot of 64 f32 (LDS) with bf16 LDS row j of a 64-col XOR-swizzled image
DEVI float dotL64(const float* __restrict__ x, const u16* __restrict__ wl, int j) {
  float s = 0.f;
  #pragma unroll
  for (int i = 0; i < 8; ++i) {
    short8 wv8 = *(const short8*)((const char*)wl + ((j * 128 + 16 * i) ^ ((j & 7) << 4)));
    #pragma unroll
    for (int e = 0; e < 8; ++e) s += x[i * 8 + e] * b2f((u16)wv8[e]);
  }
  return s;
}
// dot of 128 f32 (LDS) with bf16 LDS row j of a 128-col XOR-swizzled image
DEVI float dotL128(const float* __restrict__ x, const u16* __restrict__ wl, int j) {
  float s = 0.f;
  #pragma unroll
  for (int i = 0; i < 16; ++i) {
    short8 wv8 = *(const short8*)((const char*)wl + ((j * 256 + 16 * i) ^ ((j & 7) << 4)));
    #pragma unroll
    for (int e = 0; e < 8; ++e) s += x[i * 8 + e] * b2f((u16)wv8[e]);
  }
  return s;
}

// LayerNorm of 8 rows x 64 cols living in LDS (256 threads).
DEVI void ln8(const float* src, float* dst, const float* __restrict__ g,
              const float* __restrict__ b, int t) {
  int l = t & 63, w = t >> 6;
  int r = w * 2 + (l >> 5), c = l & 31;
  float x0 = src[r * 64 + c], x1 = src[r * 64 + c + 32];
  float s = x0 + x1, q2 = x0 * x0 + x1 * x1;
  #pragma unroll
  for (int m = 1; m < 32; m <<= 1) { s += __shfl_xor(s, m); q2 += __shfl_xor(q2, m); }
  float mean = s * (1.f / 64.f);
  float rs = rsqrtf(q2 * (1.f / 64.f) - mean * mean + LNEPS);
  dst[r * 64 + c]      = (x0 - mean) * rs * g[c]      + b[c];
  dst[r * 64 + c + 32] = (x1 - mean) * rs * g[c + 32] + b[c + 32];
}

// ---------------------------------------------------------------------------
// K0: blocks 0..271: ALL weights -> bf16 XOR-swizzled images.
//     blocks 272..303: initial slots -> LN -> q into q_ws.
// ---------------------------------------------------------------------------
__global__ __launch_bounds__(256) void k_prep(
    const float* __restrict__ Wp, const float* __restrict__ Wk,
    const float* __restrict__ Wv, const float* __restrict__ W_ih,
    const float* __restrict__ W_hh, const float* __restrict__ W1,
    const float* __restrict__ W2, const float* __restrict__ Wq,
    u16* __restrict__ wp_sw, u16* __restrict__ wk_sw, u16* __restrict__ wv_sw,
    u16* __restrict__ wupd_sw,
    const float* __restrict__ noise, const float* __restrict__ mu,
    const float* __restrict__ ls, const float* __restrict__ gs,
    const float* __restrict__ bs, float* __restrict__ q_ws) {
  const int t = threadIdx.x;
  if (blockIdx.x < 272) {
    int i = blockIdx.x * 256 + t;
    if (i < 16384) {
      wp_sw[i ^ (((i >> 8) & 7) << 3)] = f2b(Wp[i]);
    } else if (i < 20480) {
      int j = i - 16384; wk_sw[j ^ (((j >> 6) & 7) << 3)] = f2b(Wk[j]);
    } else if (i < 24576) {
      int j = i - 20480; wv_sw[j ^ (((j >> 6) & 7) << 3)] = f2b(Wv[j]);
    } else if (i < 36864) {
      int j = i - 24576; wupd_sw[j ^ (((j >> 6) & 7) << 3)] = f2b(W_ih[j]);
    } else if (i < 49152) {
      int j = i - 36864; wupd_sw[12288 + (j ^ (((j >> 6) & 7) << 3))] = f2b(W_hh[j]);
    } else if (i < 57344) {
      int j = i - 49152; wupd_sw[24576 + (j ^ (((j >> 6) & 7) << 3))] = f2b(W1[j]);
    } else if (i < 65536) {
      int j = i - 57344; wupd_sw[32768 + (j ^ (((j >> 7) & 7) << 3))] = f2b(W2[j]);
    } else if (i < 69632) {
      int j = i - 65536; wupd_sw[40960 + (j ^ (((j >> 6) & 7) << 3))] = f2b(Wq[j]);
    }
    return;
  }
  const int b = blockIdx.x - 272;
  __shared__ float sl[512], snl[512];
  for (int i = t; i < 512; i += 256) {
    int d = i & 63;
    sl[i] = mu[d] + __expf(ls[d]) * noise[b * 512 + i];
  }
  __syncthreads();
  ln8(sl, snl, gs, bs, t);
  __syncthreads();
  for (int i = t; i < 512; i += 256)
    q_ws[b * 512 + i] = SCALEc * dot64(snl + (i >> 6) * 64, Wq + (i & 63) * 64);
}

// ---------------------------------------------------------------------------
// K1: proj, 512-thread blocks (8 waves x 16 rows = 128 rows/block, grid 1024).
// Weight LDS (48KB) shared by 8 waves -> 16 waves/CU (4/SIMD), 2x R10's TLP;
// staging traffic halved. Compute path identical to R10.
// k_ws: per-128-row swizzle image; v_ws linear.
// ---------------------------------------------------------------------------
__global__ __launch_bounds__(512) void k_proj_kv(
    const float* __restrict__ in, const float* __restrict__ gpro,
    const float* __restrict__ bpro, const u16* __restrict__ wp_sw,
    const float* __restrict__ bproj, const float* __restrict__ gin,
    const float* __restrict__ bin, const u16* __restrict__ wk_sw,
    const u16* __restrict__ wv_sw, u16* __restrict__ k_ws,
    u16* __restrict__ v_ws) {
  __shared__ __align__(16) u16 wp_lds[64 * 256];    // 32KB
  __shared__ __align__(16) u16 wk_lds[64 * 64];     // 8KB
  __shared__ __align__(16) u16 wv_lds[64 * 64];     // 8KB
  __shared__ __align__(16) u16 xn_lds[128 * 64];    // 16KB (128 rows)
  __shared__ float gp_l[256], bp_l[256], bj_l[64], gn_l[64], bn_l[64];

  const int t = threadIdx.x;
  const int l = t & 63, w = t >> 6;          // w in 0..7

  {  // staging: wp 4 instr/wave, wk/wv 1 instr/wave
    #pragma unroll
    for (int i = 0; i < 4; ++i) {
      int off = w * 4096 + i * 1024 + l * 16;
      gll16((const char*)wp_sw + off, (char*)wp_lds + off);
    }
    {
      int off = w * 1024 + l * 16;
      gll16((const char*)wk_sw + off, (char*)wk_lds + off);
      gll16((const char*)wv_sw + off, (char*)wv_lds + off);
    }
  }
  if (t < 256) { gp_l[t] = gpro[t]; bp_l[t] = bpro[t]; }
  if (t < 64) { bj_l[t] = bproj[t]; gn_l[t] = gin[t]; bn_l[t] = bin[t]; }

  const int r16 = l & 15, q4 = l >> 4;
  const long rowbase = (long)blockIdx.x * 128 + w * 16;
  const long grow = rowbase + r16;
  const float* rp = in + grow * 256;

  short8 a[8];
  float sum = 0.f, sq = 0.f;
  #pragma unroll
  for (int ks = 0; ks < 8; ++ks) {
    float4 L0 = *(const float4*)(rp + ks * 32 + q4 * 8);
    float4 L1 = *(const float4*)(rp + ks * 32 + q4 * 8 + 4);
    sum += L0.x + L0.y + L0.z + L0.w + L1.x + L1.y + L1.z + L1.w;
    sq += L0.x * L0.x + L0.y * L0.y + L0.z * L0.z + L0.w * L0.w +
          L1.x * L1.x + L1.y * L1.y + L1.z * L1.z + L1.w * L1.w;
    a[ks][0] = (short)f2b(L0.x); a[ks][1] = (short)f2b(L0.y);
    a[ks][2] = (short)f2b(L0.z); a[ks][3] = (short)f2b(L0.w);
    a[ks][4] = (short)f2b(L1.x); a[ks][5] = (short)f2b(L1.y);
    a[ks][6] = (short)f2b(L1.z); a[ks][7] = (short)f2b(L1.w);
  }
  __syncthreads();  // staging (vmcnt) + smalls complete

  sum += __shfl_xor(sum, 16); sum += __shfl_xor(sum, 32);
  sq  += __shfl_xor(sq, 16);  sq  += __shfl_xor(sq, 32);
  float mean = sum * (1.f / 256.f);
  float rs = rsqrtf(sq * (1.f / 256.f) - mean * mean + LNEPS);
  #pragma unroll
  for (int ks = 0; ks < 8; ++ks) {
    #pragma unroll
    for (int j = 0; j < 8; ++j) {
      int kidx = ks * 32 + q4 * 8 + j;
      float x = b2f((u16)a[ks][j]);
      a[ks][j] = (short)f2b((x - mean) * rs * gp_l[kidx] + bp_l[kidx]);
    }
  }

  f32x4v acc[4];
  #pragma unroll
  for (int nt = 0; nt < 4; ++nt)
    #pragma unroll
    for (int i = 0; i < 4; ++i) acc[nt][i] = 0.f;
  #pragma unroll
  for (int ks = 0; ks < 8; ++ks) {
    #pragma unroll
    for (int nt = 0; nt < 4; ++nt) {
      int n = nt * 16 + r16;
      int byte = (n * 512 + 64 * ks + 16 * q4) ^ ((n & 7) << 4);
      short8 bf = *(const short8*)((const char*)wp_lds + byte);
      acc[nt] = __builtin_amdgcn_mfma_f32_16x16x32_bf16(a[ks], bf, acc[nt], 0, 0, 0);
    }
  }
  #pragma unroll
  for (int nt = 0; nt < 4; ++nt) {
    float bb = bj_l[nt * 16 + r16];
    #pragma unroll
    for (int reg = 0; reg < 4; ++reg) acc[nt][reg] += bb;
  }
  #pragma unroll
  for (int reg = 0; reg < 4; ++reg) {
    float s = acc[0][reg] + acc[1][reg] + acc[2][reg] + acc[3][reg];
    float q2 = acc[0][reg] * acc[0][reg] + acc[1][reg] * acc[1][reg] +
               acc[2][reg] * acc[2][reg] + acc[3][reg] * acc[3][reg];
    #pragma unroll
    for (int m = 1; m < 16; m <<= 1) { s += __shfl_xor(s, m); q2 += __shfl_xor(q2, m); }
    float mn = s * (1.f / 64.f);
    float rr = rsqrtf(q2 * (1.f / 64.f) - mn * mn + LNEPS);
    int row = q4 * 4 + reg;            // 0..15 within wave tile
    int rowg = w * 16 + row;           // 0..127
    #pragma unroll
    for (int nt = 0; nt < 4; ++nt) {
      int col = nt * 16 + r16;
      float y = (acc[nt][reg] - mn) * rr * gn_l[col] + bn_l[col];
      int byte = (rowg * 128 + 2 * col) ^ ((row & 7) << 4);
      *(u16*)((char*)xn_lds + byte) = f2b(y);
    }
  }
  __syncthreads();

  f32x4v kacc[4], vacc[4];
  #pragma unroll
  for (int nt = 0; nt < 4; ++nt)
    #pragma unroll
    for (int i = 0; i < 4; ++i) { kacc[nt][i] = 0.f; vacc[nt][i] = 0.f; }
  #pragma unroll
  for (int ks = 0; ks < 2; ++ks) {
    int rowg2 = w * 16 + r16;
    int abyte = (rowg2 * 128 + 64 * ks + 16 * q4) ^ ((r16 & 7) << 4);
    short8 af = *(const short8*)((const char*)xn_lds + abyte);
    #pragma unroll
    for (int nt = 0; nt < 4; ++nt) {
      int n = nt * 16 + r16;
      int bbyte = (n * 128 + 64 * ks + 16 * q4) ^ ((n & 7) << 4);
      short8 bk = *(const short8*)((const char*)wk_lds + bbyte);
      short8 bv = *(const short8*)((const char*)wv_lds + bbyte);
      kacc[nt] = __builtin_amdgcn_mfma_f32_16x16x32_bf16(af, bk, kacc[nt], 0, 0, 0);
      vacc[nt] = __builtin_amdgcn_mfma_f32_16x16x32_bf16(af, bv, vacc[nt], 0, 0, 0);
    }
  }
  #pragma unroll
  for (int nt = 0; nt < 4; ++nt) {
    #pragma unroll
    for (int reg = 0; reg < 4; ++reg) {
      int row = q4 * 4 + reg;
      long gr = rowbase + row;
      int col = nt * 16 + r16;
      long tile = gr >> 7;               // k: per-128-row swizzle image
      int  r    = (int)(gr & 127);
      long ko = tile * 8192 + ((r * 64 + col) ^ ((r & 7) << 3));
      k_ws[ko] = f2b(kacc[nt][reg]);
      v_ws[gr * 64 + col] = f2b(vacc[nt][reg]);
    }
  }
}

// ---------------------------------------------------------------------------
// K2: pure attention stream. grid (32,32), 128 thr. (unchanged from R10)
// ---------------------------------------------------------------------------
__global__ __launch_bounds__(128) void k_attn(
    const float* __restrict__ q_ws, const u16* __restrict__ k_img,
    const u16* __restrict__ v_ws, float* __restrict__ S_part,
    float* __restrict__ U_part) {
  const int bx = blockIdx.x, by = blockIdx.y, t = threadIdx.x;
  const int l = t & 63, w = t >> 6;
  __shared__ __align__(16) u16 k_l[8192];
  __shared__ float ql[512];
  __shared__ __align__(16) float attn_l[1024];
  __shared__ float sred[16];

  {
    const char* gsrc = (const char*)(k_img + ((long)(by * 32 + bx)) * 8192);
    #pragma unroll
    for (int i = 0; i < 8; ++i) {
      int off = i * 2048 + t * 16;
      gll16(gsrc + off, (char*)k_l + off);
    }
  }
  for (int i = t; i < 512; i += 128) ql[i] = q_ws[by * 512 + i];
  __syncthreads();

  short8 kw8[8];
  #pragma unroll
  for (int j = 0; j < 8; ++j)
    kw8[j] = *(const short8*)((const char*)k_l + ((t * 128 + 16 * j) ^ ((t & 7) << 4)));
  float lg[8];
  #pragma unroll
  for (int i = 0; i < 8; ++i) lg[i] = 0.f;
  #pragma unroll
  for (int c4 = 0; c4 < 16; ++c4) {
    int j = c4 >> 1, e0 = (c4 & 1) * 4;
    float f0 = b2f((u16)kw8[j][e0]);
    float f1 = b2f((u16)kw8[j][e0 + 1]);
    float f2v = b2f((u16)kw8[j][e0 + 2]);
    float f3 = b2f((u16)kw8[j][e0 + 3]);
    #pragma unroll
    for (int kk = 0; kk < 8; ++kk) {
      float4 qv = *(const float4*)(ql + kk * 64 + c4 * 4);
      lg[kk] += qv.x * f0 + qv.y * f1 + qv.z * f2v + qv.w * f3;
    }
  }
  float mx = lg[0];
  #pragma unroll
  for (int kk = 1; kk < 8; ++kk) mx = fmaxf(mx, lg[kk]);
  float e[8], ss = 0.f;
  #pragma unroll
  for (int kk = 0; kk < 8; ++kk) { e[kk] = __expf(lg[kk] - mx); ss += e[kk]; }
  float inv = 1.f / ss;
  #pragma unroll
  for (int kk = 0; kk < 8; ++kk) e[kk] *= inv;
  float4 A0 = {e[0], e[1], e[2], e[3]}, A1 = {e[4], e[5], e[6], e[7]};
  *(float4*)(attn_l + t * 8) = A0;
  *(float4*)(attn_l + t * 8 + 4) = A1;
  __syncthreads();

  float au[8][2];
  #pragma unroll
  for (int i = 0; i < 8; ++i) { au[i][0] = 0.f; au[i][1] = 0.f; }
  const int p = l & 31, g = l >> 5;
  const u32* vw = (const u32*)(v_ws + ((long)by * Nn + bx * 128 + w * 64) * 64);
  #pragma unroll 8
  for (int nn = 0; nn < 32; ++nn) {
    int n = nn * 2 + g;
    float4 a0 = *(const float4*)(attn_l + (w * 64 + n) * 8);
    float4 a1 = *(const float4*)(attn_l + (w * 64 + n) * 8 + 4);
    u32 vv = vw[n * 32 + p];
    float vlo = b2f((u16)(vv & 0xffff)), vhi = b2f((u16)(vv >> 16));
    au[0][0] += a0.x * vlo; au[0][1] += a0.x * vhi;
    au[1][0] += a0.y * vlo; au[1][1] += a0.y * vhi;
    au[2][0] += a0.z * vlo; au[2][1] += a0.z * vhi;
    au[3][0] += a0.w * vlo; au[3][1] += a0.w * vhi;
    au[4][0] += a1.x * vlo; au[4][1] += a1.x * vhi;
    au[5][0] += a1.y * vlo; au[5][1] += a1.y * vhi;
    au[6][0] += a1.z * vlo; au[6][1] += a1.z * vhi;
    au[7][0] += a1.w * vlo; au[7][1] += a1.w * vhi;
  }
  #pragma unroll
  for (int kk = 0; kk < 8; ++kk) {
    au[kk][0] += __shfl_xor(au[kk][0], 32);
    au[kk][1] += __shfl_xor(au[kk][1], 32);
  }
  float s8[8];
  #pragma unroll
  for (int kk = 0; kk < 8; ++kk) {
    s8[kk] = e[kk];
    #pragma unroll
    for (int m = 1; m < 64; m <<= 1) s8[kk] += __shfl_xor(s8[kk], m);
  }
  __syncthreads();
  float* ured = attn_l;
  if (l < 32) {
    #pragma unroll
    for (int kk = 0; kk < 8; ++kk) {
      ured[w * 512 + kk * 64 + 2 * p]     = au[kk][0];
      ured[w * 512 + kk * 64 + 2 * p + 1] = au[kk][1];
    }
  }
  if (l == 0) {
    #pragma unroll
    for (int kk = 0; kk < 8; ++kk) sred[w * 8 + kk] = s8[kk];
  }
  __syncthreads();
  for (int i = t; i < 512; i += 128)
    U_part[((long)(by * 32 + bx)) * 512 + i] = ured[i] + ured[512 + i];
  if (t < 8)
    S_part[(by * 32 + bx) * 8 + t] = sred[t] + sred[8 + t];
}

// ---------------------------------------------------------------------------
// K3: reduce partials, GRU, MLP -> slots; LN+q -> q_ws. Weight matmuls read
// bf16 XOR-swizzled LDS images staged via gll16. (unchanged from R10)
// ---------------------------------------------------------------------------
__global__ __launch_bounds__(256) void k_update(
    const float* __restrict__ S_part, const float* __restrict__ U_part,
    const float* __restrict__ slots_in, int init_slots,
    const float* __restrict__ noise, const float* __restrict__ mu,
    const float* __restrict__ ls, const u16* __restrict__ wupd_sw,
    const float* __restrict__ b_ih, const float* __restrict__ b_hh,
    const float* __restrict__ gm, const float* __restrict__ bm,
    const float* __restrict__ b1, const float* __restrict__ b2,
    const float* __restrict__ gs, const float* __restrict__ bs,
    float* __restrict__ slots_out, float* __restrict__ q_ws,
    float* __restrict__ out_slots, int write_out) {
  const int b = blockIdx.x, t = threadIdx.x;
  __shared__ __align__(16) u16 wupd[45056];
  __shared__ float u_l[512], sp[512], gi[1536], gh[1536], sn2[512], mi[512],
      h1[1024], Ssum[8];
  const u16* wih_l = wupd;
  const u16* whh_l = wupd + 12288;
  const u16* w1_l  = wupd + 24576;
  const u16* w2_l  = wupd + 32768;
  const u16* wq_l  = wupd + 40960;

  {
    #pragma unroll
    for (int c = 0; c < 22; ++c) {
      int off = c * 4096 + t * 16;
      gll16((const char*)wupd_sw + off, (char*)wupd + off);
    }
  }
  if (t < 8) {
    float s = 0.f;
    #pragma unroll
    for (int ch = 0; ch < 32; ++ch) s += S_part[(b * 32 + ch) * 8 + t];
    Ssum[t] = s;
  }
  for (int i = t; i < 512; i += 256) {
    float v;
    if (init_slots) { int d = i & 63; v = mu[d] + __expf(ls[d]) * noise[b * 512 + i]; }
    else v = slots_in[b * 512 + i];
    sp[i] = v;
  }
  __syncthreads();
  for (int i = t; i < 512; i += 256) {
    float s = 0.f;
    #pragma unroll
    for (int ch = 0; ch < 32; ++ch) s += U_part[((long)(b * 32 + ch)) * 512 + i];
    u_l[i] = s / (Ssum[i >> 6] + EPSc);
  }
  __syncthreads();
  for (int i = t; i < 1536; i += 256) {
    int kk = i / 192, j = i - kk * 192;
    gi[i] = b_ih[j] + dotL64(u_l + kk * 64, wih_l, j);
    gh[i] = b_hh[j] + dotL64(sp + kk * 64, whh_l, j);
  }
  __syncthreads();
  for (int i = t; i < 512; i += 256) {
    int kk = i >> 6, d = i & 63, base = kk * 192;
    float r = sigmoidf_(gi[base + d] + gh[base + d]);
    float z = sigmoidf_(gi[base + 64 + d] + gh[base + 64 + d]);
    float nn = tanhf(gi[base + 128 + d] + r * gh[base + 128 + d]);
    sn2[i] = (1.f - z) * nn + z * sp[i];
  }
  __syncthreads();
  ln8(sn2, mi, gm, bm, t);
  __syncthreads();
  for (int i = t; i < 1024; i += 256) {
    int kk = i >> 7, j = i & 127;
    h1[i] = fmaxf(b1[j] + dotL64(mi + kk * 64, w1_l, j), 0.f);
  }
  __syncthreads();
  for (int i = t; i < 512; i += 256) {
    int kk = i >> 6, d = i & 63;
    float s = sn2[i] + b2[d] + dotL128(h1 + kk * 128, w2_l, d);
    slots_out[b * 512 + i] = s;
    if (write_out) out_slots[b * 512 + i] = s;
    u_l[i] = s;
  }
  __syncthreads();
  ln8(u_l, mi, gs, bs, t);
  __syncthreads();
  for (int i = t; i < 512; i += 256)
    q_ws[b * 512 + i] = SCALEc * dotL64(mi + (i >> 6) * 64, wq_l, i & 63);
}

// ---------------------------------------------------------------------------
// K4: final attention map. grid (32,32), 128 thr. (unchanged from R10)
// ---------------------------------------------------------------------------
__global__ __launch_bounds__(128) void k_final(
    const float* __restrict__ q_ws, const u16* __restrict__ k_img,
    float* __restrict__ outA) {
  const int bx = blockIdx.x, by = blockIdx.y, t = threadIdx.x;
  __shared__ __align__(16) u16 k_l[8192];
  __shared__ float ql[512];
  {
    const char* gsrc = (const char*)(k_img + ((long)(by * 32 + bx)) * 8192);
    #pragma unroll
    for (int i = 0; i < 8; ++i) {
      int off = i * 2048 + t * 16;
      gll16(gsrc + off, (char*)k_l + off);
    }
  }
  for (int i = t; i < 512; i += 128) ql[i] = q_ws[by * 512 + i];
  __syncthreads();
  short8 kw8[8];
  #pragma unroll
  for (int j = 0; j < 8; ++j)
    kw8[j] = *(const short8*)((const char*)k_l + ((t * 128 + 16 * j) ^ ((t & 7) << 4)));
  float lg[8];
  #pragma unroll
  for (int i = 0; i < 8; ++i) lg[i] = 0.f;
  #pragma unroll
  for (int c4 = 0; c4 < 16; ++c4) {
    int j = c4 >> 1, e0 = (c4 & 1) * 4;
    float f0 = b2f((u16)kw8[j][e0]);
    float f1 = b2f((u16)kw8[j][e0 + 1]);
    float f2v = b2f((u16)kw8[j][e0 + 2]);
    float f3 = b2f((u16)kw8[j][e0 + 3]);
    #pragma unroll
    for (int kk = 0; kk < 8; ++kk) {
      float4 qv = *(const float4*)(ql + kk * 64 + c4 * 4);
      lg[kk] += qv.x * f0 + qv.y * f1 + qv.z * f2v + qv.w * f3;
    }
  }
  float mx = lg[0];
  #pragma unroll
  for (int kk = 1; kk < 8; ++kk) mx = fmaxf(mx, lg[kk]);
  float e[8], ss = 0.f;
  #pragma unroll
  for (int kk = 0; kk < 8; ++kk) { e[kk] = __expf(lg[kk] - mx); ss += e[kk]; }
  float inv = 1.f / ss;
  int n = bx * 128 + t;
  #pragma unroll
  for (int kk = 0; kk < 8; ++kk)
    outA[((long)by * 8 + kk) * 4096 + n] = e[kk] * inv;
}

extern "C" void kernel_launch(void* const* d_in, const int* in_sizes, int n_in,
                              void* d_out, int out_size, void* d_ws, size_t ws_size,
                              hipStream_t stream) {
  (void)in_sizes; (void)n_in; (void)out_size; (void)ws_size;
  const float* in    = (const float*)d_in[0];
  const float* noise = (const float*)d_in[1];
  const float* mu    = (const float*)d_in[2];
  const float* ls    = (const float*)d_in[3];
  const float* gpro  = (const float*)d_in[4];
  const float* bpro  = (const float*)d_in[5];
  const float* Wp    = (const float*)d_in[6];
  const float* bproj = (const float*)d_in[7];
  const float* Wq    = (const float*)d_in[8];
  const float* Wk    = (const float*)d_in[9];
  const float* Wv    = (const float*)d_in[10];
  const float* W_ih  = (const float*)d_in[11];
  const float* W_hh  = (const float*)d_in[12];
  const float* b_ih  = (const float*)d_in[13];
  const float* b_hh  = (const float*)d_in[14];
  const float* W1    = (const float*)d_in[15];
  const float* b1    = (const float*)d_in[16];
  const float* W2    = (const float*)d_in[17];
  const float* b2    = (const float*)d_in[18];
  const float* gin   = (const float*)d_in[19];
  const float* bin   = (const float*)d_in[20];
  const float* gs    = (const float*)d_in[21];
  const float* bs    = (const float*)d_in[22];
  const float* gm    = (const float*)d_in[23];
  const float* bm    = (const float*)d_in[24];

  char* ws = (char*)d_ws;
  u16* k_ws      = (u16*)ws;                                   // 16 MiB swizzle image
  u16* v_ws      = (u16*)(ws + 16777216);                      // 16 MiB linear
  float* S_part  = (float*)(ws + 33554432);                    // 32 KiB
  float* U_part  = (float*)(ws + 33554432 + 32768);            // 2 MiB
  float* slots_a = (float*)(ws + 33554432 + 32768 + 2097152);  // 64 KiB
  float* slots_b = (float*)(ws + 33554432 + 32768 + 2097152 + 65536);
  float* q_ws    = (float*)(ws + 33554432 + 32768 + 2097152 + 131072);
  u16* wp_sw     = (u16*)(ws + 33554432 + 32768 + 2097152 + 131072 + 65536);
  u16* wk_sw     = wp_sw + 16384;
  u16* wv_sw     = wk_sw + 4096;
  u16* wupd_sw   = wv_sw + 4096;                               // 45056 u16
  float* out = (float*)d_out;

  k_prep<<<dim3(304), dim3(256), 0, stream>>>(Wp, Wk, Wv, W_ih, W_hh, W1, W2, Wq,
                                              wp_sw, wk_sw, wv_sw, wupd_sw,
                                              noise, mu, ls, gs, bs, q_ws);
  k_proj_kv<<<dim3(1024), dim3(512), 0, stream>>>(in, gpro, bpro, wp_sw, bproj,
                                                  gin, bin, wk_sw, wv_sw, k_ws, v_ws);
  dim3 ga(32, 32), ba(128);
  // iter 0
  k_attn<<<ga, ba, 0, stream>>>(q_ws, k_ws, v_ws, S_part, U_part);
  k_update<<<dim3(32), dim3(256), 0, stream>>>(S_part, U_part, slots_a, 1, noise,
                                               mu, ls, wupd_sw, b_ih, b_hh, gm, bm,
                                               b1, b2, gs, bs, slots_a, q_ws, out, 0);
  // iter 1
  k_attn<<<ga, ba, 0, stream>>>(q_ws, k_ws, v_ws, S_part, U_part);
  k_update<<<dim3(32), dim3(256), 0, stream>>>(S_part, U_part, slots_a, 0, noise,
                                               mu, ls, wupd_sw, b_ih, b_hh, gm, bm,
                                               b1, b2, gs, bs, slots_b, q_ws, out, 0);
  // iter 2 (slots -> d_out)
  k_attn<<<ga, ba, 0, stream>>>(q_ws, k_ws, v_ws, S_part, U_part);
  k_update<<<dim3(32), dim3(256), 0, stream>>>(S_part, U_part, slots_b, 0, noise,
                                               mu, ls, wupd_sw, b_ih, b_hh, gm, bm,
                                               b1, b2, gs, bs, slots_a, q_ws, out, 1);
  // final attention map
  k_final<<<ga, ba, 0, stream>>>(q_ws, k_ws, out + 16384);
}

// Round 12
// 153.999 us; speedup vs baseline: 2.1840x; 1.1446x over previous
//
#include <hip/hip_runtime.h>

typedef unsigned short u16;
typedef unsigned int   u32;
typedef __attribute__((ext_vector_type(8)))  short short8;
typedef __attribute__((ext_vector_type(4)))  float f32x4v;

#define DEVI __device__ __forceinline__

constexpr int   Bb = 32, Nn = 4096, Dd = 256, Kk = 8, SDd = 64, HDd = 128;
constexpr float EPSc = 1e-8f, LNEPS = 1e-5f, SCALEc = 0.125f;  // SD^-0.5

DEVI u16 f2b(float f) {            // f32 -> bf16 RNE
  u32 u = __builtin_bit_cast(u32, f);
  return (u16)((u + 0x7fffu + ((u >> 16) & 1u)) >> 16);
}
DEVI float b2f(u16 s) { return __builtin_bit_cast(float, ((u32)s) << 16); }
DEVI float sigmoidf_(float x) { return 1.f / (1.f + __expf(-x)); }

DEVI void gll16(const void* g, void* l) {   // async 16B/lane global->LDS
  __builtin_amdgcn_global_load_lds(
      (const __attribute__((address_space(1))) u32*)g,
      (__attribute__((address_space(3))) u32*)l, 16, 0, 0);
}

DEVI float dot64(const float* __restrict__ a, const float* __restrict__ w) {
  float s = 0.f;
  #pragma unroll
  for (int i = 0; i < 16; ++i) {
    float4 av = *(const float4*)(a + i * 4);
    float4 wv = *(const float4*)(w + i * 4);
    s += av.x * wv.x + av.y * wv.y + av.z * wv.z + av.w * wv.w;
  }
  return s;
}
// dot of 64 f32 (LDS) with bf16 LDS row j of a 64-col XOR-swizzled image
DEVI float dotL64(const float* __restrict__ x, const u16* __restrict__ wl, int j) {
  float s = 0.f;
  #pragma unroll
  for (int i = 0; i < 8; ++i) {
    short8 wv8 = *(const short8*)((const char*)wl + ((j * 128 + 16 * i) ^ ((j & 7) << 4)));
    #pragma unroll
    for (int e = 0; e < 8; ++e) s += x[i * 8 + e] * b2f((u16)wv8[e]);
  }
  return s;
}
// dot of 128 f32 (LDS) with bf16 LDS row j of a 128-col XOR-swizzled image
DEVI float dotL128(const float* __restrict__ x, const u16* __restrict__ wl, int j) {
  float s = 0.f;
  #pragma unroll
  for (int i = 0; i < 16; ++i) {
    short8 wv8 = *(const short8*)((const char*)wl + ((j * 256 + 16 * i) ^ ((j & 7) << 4)));
    #pragma unroll
    for (int e = 0; e < 8; ++e) s += x[i * 8 + e] * b2f((u16)wv8[e]);
  }
  return s;
}

// LayerNorm of 8 rows x 64 cols living in LDS (256 threads).
DEVI void ln8(const float* src, float* dst, const float* __restrict__ g,
              const float* __restrict__ b, int t) {
  int l = t & 63, w = t >> 6;
  int r = w * 2 + (l >> 5), c = l & 31;
  float x0 = src[r * 64 + c], x1 = src[r * 64 + c + 32];
  float s = x0 + x1, q2 = x0 * x0 + x1 * x1;
  #pragma unroll
  for (int m = 1; m < 32; m <<= 1) { s += __shfl_xor(s, m); q2 += __shfl_xor(q2, m); }
  float mean = s * (1.f / 64.f);
  float rs = rsqrtf(q2 * (1.f / 64.f) - mean * mean + LNEPS);
  dst[r * 64 + c]      = (x0 - mean) * rs * g[c]      + b[c];
  dst[r * 64 + c + 32] = (x1 - mean) * rs * g[c + 32] + b[c + 32];
}

// ---------------------------------------------------------------------------
// K0: blocks 0..271: ALL weights -> bf16 XOR-swizzled images.
//     blocks 272..303: initial slots -> LN -> q into q_ws.
// ---------------------------------------------------------------------------
__global__ __launch_bounds__(256) void k_prep(
    const float* __restrict__ Wp, const float* __restrict__ Wk,
    const float* __restrict__ Wv, const float* __restrict__ W_ih,
    const float* __restrict__ W_hh, const float* __restrict__ W1,
    const float* __restrict__ W2, const float* __restrict__ Wq,
    u16* __restrict__ wp_sw, u16* __restrict__ wk_sw, u16* __restrict__ wv_sw,
    u16* __restrict__ wupd_sw,
    const float* __restrict__ noise, const float* __restrict__ mu,
    const float* __restrict__ ls, const float* __restrict__ gs,
    const float* __restrict__ bs, float* __restrict__ q_ws) {
  const int t = threadIdx.x;
  if (blockIdx.x < 272) {
    int i = blockIdx.x * 256 + t;
    if (i < 16384) {
      wp_sw[i ^ (((i >> 8) & 7) << 3)] = f2b(Wp[i]);
    } else if (i < 20480) {
      int j = i - 16384; wk_sw[j ^ (((j >> 6) & 7) << 3)] = f2b(Wk[j]);
    } else if (i < 24576) {
      int j = i - 20480; wv_sw[j ^ (((j >> 6) & 7) << 3)] = f2b(Wv[j]);
    } else if (i < 36864) {
      int j = i - 24576; wupd_sw[j ^ (((j >> 6) & 7) << 3)] = f2b(W_ih[j]);
    } else if (i < 49152) {
      int j = i - 36864; wupd_sw[12288 + (j ^ (((j >> 6) & 7) << 3))] = f2b(W_hh[j]);
    } else if (i < 57344) {
      int j = i - 49152; wupd_sw[24576 + (j ^ (((j >> 6) & 7) << 3))] = f2b(W1[j]);
    } else if (i < 65536) {
      int j = i - 57344; wupd_sw[32768 + (j ^ (((j >> 7) & 7) << 3))] = f2b(W2[j]);
    } else if (i < 69632) {
      int j = i - 65536; wupd_sw[40960 + (j ^ (((j >> 6) & 7) << 3))] = f2b(Wq[j]);
    }
    return;
  }
  const int b = blockIdx.x - 272;
  __shared__ float sl[512], snl[512];
  for (int i = t; i < 512; i += 256) {
    int d = i & 63;
    sl[i] = mu[d] + __expf(ls[d]) * noise[b * 512 + i];
  }
  __syncthreads();
  ln8(sl, snl, gs, bs, t);
  __syncthreads();
  for (int i = t; i < 512; i += 256)
    q_ws[b * 512 + i] = SCALEc * dot64(snl + (i >> 6) * 64, Wq + (i & 63) * 64);
}

// ---------------------------------------------------------------------------
// K1: proj, 512-thread blocks (8 waves x 16 rows = 128 rows/block, grid 1024).
// Same as R11 EXCEPT epilogue: k/v outputs staged through xn_lds and written
// with coalesced uint4 stores (2+2 per thread) instead of 32 scalar u16.
// k_ws: per-128-row swizzle image; v_ws linear.
// ---------------------------------------------------------------------------
__global__ __launch_bounds__(512) void k_proj_kv(
    const float* __restrict__ in, const float* __restrict__ gpro,
    const float* __restrict__ bpro, const u16* __restrict__ wp_sw,
    const float* __restrict__ bproj, const float* __restrict__ gin,
    const float* __restrict__ bin, const u16* __restrict__ wk_sw,
    const u16* __restrict__ wv_sw, u16* __restrict__ k_ws,
    u16* __restrict__ v_ws) {
  __shared__ __align__(16) u16 wp_lds[64 * 256];    // 32KB
  __shared__ __align__(16) u16 wk_lds[64 * 64];     // 8KB
  __shared__ __align__(16) u16 wv_lds[64 * 64];     // 8KB
  __shared__ __align__(16) u16 xn_lds[128 * 64];    // 16KB (reused as out tile)
  __shared__ float gp_l[256], bp_l[256], bj_l[64], gn_l[64], bn_l[64];

  const int t = threadIdx.x;
  const int l = t & 63, w = t >> 6;          // w in 0..7

  {  // staging: wp 4 instr/wave, wk/wv 1 instr/wave
    #pragma unroll
    for (int i = 0; i < 4; ++i) {
      int off = w * 4096 + i * 1024 + l * 16;
      gll16((const char*)wp_sw + off, (char*)wp_lds + off);
    }
    {
      int off = w * 1024 + l * 16;
      gll16((const char*)wk_sw + off, (char*)wk_lds + off);
      gll16((const char*)wv_sw + off, (char*)wv_lds + off);
    }
  }
  if (t < 256) { gp_l[t] = gpro[t]; bp_l[t] = bpro[t]; }
  if (t < 64) { bj_l[t] = bproj[t]; gn_l[t] = gin[t]; bn_l[t] = bin[t]; }

  const int r16 = l & 15, q4 = l >> 4;
  const long rowbase = (long)blockIdx.x * 128 + w * 16;
  const long grow = rowbase + r16;
  const float* rp = in + grow * 256;

  short8 a[8];
  float sum = 0.f, sq = 0.f;
  #pragma unroll
  for (int ks = 0; ks < 8; ++ks) {
    float4 L0 = *(const float4*)(rp + ks * 32 + q4 * 8);
    float4 L1 = *(const float4*)(rp + ks * 32 + q4 * 8 + 4);
    sum += L0.x + L0.y + L0.z + L0.w + L1.x + L1.y + L1.z + L1.w;
    sq += L0.x * L0.x + L0.y * L0.y + L0.z * L0.z + L0.w * L0.w +
          L1.x * L1.x + L1.y * L1.y + L1.z * L1.z + L1.w * L1.w;
    a[ks][0] = (short)f2b(L0.x); a[ks][1] = (short)f2b(L0.y);
    a[ks][2] = (short)f2b(L0.z); a[ks][3] = (short)f2b(L0.w);
    a[ks][4] = (short)f2b(L1.x); a[ks][5] = (short)f2b(L1.y);
    a[ks][6] = (short)f2b(L1.z); a[ks][7] = (short)f2b(L1.w);
  }
  __syncthreads();  // staging (vmcnt) + smalls complete

  sum += __shfl_xor(sum, 16); sum += __shfl_xor(sum, 32);
  sq  += __shfl_xor(sq, 16);  sq  += __shfl_xor(sq, 32);
  float mean = sum * (1.f / 256.f);
  float rs = rsqrtf(sq * (1.f / 256.f) - mean * mean + LNEPS);
  #pragma unroll
  for (int ks = 0; ks < 8; ++ks) {
    #pragma unroll
    for (int j = 0; j < 8; ++j) {
      int kidx = ks * 32 + q4 * 8 + j;
      float x = b2f((u16)a[ks][j]);
      a[ks][j] = (short)f2b((x - mean) * rs * gp_l[kidx] + bp_l[kidx]);
    }
  }

  f32x4v acc[4];
  #pragma unroll
  for (int nt = 0; nt < 4; ++nt)
    #pragma unroll
    for (int i = 0; i < 4; ++i) acc[nt][i] = 0.f;
  #pragma unroll
  for (int ks = 0; ks < 8; ++ks) {
    #pragma unroll
    for (int nt = 0; nt < 4; ++nt) {
      int n = nt * 16 + r16;
      int byte = (n * 512 + 64 * ks + 16 * q4) ^ ((n & 7) << 4);
      short8 bf = *(const short8*)((const char*)wp_lds + byte);
      acc[nt] = __builtin_amdgcn_mfma_f32_16x16x32_bf16(a[ks], bf, acc[nt], 0, 0, 0);
    }
  }
  #pragma unroll
  for (int nt = 0; nt < 4; ++nt) {
    float bb = bj_l[nt * 16 + r16];
    #pragma unroll
    for (int reg = 0; reg < 4; ++reg) acc[nt][reg] += bb;
  }
  #pragma unroll
  for (int reg = 0; reg < 4; ++reg) {
    float s = acc[0][reg] + acc[1][reg] + acc[2][reg] + acc[3][reg];
    float q2 = acc[0][reg] * acc[0][reg] + acc[1][reg] * acc[1][reg] +
               acc[2][reg] * acc[2][reg] + acc[3][reg] * acc[3][reg];
    #pragma unroll
    for (int m = 1; m < 16; m <<= 1) { s += __shfl_xor(s, m); q2 += __shfl_xor(q2, m); }
    float mn = s * (1.f / 64.f);
    float rr = rsqrtf(q2 * (1.f / 64.f) - mn * mn + LNEPS);
    int row = q4 * 4 + reg;            // 0..15 within wave tile
    int rowg = w * 16 + row;           // 0..127
    #pragma unroll
    for (int nt = 0; nt < 4; ++nt) {
      int col = nt * 16 + r16;
      float y = (acc[nt][reg] - mn) * rr * gn_l[col] + bn_l[col];
      int byte = (rowg * 128 + 2 * col) ^ ((row & 7) << 4);
      *(u16*)((char*)xn_lds + byte) = f2b(y);
    }
  }
  __syncthreads();

  f32x4v kacc[4], vacc[4];
  #pragma unroll
  for (int nt = 0; nt < 4; ++nt)
    #pragma unroll
    for (int i = 0; i < 4; ++i) { kacc[nt][i] = 0.f; vacc[nt][i] = 0.f; }
  #pragma unroll
  for (int ks = 0; ks < 2; ++ks) {
    int rowg2 = w * 16 + r16;
    int abyte = (rowg2 * 128 + 64 * ks + 16 * q4) ^ ((r16 & 7) << 4);
    short8 af = *(const short8*)((const char*)xn_lds + abyte);
    #pragma unroll
    for (int nt = 0; nt < 4; ++nt) {
      int n = nt * 16 + r16;
      int bbyte = (n * 128 + 64 * ks + 16 * q4) ^ ((n & 7) << 4);
      short8 bk = *(const short8*)((const char*)wk_lds + bbyte);
      short8 bv = *(const short8*)((const char*)wv_lds + bbyte);
      kacc[nt] = __builtin_amdgcn_mfma_f32_16x16x32_bf16(af, bk, kacc[nt], 0, 0, 0);
      vacc[nt] = __builtin_amdgcn_mfma_f32_16x16x32_bf16(af, bv, vacc[nt], 0, 0, 0);
    }
  }
  // ---- vectorized epilogue: k (swizzled image) then v (linear), via LDS ----
  // each wave writes only its own 16 rows of xn_lds; xn reads above were also
  // own-wave rows, so in-wave ordering suffices before the barrier.
  #pragma unroll
  for (int nt = 0; nt < 4; ++nt) {
    #pragma unroll
    for (int reg = 0; reg < 4; ++reg) {
      int row = w * 16 + q4 * 4 + reg;     // 0..127
      int col = nt * 16 + r16;
      int idx = (row * 64 + col) ^ ((row & 7) << 3);   // u16 idx, swizzled
      xn_lds[idx] = f2b(kacc[nt][reg]);
    }
  }
  __syncthreads();
  {  // copy 16KB image tile -> k_ws (linear copy preserves swizzle image)
    const uint4* src = (const uint4*)xn_lds;
    uint4* dst = (uint4*)(k_ws + (long)blockIdx.x * 8192);
    dst[t] = src[t];
    dst[t + 512] = src[t + 512];
  }
  __syncthreads();
  #pragma unroll
  for (int nt = 0; nt < 4; ++nt) {
    #pragma unroll
    for (int reg = 0; reg < 4; ++reg) {
      int row = w * 16 + q4 * 4 + reg;
      int col = nt * 16 + r16;
      xn_lds[row * 64 + col] = f2b(vacc[nt][reg]);     // linear
    }
  }
  __syncthreads();
  {  // copy 16KB -> v_ws (linear)
    const uint4* src = (const uint4*)xn_lds;
    uint4* dst = (uint4*)(v_ws + (long)blockIdx.x * 8192);
    dst[t] = src[t];
    dst[t + 512] = src[t + 512];
  }
}

// ---------------------------------------------------------------------------
// K2: pure attention stream. grid (32,32), 128 thr. k AND v staged via gll16
// (38KB LDS -> 4 blocks/CU); PV reads v from LDS (2-way = free).
// ---------------------------------------------------------------------------
__global__ __launch_bounds__(128) void k_attn(
    const float* __restrict__ q_ws, const u16* __restrict__ k_img,
    const u16* __restrict__ v_ws, float* __restrict__ S_part,
    float* __restrict__ U_part) {
  const int bx = blockIdx.x, by = blockIdx.y, t = threadIdx.x;
  const int l = t & 63, w = t >> 6;
  __shared__ __align__(16) u16 k_l[8192];        // 16KB swizzle tile
  __shared__ __align__(16) u16 v_l[8192];        // 16KB linear tile
  __shared__ float ql[512];
  __shared__ __align__(16) float attn_l[1024];
  __shared__ float sred[16];

  {
    const char* ksrc = (const char*)(k_img + ((long)(by * 32 + bx)) * 8192);
    const char* vsrc = (const char*)(v_ws + ((long)(by * 32 + bx)) * 8192);
    #pragma unroll
    for (int i = 0; i < 8; ++i) {
      int off = i * 2048 + t * 16;
      gll16(ksrc + off, (char*)k_l + off);
      gll16(vsrc + off, (char*)v_l + off);
    }
  }
  for (int i = t; i < 512; i += 128) ql[i] = q_ws[by * 512 + i];
  __syncthreads();

  short8 kw8[8];
  #pragma unroll
  for (int j = 0; j < 8; ++j)
    kw8[j] = *(const short8*)((const char*)k_l + ((t * 128 + 16 * j) ^ ((t & 7) << 4)));
  float lg[8];
  #pragma unroll
  for (int i = 0; i < 8; ++i) lg[i] = 0.f;
  #pragma unroll
  for (int c4 = 0; c4 < 16; ++c4) {
    int j = c4 >> 1, e0 = (c4 & 1) * 4;
    float f0 = b2f((u16)kw8[j][e0]);
    float f1 = b2f((u16)kw8[j][e0 + 1]);
    float f2v = b2f((u16)kw8[j][e0 + 2]);
    float f3 = b2f((u16)kw8[j][e0 + 3]);
    #pragma unroll
    for (int kk = 0; kk < 8; ++kk) {
      float4 qv = *(const float4*)(ql + kk * 64 + c4 * 4);
      lg[kk] += qv.x * f0 + qv.y * f1 + qv.z * f2v + qv.w * f3;
    }
  }
  float mx = lg[0];
  #pragma unroll
  for (int kk = 1; kk < 8; ++kk) mx = fmaxf(mx, lg[kk]);
  float e[8], ss = 0.f;
  #pragma unroll
  for (int kk = 0; kk < 8; ++kk) { e[kk] = __expf(lg[kk] - mx); ss += e[kk]; }
  float inv = 1.f / ss;
  #pragma unroll
  for (int kk = 0; kk < 8; ++kk) e[kk] *= inv;
  float4 A0 = {e[0], e[1], e[2], e[3]}, A1 = {e[4], e[5], e[6], e[7]};
  *(float4*)(attn_l + t * 8) = A0;
  *(float4*)(attn_l + t * 8 + 4) = A1;
  __syncthreads();

  float au[8][2];
  #pragma unroll
  for (int i = 0; i < 8; ++i) { au[i][0] = 0.f; au[i][1] = 0.f; }
  const int p = l & 31, g = l >> 5;
  const u32* vl32 = (const u32*)v_l;
  #pragma unroll 8
  for (int nn = 0; nn < 32; ++nn) {
    int n = nn * 2 + g;
    float4 a0 = *(const float4*)(attn_l + (w * 64 + n) * 8);
    float4 a1 = *(const float4*)(attn_l + (w * 64 + n) * 8 + 4);
    u32 vv = vl32[(w * 64 + n) * 32 + p];
    float vlo = b2f((u16)(vv & 0xffff)), vhi = b2f((u16)(vv >> 16));
    au[0][0] += a0.x * vlo; au[0][1] += a0.x * vhi;
    au[1][0] += a0.y * vlo; au[1][1] += a0.y * vhi;
    au[2][0] += a0.z * vlo; au[2][1] += a0.z * vhi;
    au[3][0] += a0.w * vlo; au[3][1] += a0.w * vhi;
    au[4][0] += a1.x * vlo; au[4][1] += a1.x * vhi;
    au[5][0] += a1.y * vlo; au[5][1] += a1.y * vhi;
    au[6][0] += a1.z * vlo; au[6][1] += a1.z * vhi;
    au[7][0] += a1.w * vlo; au[7][1] += a1.w * vhi;
  }
  #pragma unroll
  for (int kk = 0; kk < 8; ++kk) {
    au[kk][0] += __shfl_xor(au[kk][0], 32);
    au[kk][1] += __shfl_xor(au[kk][1], 32);
  }
  float s8[8];
  #pragma unroll
  for (int kk = 0; kk < 8; ++kk) {
    s8[kk] = e[kk];
    #pragma unroll
    for (int m = 1; m < 64; m <<= 1) s8[kk] += __shfl_xor(s8[kk], m);
  }
  __syncthreads();
  float* ured = attn_l;
  if (l < 32) {
    #pragma unroll
    for (int kk = 0; kk < 8; ++kk) {
      ured[w * 512 + kk * 64 + 2 * p]     = au[kk][0];
      ured[w * 512 + kk * 64 + 2 * p + 1] = au[kk][1];
    }
  }
  if (l == 0) {
    #pragma unroll
    for (int kk = 0; kk < 8; ++kk) sred[w * 8 + kk] = s8[kk];
  }
  __syncthreads();
  for (int i = t; i < 512; i += 128)
    U_part[((long)(by * 32 + bx)) * 512 + i] = ured[i] + ured[512 + i];
  if (t < 8)
    S_part[(by * 32 + bx) * 8 + t] = sred[t] + sred[8 + t];
}

// ---------------------------------------------------------------------------
// K3: reduce partials, GRU, MLP -> slots; LN+q -> q_ws. Weight matmuls read
// bf16 XOR-swizzled LDS images staged via gll16. (unchanged from R11)
// ---------------------------------------------------------------------------
__global__ __launch_bounds__(256) void k_update(
    const float* __restrict__ S_part, const float* __restrict__ U_part,
    const float* __restrict__ slots_in, int init_slots,
    const float* __restrict__ noise, const float* __restrict__ mu,
    const float* __restrict__ ls, const u16* __restrict__ wupd_sw,
    const float* __restrict__ b_ih, const float* __restrict__ b_hh,
    const float* __restrict__ gm, const float* __restrict__ bm,
    const float* __restrict__ b1, const float* __restrict__ b2,
    const float* __restrict__ gs, const float* __restrict__ bs,
    float* __restrict__ slots_out, float* __restrict__ q_ws,
    float* __restrict__ out_slots, int write_out) {
  const int b = blockIdx.x, t = threadIdx.x;
  __shared__ __align__(16) u16 wupd[45056];
  __shared__ float u_l[512], sp[512], gi[1536], gh[1536], sn2[512], mi[512],
      h1[1024], Ssum[8];
  const u16* wih_l = wupd;
  const u16* whh_l = wupd + 12288;
  const u16* w1_l  = wupd + 24576;
  const u16* w2_l  = wupd + 32768;
  const u16* wq_l  = wupd + 40960;

  {
    #pragma unroll
    for (int c = 0; c < 22; ++c) {
      int off = c * 4096 + t * 16;
      gll16((const char*)wupd_sw + off, (char*)wupd + off);
    }
  }
  if (t < 8) {
    float s = 0.f;
    #pragma unroll
    for (int ch = 0; ch < 32; ++ch) s += S_part[(b * 32 + ch) * 8 + t];
    Ssum[t] = s;
  }
  for (int i = t; i < 512; i += 256) {
    float v;
    if (init_slots) { int d = i & 63; v = mu[d] + __expf(ls[d]) * noise[b * 512 + i]; }
    else v = slots_in[b * 512 + i];
    sp[i] = v;
  }
  __syncthreads();
  for (int i = t; i < 512; i += 256) {
    float s = 0.f;
    #pragma unroll
    for (int ch = 0; ch < 32; ++ch) s += U_part[((long)(b * 32 + ch)) * 512 + i];
    u_l[i] = s / (Ssum[i >> 6] + EPSc);
  }
  __syncthreads();
  for (int i = t; i < 1536; i += 256) {
    int kk = i / 192, j = i - kk * 192;
    gi[i] = b_ih[j] + dotL64(u_l + kk * 64, wih_l, j);
    gh[i] = b_hh[j] + dotL64(sp + kk * 64, whh_l, j);
  }
  __syncthreads();
  for (int i = t; i < 512; i += 256) {
    int kk = i >> 6, d = i & 63, base = kk * 192;
    float r = sigmoidf_(gi[base + d] + gh[base + d]);
    float z = sigmoidf_(gi[base + 64 + d] + gh[base + 64 + d]);
    float nn = tanhf(gi[base + 128 + d] + r * gh[base + 128 + d]);
    sn2[i] = (1.f - z) * nn + z * sp[i];
  }
  __syncthreads();
  ln8(sn2, mi, gm, bm, t);
  __syncthreads();
  for (int i = t; i < 1024; i += 256) {
    int kk = i >> 7, j = i & 127;
    h1[i] = fmaxf(b1[j] + dotL64(mi + kk * 64, w1_l, j), 0.f);
  }
  __syncthreads();
  for (int i = t; i < 512; i += 256) {
    int kk = i >> 6, d = i & 63;
    float s = sn2[i] + b2[d] + dotL128(h1 + kk * 128, w2_l, d);
    slots_out[b * 512 + i] = s;
    if (write_out) out_slots[b * 512 + i] = s;
    u_l[i] = s;
  }
  __syncthreads();
  ln8(u_l, mi, gs, bs, t);
  __syncthreads();
  for (int i = t; i < 512; i += 256)
    q_ws[b * 512 + i] = SCALEc * dotL64(mi + (i >> 6) * 64, wq_l, i & 63);
}

// ---------------------------------------------------------------------------
// K4: final attention map. grid (32,32), 128 thr. (unchanged from R11)
// ---------------------------------------------------------------------------
__global__ __launch_bounds__(128) void k_final(
    const float* __restrict__ q_ws, const u16* __restrict__ k_img,
    float* __restrict__ outA) {
  const int bx = blockIdx.x, by = blockIdx.y, t = threadIdx.x;
  __shared__ __align__(16) u16 k_l[8192];
  __shared__ float ql[512];
  {
    const char* gsrc = (const char*)(k_img + ((long)(by * 32 + bx)) * 8192);
    #pragma unroll
    for (int i = 0; i < 8; ++i) {
      int off = i * 2048 + t * 16;
      gll16(gsrc + off, (char*)k_l + off);
    }
  }
  for (int i = t; i < 512; i += 128) ql[i] = q_ws[by * 512 + i];
  __syncthreads();
  short8 kw8[8];
  #pragma unroll
  for (int j = 0; j < 8; ++j)
    kw8[j] = *(const short8*)((const char*)k_l + ((t * 128 + 16 * j) ^ ((t & 7) << 4)));
  float lg[8];
  #pragma unroll
  for (int i = 0; i < 8; ++i) lg[i] = 0.f;
  #pragma unroll
  for (int c4 = 0; c4 < 16; ++c4) {
    int j = c4 >> 1, e0 = (c4 & 1) * 4;
    float f0 = b2f((u16)kw8[j][e0]);
    float f1 = b2f((u16)kw8[j][e0 + 1]);
    float f2v = b2f((u16)kw8[j][e0 + 2]);
    float f3 = b2f((u16)kw8[j][e0 + 3]);
    #pragma unroll
    for (int kk = 0; kk < 8; ++kk) {
      float4 qv = *(const float4*)(ql + kk * 64 + c4 * 4);
      lg[kk] += qv.x * f0 + qv.y * f1 + qv.z * f2v + qv.w * f3;
    }
  }
  float mx = lg[0];
  #pragma unroll
  for (int kk = 1; kk < 8; ++kk) mx = fmaxf(mx, lg[kk]);
  float e[8], ss = 0.f;
  #pragma unroll
  for (int kk = 0; kk < 8; ++kk) { e[kk] = __expf(lg[kk] - mx); ss += e[kk]; }
  float inv = 1.f / ss;
  int n = bx * 128 + t;
  #pragma unroll
  for (int kk = 0; kk < 8; ++kk)
    outA[((long)by * 8 + kk) * 4096 + n] = e[kk] * inv;
}

extern "C" void kernel_launch(void* const* d_in, const int* in_sizes, int n_in,
                              void* d_out, int out_size, void* d_ws, size_t ws_size,
                              hipStream_t stream) {
  (void)in_sizes; (void)n_in; (void)out_size; (void)ws_size;
  const float* in    = (const float*)d_in[0];
  const float* noise = (const float*)d_in[1];
  const float* mu    = (const float*)d_in[2];
  const float* ls    = (const float*)d_in[3];
  const float* gpro  = (const float*)d_in[4];
  const float* bpro  = (const float*)d_in[5];
  const float* Wp    = (const float*)d_in[6];
  const float* bproj = (const float*)d_in[7];
  const float* Wq    = (const float*)d_in[8];
  const float* Wk    = (const float*)d_in[9];
  const float* Wv    = (const float*)d_in[10];
  const float* W_ih  = (const float*)d_in[11];
  const float* W_hh  = (const float*)d_in[12];
  const float* b_ih  = (const float*)d_in[13];
  const float* b_hh  = (const float*)d_in[14];
  const float* W1    = (const float*)d_in[15];
  const float* b1    = (const float*)d_in[16];
  const float* W2    = (const float*)d_in[17];
  const float* b2    = (const float*)d_in[18];
  const float* gin   = (const float*)d_in[19];
  const float* bin   = (const float*)d_in[20];
  const float* gs    = (const float*)d_in[21];
  const float* bs    = (const float*)d_in[22];
  const float* gm    = (const float*)d_in[23];
  const float* bm    = (const float*)d_in[24];

  char* ws = (char*)d_ws;
  u16* k_ws      = (u16*)ws;                                   // 16 MiB swizzle image
  u16* v_ws      = (u16*)(ws + 16777216);                      // 16 MiB linear
  float* S_part  = (float*)(ws + 33554432);                    // 32 KiB
  float* U_part  = (float*)(ws + 33554432 + 32768);            // 2 MiB
  float* slots_a = (float*)(ws + 33554432 + 32768 + 2097152);  // 64 KiB
  float* slots_b = (float*)(ws + 33554432 + 32768 + 2097152 + 65536);
  float* q_ws    = (float*)(ws + 33554432 + 32768 + 2097152 + 131072);
  u16* wp_sw     = (u16*)(ws + 33554432 + 32768 + 2097152 + 131072 + 65536);
  u16* wk_sw     = wp_sw + 16384;
  u16* wv_sw     = wk_sw + 4096;
  u16* wupd_sw   = wv_sw + 4096;                               // 45056 u16
  float* out = (float*)d_out;

  k_prep<<<dim3(304), dim3(256), 0, stream>>>(Wp, Wk, Wv, W_ih, W_hh, W1, W2, Wq,
                                              wp_sw, wk_sw, wv_sw, wupd_sw,
                                              noise, mu, ls, gs, bs, q_ws);
  k_proj_kv<<<dim3(1024), dim3(512), 0, stream>>>(in, gpro, bpro, wp_sw, bproj,
                                                  gin, bin, wk_sw, wv_sw, k_ws, v_ws);
  dim3 ga(32, 32), ba(128);
  // iter 0
  k_attn<<<ga, ba, 0, stream>>>(q_ws, k_ws, v_ws, S_part, U_part);
  k_update<<<dim3(32), dim3(256), 0, stream>>>(S_part, U_part, slots_a, 1, noise,
                                               mu, ls, wupd_sw, b_ih, b_hh, gm, bm,
                                               b1, b2, gs, bs, slots_a, q_ws, out, 0);
  // iter 1
  k_attn<<<ga, ba, 0, stream>>>(q_ws, k_ws, v_ws, S_part, U_part);
  k_update<<<dim3(32), dim3(256), 0, stream>>>(S_part, U_part, slots_a, 0, noise,
                                               mu, ls, wupd_sw, b_ih, b_hh, gm, bm,
                                               b1, b2, gs, bs, slots_b, q_ws, out, 0);
  // iter 2 (slots -> d_out)
  k_attn<<<ga, ba, 0, stream>>>(q_ws, k_ws, v_ws, S_part, U_part);
  k_update<<<dim3(32), dim3(256), 0, stream>>>(S_part, U_part, slots_b, 0, noise,
                                               mu, ls, wupd_sw, b_ih, b_hh, gm, bm,
                                               b1, b2, gs, bs, slots_a, q_ws, out, 1);
  // final attention map
  k_final<<<ga, ba, 0, stream>>>(q_ws, k_ws, out + 16384);
}

// Round 13
// 151.882 us; speedup vs baseline: 2.2144x; 1.0139x over previous
//
#include <hip/hip_runtime.h>

typedef unsigned short u16;
typedef unsigned int   u32;
typedef __attribute__((ext_vector_type(8)))  short short8;
typedef __attribute__((ext_vector_type(4)))  float f32x4v;

#define DEVI __device__ __forceinline__

constexpr int   Bb = 32, Nn = 4096, Dd = 256, Kk = 8, SDd = 64, HDd = 128;
constexpr float EPSc = 1e-8f, LNEPS = 1e-5f, SCALEc = 0.125f;  // SD^-0.5

DEVI u16 f2b(float f) {            // f32 -> bf16 RNE
  u32 u = __builtin_bit_cast(u32, f);
  return (u16)((u + 0x7fffu + ((u >> 16) & 1u)) >> 16);
}
DEVI float b2f(u16 s) { return __builtin_bit_cast(float, ((u32)s) << 16); }
DEVI float sigmoidf_(float x) { return 1.f / (1.f + __expf(-x)); }

DEVI void gll16(const void* g, void* l) {   // async 16B/lane global->LDS
  __builtin_amdgcn_global_load_lds(
      (const __attribute__((address_space(1))) u32*)g,
      (__attribute__((address_space(3))) u32*)l, 16, 0, 0);
}

DEVI float dot64(const float* __restrict__ a, const float* __restrict__ w) {
  float s = 0.f;
  #pragma unroll
  for (int i = 0; i < 16; ++i) {
    float4 av = *(const float4*)(a + i * 4);
    float4 wv = *(const float4*)(w + i * 4);
    s += av.x * wv.x + av.y * wv.y + av.z * wv.z + av.w * wv.w;
  }
  return s;
}
// dot of 64 f32 (LDS) with bf16 LDS row j of a 64-col XOR-swizzled image
DEVI float dotL64(const float* __restrict__ x, const u16* __restrict__ wl, int j) {
  float s = 0.f;
  #pragma unroll
  for (int i = 0; i < 8; ++i) {
    short8 wv8 = *(const short8*)((const char*)wl + ((j * 128 + 16 * i) ^ ((j & 7) << 4)));
    #pragma unroll
    for (int e = 0; e < 8; ++e) s += x[i * 8 + e] * b2f((u16)wv8[e]);
  }
  return s;
}
// dot of 128 f32 (LDS) with bf16 LDS row j of a 128-col XOR-swizzled image
DEVI float dotL128(const float* __restrict__ x, const u16* __restrict__ wl, int j) {
  float s = 0.f;
  #pragma unroll
  for (int i = 0; i < 16; ++i) {
    short8 wv8 = *(const short8*)((const char*)wl + ((j * 256 + 16 * i) ^ ((j & 7) << 4)));
    #pragma unroll
    for (int e = 0; e < 8; ++e) s += x[i * 8 + e] * b2f((u16)wv8[e]);
  }
  return s;
}

// LayerNorm of 8 rows x 64 cols living in LDS (256 threads).
DEVI void ln8(const float* src, float* dst, const float* __restrict__ g,
              const float* __restrict__ b, int t) {
  int l = t & 63, w = t >> 6;
  int r = w * 2 + (l >> 5), c = l & 31;
  float x0 = src[r * 64 + c], x1 = src[r * 64 + c + 32];
  float s = x0 + x1, q2 = x0 * x0 + x1 * x1;
  #pragma unroll
  for (int m = 1; m < 32; m <<= 1) { s += __shfl_xor(s, m); q2 += __shfl_xor(q2, m); }
  float mean = s * (1.f / 64.f);
  float rs = rsqrtf(q2 * (1.f / 64.f) - mean * mean + LNEPS);
  dst[r * 64 + c]      = (x0 - mean) * rs * g[c]      + b[c];
  dst[r * 64 + c + 32] = (x1 - mean) * rs * g[c + 32] + b[c + 32];
}

// ---------------------------------------------------------------------------
// K0: weight -> bf16 XOR-swizzled images only (272 blocks).
// ---------------------------------------------------------------------------
__global__ __launch_bounds__(256) void k_prep(
    const float* __restrict__ Wp, const float* __restrict__ Wk,
    const float* __restrict__ Wv, const float* __restrict__ W_ih,
    const float* __restrict__ W_hh, const float* __restrict__ W1,
    const float* __restrict__ W2, const float* __restrict__ Wq,
    u16* __restrict__ wp_sw, u16* __restrict__ wk_sw, u16* __restrict__ wv_sw,
    u16* __restrict__ wupd_sw) {
  const int t = threadIdx.x;
  int i = blockIdx.x * 256 + t;
  if (i < 16384) {
    wp_sw[i ^ (((i >> 8) & 7) << 3)] = f2b(Wp[i]);
  } else if (i < 20480) {
    int j = i - 16384; wk_sw[j ^ (((j >> 6) & 7) << 3)] = f2b(Wk[j]);
  } else if (i < 24576) {
    int j = i - 20480; wv_sw[j ^ (((j >> 6) & 7) << 3)] = f2b(Wv[j]);
  } else if (i < 36864) {
    int j = i - 24576; wupd_sw[j ^ (((j >> 6) & 7) << 3)] = f2b(W_ih[j]);
  } else if (i < 49152) {
    int j = i - 36864; wupd_sw[12288 + (j ^ (((j >> 6) & 7) << 3))] = f2b(W_hh[j]);
  } else if (i < 57344) {
    int j = i - 49152; wupd_sw[24576 + (j ^ (((j >> 6) & 7) << 3))] = f2b(W1[j]);
  } else if (i < 65536) {
    int j = i - 57344; wupd_sw[32768 + (j ^ (((j >> 7) & 7) << 3))] = f2b(W2[j]);
  } else if (i < 69632) {
    int j = i - 65536; wupd_sw[40960 + (j ^ (((j >> 6) & 7) << 3))] = f2b(Wq[j]);
  }
}

// ---------------------------------------------------------------------------
// K1: proj (blocks 0..1023, as R12) + initial-q blocks (1024..1055), which
// stage the wq image from wupd_sw (written in the PREVIOUS launch) and
// compute q0 = LN(init_slots) @ Wq^T * SCALE concurrently with proj.
// ---------------------------------------------------------------------------
__global__ __launch_bounds__(512) void k_proj_kv(
    const float* __restrict__ in, const float* __restrict__ gpro,
    const float* __restrict__ bpro, const u16* __restrict__ wp_sw,
    const float* __restrict__ bproj, const float* __restrict__ gin,
    const float* __restrict__ bin, const u16* __restrict__ wk_sw,
    const u16* __restrict__ wv_sw, u16* __restrict__ k_ws,
    u16* __restrict__ v_ws, const u16* __restrict__ wupd_sw,
    const float* __restrict__ noise, const float* __restrict__ mu,
    const float* __restrict__ ls, const float* __restrict__ gs,
    const float* __restrict__ bs, float* __restrict__ q_ws) {
  __shared__ __align__(16) u16 wp_lds[64 * 256];    // 32KB
  __shared__ __align__(16) u16 wk_lds[64 * 64];     // 8KB (q-init: wq image)
  __shared__ __align__(16) u16 wv_lds[64 * 64];     // 8KB
  __shared__ __align__(16) u16 xn_lds[128 * 64];    // 16KB (q-init: snl)
  __shared__ float gp_l[256], bp_l[256], bj_l[64], gn_l[64], bn_l[64];

  const int t = threadIdx.x;
  const int l = t & 63, w = t >> 6;          // w in 0..7

  if (blockIdx.x >= 1024) {   // ---- initial-q blocks ----
    const int b = (int)blockIdx.x - 1024;
    // stage wq swizzle image (8192 B, 1 instr across 512 lanes)
    gll16((const char*)wupd_sw + 81920 + t * 16, (char*)wk_lds + t * 16);
    const int d = t & 63, row = t >> 6;   // row 0..7 == wave id
    float x = mu[d] + __expf(ls[d]) * noise[b * 512 + t];
    float s = x, q2 = x * x;
    #pragma unroll
    for (int m = 1; m < 64; m <<= 1) { s += __shfl_xor(s, m); q2 += __shfl_xor(q2, m); }
    float mean = s * (1.f / 64.f);
    float rs = rsqrtf(q2 * (1.f / 64.f) - mean * mean + LNEPS);
    float* snl = (float*)xn_lds;
    snl[t] = (x - mean) * rs * gs[d] + bs[d];
    __syncthreads();   // snl ready + wq staged (barrier drains vmcnt)
    q_ws[b * 512 + t] = SCALEc * dotL64(snl + row * 64, wk_lds, d);
    return;
  }

  {  // staging: wp 4 instr/wave, wk/wv 1 instr/wave
    #pragma unroll
    for (int i = 0; i < 4; ++i) {
      int off = w * 4096 + i * 1024 + l * 16;
      gll16((const char*)wp_sw + off, (char*)wp_lds + off);
    }
    {
      int off = w * 1024 + l * 16;
      gll16((const char*)wk_sw + off, (char*)wk_lds + off);
      gll16((const char*)wv_sw + off, (char*)wv_lds + off);
    }
  }
  if (t < 256) { gp_l[t] = gpro[t]; bp_l[t] = bpro[t]; }
  if (t < 64) { bj_l[t] = bproj[t]; gn_l[t] = gin[t]; bn_l[t] = bin[t]; }

  const int r16 = l & 15, q4 = l >> 4;
  const long rowbase = (long)blockIdx.x * 128 + w * 16;
  const long grow = rowbase + r16;
  const float* rp = in + grow * 256;

  short8 a[8];
  float sum = 0.f, sq = 0.f;
  #pragma unroll
  for (int ks = 0; ks < 8; ++ks) {
    float4 L0 = *(const float4*)(rp + ks * 32 + q4 * 8);
    float4 L1 = *(const float4*)(rp + ks * 32 + q4 * 8 + 4);
    sum += L0.x + L0.y + L0.z + L0.w + L1.x + L1.y + L1.z + L1.w;
    sq += L0.x * L0.x + L0.y * L0.y + L0.z * L0.z + L0.w * L0.w +
          L1.x * L1.x + L1.y * L1.y + L1.z * L1.z + L1.w * L1.w;
    a[ks][0] = (short)f2b(L0.x); a[ks][1] = (short)f2b(L0.y);
    a[ks][2] = (short)f2b(L0.z); a[ks][3] = (short)f2b(L0.w);
    a[ks][4] = (short)f2b(L1.x); a[ks][5] = (short)f2b(L1.y);
    a[ks][6] = (short)f2b(L1.z); a[ks][7] = (short)f2b(L1.w);
  }
  __syncthreads();  // staging (vmcnt) + smalls complete

  sum += __shfl_xor(sum, 16); sum += __shfl_xor(sum, 32);
  sq  += __shfl_xor(sq, 16);  sq  += __shfl_xor(sq, 32);
  float mean = sum * (1.f / 256.f);
  float rs = rsqrtf(sq * (1.f / 256.f) - mean * mean + LNEPS);
  #pragma unroll
  for (int ks = 0; ks < 8; ++ks) {
    #pragma unroll
    for (int j = 0; j < 8; ++j) {
      int kidx = ks * 32 + q4 * 8 + j;
      float x = b2f((u16)a[ks][j]);
      a[ks][j] = (short)f2b((x - mean) * rs * gp_l[kidx] + bp_l[kidx]);
    }
  }

  f32x4v acc[4];
  #pragma unroll
  for (int nt = 0; nt < 4; ++nt)
    #pragma unroll
    for (int i = 0; i < 4; ++i) acc[nt][i] = 0.f;
  #pragma unroll
  for (int ks = 0; ks < 8; ++ks) {
    #pragma unroll
    for (int nt = 0; nt < 4; ++nt) {
      int n = nt * 16 + r16;
      int byte = (n * 512 + 64 * ks + 16 * q4) ^ ((n & 7) << 4);
      short8 bf = *(const short8*)((const char*)wp_lds + byte);
      acc[nt] = __builtin_amdgcn_mfma_f32_16x16x32_bf16(a[ks], bf, acc[nt], 0, 0, 0);
    }
  }
  #pragma unroll
  for (int nt = 0; nt < 4; ++nt) {
    float bb = bj_l[nt * 16 + r16];
    #pragma unroll
    for (int reg = 0; reg < 4; ++reg) acc[nt][reg] += bb;
  }
  #pragma unroll
  for (int reg = 0; reg < 4; ++reg) {
    float s = acc[0][reg] + acc[1][reg] + acc[2][reg] + acc[3][reg];
    float q2 = acc[0][reg] * acc[0][reg] + acc[1][reg] * acc[1][reg] +
               acc[2][reg] * acc[2][reg] + acc[3][reg] * acc[3][reg];
    #pragma unroll
    for (int m = 1; m < 16; m <<= 1) { s += __shfl_xor(s, m); q2 += __shfl_xor(q2, m); }
    float mn = s * (1.f / 64.f);
    float rr = rsqrtf(q2 * (1.f / 64.f) - mn * mn + LNEPS);
    int row = q4 * 4 + reg;            // 0..15 within wave tile
    int rowg = w * 16 + row;           // 0..127
    #pragma unroll
    for (int nt = 0; nt < 4; ++nt) {
      int col = nt * 16 + r16;
      float y = (acc[nt][reg] - mn) * rr * gn_l[col] + bn_l[col];
      int byte = (rowg * 128 + 2 * col) ^ ((row & 7) << 4);
      *(u16*)((char*)xn_lds + byte) = f2b(y);
    }
  }
  __syncthreads();

  f32x4v kacc[4], vacc[4];
  #pragma unroll
  for (int nt = 0; nt < 4; ++nt)
    #pragma unroll
    for (int i = 0; i < 4; ++i) { kacc[nt][i] = 0.f; vacc[nt][i] = 0.f; }
  #pragma unroll
  for (int ks = 0; ks < 2; ++ks) {
    int rowg2 = w * 16 + r16;
    int abyte = (rowg2 * 128 + 64 * ks + 16 * q4) ^ ((r16 & 7) << 4);
    short8 af = *(const short8*)((const char*)xn_lds + abyte);
    #pragma unroll
    for (int nt = 0; nt < 4; ++nt) {
      int n = nt * 16 + r16;
      int bbyte = (n * 128 + 64 * ks + 16 * q4) ^ ((n & 7) << 4);
      short8 bk = *(const short8*)((const char*)wk_lds + bbyte);
      short8 bv = *(const short8*)((const char*)wv_lds + bbyte);
      kacc[nt] = __builtin_amdgcn_mfma_f32_16x16x32_bf16(af, bk, kacc[nt], 0, 0, 0);
      vacc[nt] = __builtin_amdgcn_mfma_f32_16x16x32_bf16(af, bv, vacc[nt], 0, 0, 0);
    }
  }
  // ---- vectorized epilogue: k (swizzled image) then v (linear), via LDS ----
  #pragma unroll
  for (int nt = 0; nt < 4; ++nt) {
    #pragma unroll
    for (int reg = 0; reg < 4; ++reg) {
      int row = w * 16 + q4 * 4 + reg;     // 0..127
      int col = nt * 16 + r16;
      int idx = (row * 64 + col) ^ ((row & 7) << 3);   // u16 idx, swizzled
      xn_lds[idx] = f2b(kacc[nt][reg]);
    }
  }
  __syncthreads();
  {  // copy 16KB image tile -> k_ws (linear copy preserves swizzle image)
    const uint4* src = (const uint4*)xn_lds;
    uint4* dst = (uint4*)(k_ws + (long)blockIdx.x * 8192);
    dst[t] = src[t];
    dst[t + 512] = src[t + 512];
  }
  __syncthreads();
  #pragma unroll
  for (int nt = 0; nt < 4; ++nt) {
    #pragma unroll
    for (int reg = 0; reg < 4; ++reg) {
      int row = w * 16 + q4 * 4 + reg;
      int col = nt * 16 + r16;
      xn_lds[row * 64 + col] = f2b(vacc[nt][reg]);     // linear
    }
  }
  __syncthreads();
  {  // copy 16KB -> v_ws (linear)
    const uint4* src = (const uint4*)xn_lds;
    uint4* dst = (uint4*)(v_ws + (long)blockIdx.x * 8192);
    dst[t] = src[t];
    dst[t + 512] = src[t + 512];
  }
}

// ---------------------------------------------------------------------------
// K2: pure attention stream. grid (32,32), 128 thr. k AND v staged via gll16
// (38KB LDS -> 4 blocks/CU); PV reads v from LDS. (unchanged from R12)
// ---------------------------------------------------------------------------
__global__ __launch_bounds__(128) void k_attn(
    const float* __restrict__ q_ws, const u16* __restrict__ k_img,
    const u16* __restrict__ v_ws, float* __restrict__ S_part,
    float* __restrict__ U_part) {
  const int bx = blockIdx.x, by = blockIdx.y, t = threadIdx.x;
  const int l = t & 63, w = t >> 6;
  __shared__ __align__(16) u16 k_l[8192];        // 16KB swizzle tile
  __shared__ __align__(16) u16 v_l[8192];        // 16KB linear tile
  __shared__ float ql[512];
  __shared__ __align__(16) float attn_l[1024];
  __shared__ float sred[16];

  {
    const char* ksrc = (const char*)(k_img + ((long)(by * 32 + bx)) * 8192);
    const char* vsrc = (const char*)(v_ws + ((long)(by * 32 + bx)) * 8192);
    #pragma unroll
    for (int i = 0; i < 8; ++i) {
      int off = i * 2048 + t * 16;
      gll16(ksrc + off, (char*)k_l + off);
      gll16(vsrc + off, (char*)v_l + off);
    }
  }
  for (int i = t; i < 512; i += 128) ql[i] = q_ws[by * 512 + i];
  __syncthreads();

  short8 kw8[8];
  #pragma unroll
  for (int j = 0; j < 8; ++j)
    kw8[j] = *(const short8*)((const char*)k_l + ((t * 128 + 16 * j) ^ ((t & 7) << 4)));
  float lg[8];
  #pragma unroll
  for (int i = 0; i < 8; ++i) lg[i] = 0.f;
  #pragma unroll
  for (int c4 = 0; c4 < 16; ++c4) {
    int j = c4 >> 1, e0 = (c4 & 1) * 4;
    float f0 = b2f((u16)kw8[j][e0]);
    float f1 = b2f((u16)kw8[j][e0 + 1]);
    float f2v = b2f((u16)kw8[j][e0 + 2]);
    float f3 = b2f((u16)kw8[j][e0 + 3]);
    #pragma unroll
    for (int kk = 0; kk < 8; ++kk) {
      float4 qv = *(const float4*)(ql + kk * 64 + c4 * 4);
      lg[kk] += qv.x * f0 + qv.y * f1 + qv.z * f2v + qv.w * f3;
    }
  }
  float mx = lg[0];
  #pragma unroll
  for (int kk = 1; kk < 8; ++kk) mx = fmaxf(mx, lg[kk]);
  float e[8], ss = 0.f;
  #pragma unroll
  for (int kk = 0; kk < 8; ++kk) { e[kk] = __expf(lg[kk] - mx); ss += e[kk]; }
  float inv = 1.f / ss;
  #pragma unroll
  for (int kk = 0; kk < 8; ++kk) e[kk] *= inv;
  float4 A0 = {e[0], e[1], e[2], e[3]}, A1 = {e[4], e[5], e[6], e[7]};
  *(float4*)(attn_l + t * 8) = A0;
  *(float4*)(attn_l + t * 8 + 4) = A1;
  __syncthreads();

  float au[8][2];
  #pragma unroll
  for (int i = 0; i < 8; ++i) { au[i][0] = 0.f; au[i][1] = 0.f; }
  const int p = l & 31, g = l >> 5;
  const u32* vl32 = (const u32*)v_l;
  #pragma unroll 8
  for (int nn = 0; nn < 32; ++nn) {
    int n = nn * 2 + g;
    float4 a0 = *(const float4*)(attn_l + (w * 64 + n) * 8);
    float4 a1 = *(const float4*)(attn_l + (w * 64 + n) * 8 + 4);
    u32 vv = vl32[(w * 64 + n) * 32 + p];
    float vlo = b2f((u16)(vv & 0xffff)), vhi = b2f((u16)(vv >> 16));
    au[0][0] += a0.x * vlo; au[0][1] += a0.x * vhi;
    au[1][0] += a0.y * vlo; au[1][1] += a0.y * vhi;
    au[2][0] += a0.z * vlo; au[2][1] += a0.z * vhi;
    au[3][0] += a0.w * vlo; au[3][1] += a0.w * vhi;
    au[4][0] += a1.x * vlo; au[4][1] += a1.x * vhi;
    au[5][0] += a1.y * vlo; au[5][1] += a1.y * vhi;
    au[6][0] += a1.z * vlo; au[6][1] += a1.z * vhi;
    au[7][0] += a1.w * vlo; au[7][1] += a1.w * vhi;
  }
  #pragma unroll
  for (int kk = 0; kk < 8; ++kk) {
    au[kk][0] += __shfl_xor(au[kk][0], 32);
    au[kk][1] += __shfl_xor(au[kk][1], 32);
  }
  float s8[8];
  #pragma unroll
  for (int kk = 0; kk < 8; ++kk) {
    s8[kk] = e[kk];
    #pragma unroll
    for (int m = 1; m < 64; m <<= 1) s8[kk] += __shfl_xor(s8[kk], m);
  }
  __syncthreads();
  float* ured = attn_l;
  if (l < 32) {
    #pragma unroll
    for (int kk = 0; kk < 8; ++kk) {
      ured[w * 512 + kk * 64 + 2 * p]     = au[kk][0];
      ured[w * 512 + kk * 64 + 2 * p + 1] = au[kk][1];
    }
  }
  if (l == 0) {
    #pragma unroll
    for (int kk = 0; kk < 8; ++kk) sred[w * 8 + kk] = s8[kk];
  }
  __syncthreads();
  for (int i = t; i < 512; i += 128)
    U_part[((long)(by * 32 + bx)) * 512 + i] = ured[i] + ured[512 + i];
  if (t < 8)
    S_part[(by * 32 + bx) * 8 + t] = sred[t] + sred[8 + t];
}

// ---------------------------------------------------------------------------
// K3: reduce partials, GRU, MLP -> slots; LN+q -> q_ws. (unchanged from R12)
// ---------------------------------------------------------------------------
__global__ __launch_bounds__(256) void k_update(
    const float* __restrict__ S_part, const float* __restrict__ U_part,
    const float* __restrict__ slots_in, int init_slots,
    const float* __restrict__ noise, const float* __restrict__ mu,
    const float* __restrict__ ls, const u16* __restrict__ wupd_sw,
    const float* __restrict__ b_ih, const float* __restrict__ b_hh,
    const float* __restrict__ gm, const float* __restrict__ bm,
    const float* __restrict__ b1, const float* __restrict__ b2,
    const float* __restrict__ gs, const float* __restrict__ bs,
    float* __restrict__ slots_out, float* __restrict__ q_ws,
    float* __restrict__ out_slots, int write_out) {
  const int b = blockIdx.x, t = threadIdx.x;
  __shared__ __align__(16) u16 wupd[45056];
  __shared__ float u_l[512], sp[512], gi[1536], gh[1536], sn2[512], mi[512],
      h1[1024], Ssum[8];
  const u16* wih_l = wupd;
  const u16* whh_l = wupd + 12288;
  const u16* w1_l  = wupd + 24576;
  const u16* w2_l  = wupd + 32768;
  const u16* wq_l  = wupd + 40960;

  {
    #pragma unroll
    for (int c = 0; c < 22; ++c) {
      int off = c * 4096 + t * 16;
      gll16((const char*)wupd_sw + off, (char*)wupd + off);
    }
  }
  if (t < 8) {
    float s = 0.f;
    #pragma unroll
    for (int ch = 0; ch < 32; ++ch) s += S_part[(b * 32 + ch) * 8 + t];
    Ssum[t] = s;
  }
  for (int i = t; i < 512; i += 256) {
    float v;
    if (init_slots) { int d = i & 63; v = mu[d] + __expf(ls[d]) * noise[b * 512 + i]; }
    else v = slots_in[b * 512 + i];
    sp[i] = v;
  }
  __syncthreads();
  for (int i = t; i < 512; i += 256) {
    float s = 0.f;
    #pragma unroll
    for (int ch = 0; ch < 32; ++ch) s += U_part[((long)(b * 32 + ch)) * 512 + i];
    u_l[i] = s / (Ssum[i >> 6] + EPSc);
  }
  __syncthreads();
  for (int i = t; i < 1536; i += 256) {
    int kk = i / 192, j = i - kk * 192;
    gi[i] = b_ih[j] + dotL64(u_l + kk * 64, wih_l, j);
    gh[i] = b_hh[j] + dotL64(sp + kk * 64, whh_l, j);
  }
  __syncthreads();
  for (int i = t; i < 512; i += 256) {
    int kk = i >> 6, d = i & 63, base = kk * 192;
    float r = sigmoidf_(gi[base + d] + gh[base + d]);
    float z = sigmoidf_(gi[base + 64 + d] + gh[base + 64 + d]);
    float nn = tanhf(gi[base + 128 + d] + r * gh[base + 128 + d]);
    sn2[i] = (1.f - z) * nn + z * sp[i];
  }
  __syncthreads();
  ln8(sn2, mi, gm, bm, t);
  __syncthreads();
  for (int i = t; i < 1024; i += 256) {
    int kk = i >> 7, j = i & 127;
    h1[i] = fmaxf(b1[j] + dotL64(mi + kk * 64, w1_l, j), 0.f);
  }
  __syncthreads();
  for (int i = t; i < 512; i += 256) {
    int kk = i >> 6, d = i & 63;
    float s = sn2[i] + b2[d] + dotL128(h1 + kk * 128, w2_l, d);
    slots_out[b * 512 + i] = s;
    if (write_out) out_slots[b * 512 + i] = s;
    u_l[i] = s;
  }
  __syncthreads();
  ln8(u_l, mi, gs, bs, t);
  __syncthreads();
  for (int i = t; i < 512; i += 256)
    q_ws[b * 512 + i] = SCALEc * dotL64(mi + (i >> 6) * 64, wq_l, i & 63);
}

// ---------------------------------------------------------------------------
// K4: final attention map. grid (32,32), 128 thr. (unchanged from R12)
// ---------------------------------------------------------------------------
__global__ __launch_bounds__(128) void k_final(
    const float* __restrict__ q_ws, const u16* __restrict__ k_img,
    float* __restrict__ outA) {
  const int bx = blockIdx.x, by = blockIdx.y, t = threadIdx.x;
  __shared__ __align__(16) u16 k_l[8192];
  __shared__ float ql[512];
  {
    const char* gsrc = (const char*)(k_img + ((long)(by * 32 + bx)) * 8192);
    #pragma unroll
    for (int i = 0; i < 8; ++i) {
      int off = i * 2048 + t * 16;
      gll16(gsrc + off, (char*)k_l + off);
    }
  }
  for (int i = t; i < 512; i += 128) ql[i] = q_ws[by * 512 + i];
  __syncthreads();
  short8 kw8[8];
  #pragma unroll
  for (int j = 0; j < 8; ++j)
    kw8[j] = *(const short8*)((const char*)k_l + ((t * 128 + 16 * j) ^ ((t & 7) << 4)));
  float lg[8];
  #pragma unroll
  for (int i = 0; i < 8; ++i) lg[i] = 0.f;
  #pragma unroll
  for (int c4 = 0; c4 < 16; ++c4) {
    int j = c4 >> 1, e0 = (c4 & 1) * 4;
    float f0 = b2f((u16)kw8[j][e0]);
    float f1 = b2f((u16)kw8[j][e0 + 1]);
    float f2v = b2f((u16)kw8[j][e0 + 2]);
    float f3 = b2f((u16)kw8[j][e0 + 3]);
    #pragma unroll
    for (int kk = 0; kk < 8; ++kk) {
      float4 qv = *(const float4*)(ql + kk * 64 + c4 * 4);
      lg[kk] += qv.x * f0 + qv.y * f1 + qv.z * f2v + qv.w * f3;
    }
  }
  float mx = lg[0];
  #pragma unroll
  for (int kk = 1; kk < 8; ++kk) mx = fmaxf(mx, lg[kk]);
  float e[8], ss = 0.f;
  #pragma unroll
  for (int kk = 0; kk < 8; ++kk) { e[kk] = __expf(lg[kk] - mx); ss += e[kk]; }
  float inv = 1.f / ss;
  int n = bx * 128 + t;
  #pragma unroll
  for (int kk = 0; kk < 8; ++kk)
    outA[((long)by * 8 + kk) * 4096 + n] = e[kk] * inv;
}

extern "C" void kernel_launch(void* const* d_in, const int* in_sizes, int n_in,
                              void* d_out, int out_size, void* d_ws, size_t ws_size,
                              hipStream_t stream) {
  (void)in_sizes; (void)n_in; (void)out_size; (void)ws_size;
  const float* in    = (const float*)d_in[0];
  const float* noise = (const float*)d_in[1];
  const float* mu    = (const float*)d_in[2];
  const float* ls    = (const float*)d_in[3];
  const float* gpro  = (const float*)d_in[4];
  const float* bpro  = (const float*)d_in[5];
  const float* Wp    = (const float*)d_in[6];
  const float* bproj = (const float*)d_in[7];
  const float* Wq    = (const float*)d_in[8];
  const float* Wk    = (const float*)d_in[9];
  const float* Wv    = (const float*)d_in[10];
  const float* W_ih  = (const float*)d_in[11];
  const float* W_hh  = (const float*)d_in[12];
  const float* b_ih  = (const float*)d_in[13];
  const float* b_hh  = (const float*)d_in[14];
  const float* W1    = (const float*)d_in[15];
  const float* b1    = (const float*)d_in[16];
  const float* W2    = (const float*)d_in[17];
  const float* b2    = (const float*)d_in[18];
  const float* gin   = (const float*)d_in[19];
  const float* bin   = (const float*)d_in[20];
  const float* gs    = (const float*)d_in[21];
  const float* bs    = (const float*)d_in[22];
  const float* gm    = (const float*)d_in[23];
  const float* bm    = (const float*)d_in[24];

  char* ws = (char*)d_ws;
  u16* k_ws      = (u16*)ws;                                   // 16 MiB swizzle image
  u16* v_ws      = (u16*)(ws + 16777216);                      // 16 MiB linear
  float* S_part  = (float*)(ws + 33554432);                    // 32 KiB
  float* U_part  = (float*)(ws + 33554432 + 32768);            // 2 MiB
  float* slots_a = (float*)(ws + 33554432 + 32768 + 2097152);  // 64 KiB
  float* slots_b = (float*)(ws + 33554432 + 32768 + 2097152 + 65536);
  float* q_ws    = (float*)(ws + 33554432 + 32768 + 2097152 + 131072);
  u16* wp_sw     = (u16*)(ws + 33554432 + 32768 + 2097152 + 131072 + 65536);
  u16* wk_sw     = wp_sw + 16384;
  u16* wv_sw     = wk_sw + 4096;
  u16* wupd_sw   = wv_sw + 4096;                               // 45056 u16
  float* out = (float*)d_out;

  k_prep<<<dim3(272), dim3(256), 0, stream>>>(Wp, Wk, Wv, W_ih, W_hh, W1, W2, Wq,
                                              wp_sw, wk_sw, wv_sw, wupd_sw);
  k_proj_kv<<<dim3(1056), dim3(512), 0, stream>>>(in, gpro, bpro, wp_sw, bproj,
                                                  gin, bin, wk_sw, wv_sw, k_ws, v_ws,
                                                  wupd_sw, noise, mu, ls, gs, bs,
                                                  q_ws);
  dim3 ga(32, 32), ba(128);
  // iter 0
  k_attn<<<ga, ba, 0, stream>>>(q_ws, k_ws, v_ws, S_part, U_part);
  k_update<<<dim3(32), dim3(256), 0, stream>>>(S_part, U_part, slots_a, 1, noise,
                                               mu, ls, wupd_sw, b_ih, b_hh, gm, bm,
                                               b1, b2, gs, bs, slots_a, q_ws, out, 0);
  // iter 1
  k_attn<<<ga, ba, 0, stream>>>(q_ws, k_ws, v_ws, S_part, U_part);
  k_update<<<dim3(32), dim3(256), 0, stream>>>(S_part, U_part, slots_a, 0, noise,
                                               mu, ls, wupd_sw, b_ih, b_hh, gm, bm,
                                               b1, b2, gs, bs, slots_b, q_ws, out, 0);
  // iter 2 (slots -> d_out)
  k_attn<<<ga, ba, 0, stream>>>(q_ws, k_ws, v_ws, S_part, U_part);
  k_update<<<dim3(32), dim3(256), 0, stream>>>(S_part, U_part, slots_b, 0, noise,
                                               mu, ls, wupd_sw, b_ih, b_hh, gm, bm,
                                               b1, b2, gs, bs, slots_a, q_ws, out, 1);
  // final attention map
  k_final<<<ga, ba, 0, stream>>>(q_ws, k_ws, out + 16384);
}

// Round 15
// 150.696 us; speedup vs baseline: 2.2318x; 1.0079x over previous
//
#include <hip/hip_runtime.h>

typedef unsigned short u16;
typedef unsigned int   u32;
typedef __attribute__((ext_vector_type(8)))  short short8;
typedef __attribute__((ext_vector_type(4)))  float f32x4v;
typedef __attribute__((ext_vector_type(4)))  u32   u32x4;

#define DEVI __device__ __forceinline__

constexpr int   Bb = 32, Nn = 4096, Dd = 256, Kk = 8, SDd = 64, HDd = 128;
constexpr float EPSc = 1e-8f, LNEPS = 1e-5f, SCALEc = 0.125f;  // SD^-0.5

DEVI u16 f2b(float f) {            // f32 -> bf16 RNE
  u32 u = __builtin_bit_cast(u32, f);
  return (u16)((u + 0x7fffu + ((u >> 16) & 1u)) >> 16);
}
DEVI float b2f(u16 s) { return __builtin_bit_cast(float, ((u32)s) << 16); }
DEVI float sigmoidf_(float x) { return 1.f / (1.f + __expf(-x)); }
DEVI u32 cvtpk(float lo, float hi) {   // 2x f32 -> packed bf16 (RNE), 1 instr
  u32 r;
  asm("v_cvt_pk_bf16_f32 %0, %1, %2" : "=v"(r) : "v"(lo), "v"(hi));
  return r;
}

DEVI void gll16(const void* g, void* l) {   // async 16B/lane global->LDS
  __builtin_amdgcn_global_load_lds(
      (const __attribute__((address_space(1))) u32*)g,
      (__attribute__((address_space(3))) u32*)l, 16, 0, 0);
}

DEVI float dot64(const float* __restrict__ a, const float* __restrict__ w) {
  float s = 0.f;
  #pragma unroll
  for (int i = 0; i < 16; ++i) {
    float4 av = *(const float4*)(a + i * 4);
    float4 wv = *(const float4*)(w + i * 4);
    s += av.x * wv.x + av.y * wv.y + av.z * wv.z + av.w * wv.w;
  }
  return s;
}
// dot of 64 f32 (LDS) with bf16 LDS row j of a 64-col XOR-swizzled image
DEVI float dotL64(const float* __restrict__ x, const u16* __restrict__ wl, int j) {
  float s = 0.f;
  #pragma unroll
  for (int i = 0; i < 8; ++i) {
    short8 wv8 = *(const short8*)((const char*)wl + ((j * 128 + 16 * i) ^ ((j & 7) << 4)));
    #pragma unroll
    for (int e = 0; e < 8; ++e) s += x[i * 8 + e] * b2f((u16)wv8[e]);
  }
  return s;
}
// dot of 128 f32 (LDS) with bf16 LDS row j of a 128-col XOR-swizzled image
DEVI float dotL128(const float* __restrict__ x, const u16* __restrict__ wl, int j) {
  float s = 0.f;
  #pragma unroll
  for (int i = 0; i < 16; ++i) {
    short8 wv8 = *(const short8*)((const char*)wl + ((j * 256 + 16 * i) ^ ((j & 7) << 4)));
    #pragma unroll
    for (int e = 0; e < 8; ++e) s += x[i * 8 + e] * b2f((u16)wv8[e]);
  }
  return s;
}

// LayerNorm of 8 rows x 64 cols living in LDS (256 threads).
DEVI void ln8(const float* src, float* dst, const float* __restrict__ g,
              const float* __restrict__ b, int t) {
  int l = t & 63, w = t >> 6;
  int r = w * 2 + (l >> 5), c = l & 31;
  float x0 = src[r * 64 + c], x1 = src[r * 64 + c + 32];
  float s = x0 + x1, q2 = x0 * x0 + x1 * x1;
  #pragma unroll
  for (int m = 1; m < 32; m <<= 1) { s += __shfl_xor(s, m); q2 += __shfl_xor(q2, m); }
  float mean = s * (1.f / 64.f);
  float rs = rsqrtf(q2 * (1.f / 64.f) - mean * mean + LNEPS);
  dst[r * 64 + c]      = (x0 - mean) * rs * g[c]      + b[c];
  dst[r * 64 + c + 32] = (x1 - mean) * rs * g[c + 32] + b[c + 32];
}

// ---------------------------------------------------------------------------
// K0: weight -> bf16 XOR-swizzled images only (272 blocks).
// ---------------------------------------------------------------------------
__global__ __launch_bounds__(256) void k_prep(
    const float* __restrict__ Wp, const float* __restrict__ Wk,
    const float* __restrict__ Wv, const float* __restrict__ W_ih,
    const float* __restrict__ W_hh, const float* __restrict__ W1,
    const float* __restrict__ W2, const float* __restrict__ Wq,
    u16* __restrict__ wp_sw, u16* __restrict__ wk_sw, u16* __restrict__ wv_sw,
    u16* __restrict__ wupd_sw) {
  const int t = threadIdx.x;
  int i = blockIdx.x * 256 + t;
  if (i < 16384) {
    wp_sw[i ^ (((i >> 8) & 7) << 3)] = f2b(Wp[i]);
  } else if (i < 20480) {
    int j = i - 16384; wk_sw[j ^ (((j >> 6) & 7) << 3)] = f2b(Wk[j]);
  } else if (i < 24576) {
    int j = i - 20480; wv_sw[j ^ (((j >> 6) & 7) << 3)] = f2b(Wv[j]);
  } else if (i < 36864) {
    int j = i - 24576; wupd_sw[j ^ (((j >> 6) & 7) << 3)] = f2b(W_ih[j]);
  } else if (i < 49152) {
    int j = i - 36864; wupd_sw[12288 + (j ^ (((j >> 6) & 7) << 3))] = f2b(W_hh[j]);
  } else if (i < 57344) {
    int j = i - 49152; wupd_sw[24576 + (j ^ (((j >> 6) & 7) << 3))] = f2b(W1[j]);
  } else if (i < 65536) {
    int j = i - 57344; wupd_sw[32768 + (j ^ (((j >> 7) & 7) << 3))] = f2b(W2[j]);
  } else if (i < 69632) {
    int j = i - 65536; wupd_sw[40960 + (j ^ (((j >> 6) & 7) << 3))] = f2b(Wq[j]);
  }
}

// ---------------------------------------------------------------------------
// K1: proj, 256 thr / 64-row blocks (grid 2048) + 32 initial-q blocks.
// Rows held f32 through LN; bf16 packs via v_cvt_pk_bf16_f32.
// k_ws: per-128-row swizzle image; v_ws linear.
// ---------------------------------------------------------------------------
__global__ __launch_bounds__(256) void k_proj_kv(
    const float* __restrict__ in, const float* __restrict__ gpro,
    const float* __restrict__ bpro, const u16* __restrict__ wp_sw,
    const float* __restrict__ bproj, const float* __restrict__ gin,
    const float* __restrict__ bin, const u16* __restrict__ wk_sw,
    const u16* __restrict__ wv_sw, u16* __restrict__ k_ws,
    u16* __restrict__ v_ws, const u16* __restrict__ wupd_sw,
    const float* __restrict__ noise, const float* __restrict__ mu,
    const float* __restrict__ ls, const float* __restrict__ gs,
    const float* __restrict__ bs, float* __restrict__ q_ws) {
  __shared__ __align__(16) u16 wp_lds[64 * 256];    // 32KB
  __shared__ __align__(16) u16 wk_lds[64 * 64];     // 8KB (q-init: wq image)
  __shared__ __align__(16) u16 wv_lds[64 * 64];     // 8KB
  __shared__ __align__(16) u16 xn_lds[64 * 64];     // 8KB (xn, then out tile)
  __shared__ float gp_l[256], bp_l[256], bj_l[64], gn_l[64], bn_l[64];

  const int t = threadIdx.x, l = t & 63, w = t >> 6;

  if (blockIdx.x >= 2048) {   // ---- initial-q blocks ----
    const int b = (int)blockIdx.x - 2048;
    // stage the full 8192B wq image: two 4096B chunks (BYTE offsets!)
    gll16((const char*)wupd_sw + 81920 + t * 16, (char*)wk_lds + t * 16);
    gll16((const char*)wupd_sw + 81920 + 4096 + t * 16,
          (char*)wk_lds + 4096 + t * 16);
    float* snl = (float*)xn_lds;   // 512 floats
    #pragma unroll
    for (int h = 0; h < 2; ++h) {
      int idx = h * 256 + t, d = idx & 63;
      float x = mu[d] + __expf(ls[d]) * noise[b * 512 + idx];
      float s = x, q2 = x * x;
      #pragma unroll
      for (int m = 1; m < 64; m <<= 1) { s += __shfl_xor(s, m); q2 += __shfl_xor(q2, m); }
      float mean = s * (1.f / 64.f);
      float rs = rsqrtf(q2 * (1.f / 64.f) - mean * mean + LNEPS);
      snl[idx] = (x - mean) * rs * gs[d] + bs[d];
    }
    __syncthreads();   // snl ready + wq staged (barrier drains vmcnt)
    #pragma unroll
    for (int h = 0; h < 2; ++h) {
      int idx = h * 256 + t, d = idx & 63, row = idx >> 6;
      q_ws[b * 512 + idx] = SCALEc * dotL64(snl + row * 64, wk_lds, d);
    }
    return;
  }

  {  // weight staging: wp 8 instr/wave, wk/wv 2 instr/wave
    #pragma unroll
    for (int i = 0; i < 8; ++i) {
      int off = w * 8192 + i * 1024 + l * 16;
      gll16((const char*)wp_sw + off, (char*)wp_lds + off);
    }
    #pragma unroll
    for (int i = 0; i < 2; ++i) {
      int off = w * 2048 + i * 1024 + l * 16;
      gll16((const char*)wk_sw + off, (char*)wk_lds + off);
      gll16((const char*)wv_sw + off, (char*)wv_lds + off);
    }
  }
  gp_l[t] = gpro[t];
  bp_l[t] = bpro[t];
  if (t < 64) { bj_l[t] = bproj[t]; gn_l[t] = gin[t]; bn_l[t] = bin[t]; }

  const int r16 = l & 15, q4 = l >> 4;
  const long rowbase = (long)blockIdx.x * 64 + w * 16;
  const float* rp = in + (rowbase + r16) * 256;

  // ---- Phase A: load rows as f32, stats, LN via fma, pack via cvt_pk ----
  float4 x0[8], x1[8];
  float sum = 0.f, sq = 0.f;
  #pragma unroll
  for (int ks = 0; ks < 8; ++ks) {
    x0[ks] = *(const float4*)(rp + ks * 32 + q4 * 8);
    x1[ks] = *(const float4*)(rp + ks * 32 + q4 * 8 + 4);
    sum += x0[ks].x + x0[ks].y + x0[ks].z + x0[ks].w +
           x1[ks].x + x1[ks].y + x1[ks].z + x1[ks].w;
    sq += x0[ks].x * x0[ks].x + x0[ks].y * x0[ks].y + x0[ks].z * x0[ks].z +
          x0[ks].w * x0[ks].w + x1[ks].x * x1[ks].x + x1[ks].y * x1[ks].y +
          x1[ks].z * x1[ks].z + x1[ks].w * x1[ks].w;
  }
  __syncthreads();  // staging (vmcnt) + smalls complete

  sum += __shfl_xor(sum, 16); sum += __shfl_xor(sum, 32);
  sq  += __shfl_xor(sq, 16);  sq  += __shfl_xor(sq, 32);
  float mean = sum * (1.f / 256.f);
  float rs = rsqrtf(sq * (1.f / 256.f) - mean * mean + LNEPS);

  short8 a[8];
  #pragma unroll
  for (int ks = 0; ks < 8; ++ks) {
    int kb = ks * 32 + q4 * 8;
    float n0 = (x0[ks].x - mean) * rs * gp_l[kb + 0] + bp_l[kb + 0];
    float n1 = (x0[ks].y - mean) * rs * gp_l[kb + 1] + bp_l[kb + 1];
    float n2 = (x0[ks].z - mean) * rs * gp_l[kb + 2] + bp_l[kb + 2];
    float n3 = (x0[ks].w - mean) * rs * gp_l[kb + 3] + bp_l[kb + 3];
    float n4 = (x1[ks].x - mean) * rs * gp_l[kb + 4] + bp_l[kb + 4];
    float n5 = (x1[ks].y - mean) * rs * gp_l[kb + 5] + bp_l[kb + 5];
    float n6 = (x1[ks].z - mean) * rs * gp_l[kb + 6] + bp_l[kb + 6];
    float n7 = (x1[ks].w - mean) * rs * gp_l[kb + 7] + bp_l[kb + 7];
    u32x4 pv;
    pv.x = cvtpk(n0, n1); pv.y = cvtpk(n2, n3);
    pv.z = cvtpk(n4, n5); pv.w = cvtpk(n6, n7);
    a[ks] = __builtin_bit_cast(short8, pv);
  }

  // ---- Phase B: proj GEMM (16 rows x 64 cols, K=256) ----
  f32x4v acc[4];
  #pragma unroll
  for (int nt = 0; nt < 4; ++nt)
    #pragma unroll
    for (int i = 0; i < 4; ++i) acc[nt][i] = 0.f;
  #pragma unroll
  for (int ks = 0; ks < 8; ++ks) {
    #pragma unroll
    for (int nt = 0; nt < 4; ++nt) {
      int n = nt * 16 + r16;
      int byte = (n * 512 + 64 * ks + 16 * q4) ^ ((n & 7) << 4);
      short8 bf = *(const short8*)((const char*)wp_lds + byte);
      acc[nt] = __builtin_amdgcn_mfma_f32_16x16x32_bf16(a[ks], bf, acc[nt], 0, 0, 0);
    }
  }
  #pragma unroll
  for (int nt = 0; nt < 4; ++nt) {
    float bb = bj_l[nt * 16 + r16];
    #pragma unroll
    for (int reg = 0; reg < 4; ++reg) acc[nt][reg] += bb;
  }
  // ---- Phase C: LN(64) per output row -> swizzled xn ----
  #pragma unroll
  for (int reg = 0; reg < 4; ++reg) {
    float s = acc[0][reg] + acc[1][reg] + acc[2][reg] + acc[3][reg];
    float q2 = acc[0][reg] * acc[0][reg] + acc[1][reg] * acc[1][reg] +
               acc[2][reg] * acc[2][reg] + acc[3][reg] * acc[3][reg];
    #pragma unroll
    for (int m = 1; m < 16; m <<= 1) { s += __shfl_xor(s, m); q2 += __shfl_xor(q2, m); }
    float mn = s * (1.f / 64.f);
    float rr = rsqrtf(q2 * (1.f / 64.f) - mn * mn + LNEPS);
    int row = q4 * 4 + reg;
    int rowg = w * 16 + row;
    #pragma unroll
    for (int nt = 0; nt < 4; ++nt) {
      int col = nt * 16 + r16;
      float y = (acc[nt][reg] - mn) * rr * gn_l[col] + bn_l[col];
      int byte = (rowg * 128 + 2 * col) ^ ((row & 7) << 4);
      *(u16*)((char*)xn_lds + byte) = f2b(y);
    }
  }
  __syncthreads();

  // ---- Phase D: k,v GEMMs (K=64) ----
  f32x4v kacc[4], vacc[4];
  #pragma unroll
  for (int nt = 0; nt < 4; ++nt)
    #pragma unroll
    for (int i = 0; i < 4; ++i) { kacc[nt][i] = 0.f; vacc[nt][i] = 0.f; }
  #pragma unroll
  for (int ks = 0; ks < 2; ++ks) {
    int rowg2 = w * 16 + r16;
    int abyte = (rowg2 * 128 + 64 * ks + 16 * q4) ^ ((r16 & 7) << 4);
    short8 af = *(const short8*)((const char*)xn_lds + abyte);
    #pragma unroll
    for (int nt = 0; nt < 4; ++nt) {
      int n = nt * 16 + r16;
      int bbyte = (n * 128 + 64 * ks + 16 * q4) ^ ((n & 7) << 4);
      short8 bk = *(const short8*)((const char*)wk_lds + bbyte);
      short8 bv = *(const short8*)((const char*)wv_lds + bbyte);
      kacc[nt] = __builtin_amdgcn_mfma_f32_16x16x32_bf16(af, bk, kacc[nt], 0, 0, 0);
      vacc[nt] = __builtin_amdgcn_mfma_f32_16x16x32_bf16(af, bv, vacc[nt], 0, 0, 0);
    }
  }
  // ---- vectorized epilogue via LDS: k image slice then v linear slice ----
  // 64-row block = half of a 128-row image tile; global u16 index =
  // tile*8192 + 4096*(blk&1) + local == blk*4096 + local (low 3 row bits
  // unaffected by the 64-row offset, so the local swizzle matches).
  __syncthreads();
  #pragma unroll
  for (int nt = 0; nt < 4; ++nt) {
    #pragma unroll
    for (int reg = 0; reg < 4; ++reg) {
      int row = w * 16 + q4 * 4 + reg;     // 0..63
      int col = nt * 16 + r16;
      int idx = (row * 64 + col) ^ ((row & 7) << 3);
      xn_lds[idx] = f2b(kacc[nt][reg]);
    }
  }
  __syncthreads();
  {  // copy 8KB image slice -> k_ws
    const uint4* src = (const uint4*)xn_lds;
    uint4* dst = (uint4*)(k_ws + (long)blockIdx.x * 4096);
    dst[t] = src[t];
    dst[t + 256] = src[t + 256];
  }
  __syncthreads();
  #pragma unroll
  for (int nt = 0; nt < 4; ++nt) {
    #pragma unroll
    for (int reg = 0; reg < 4; ++reg) {
      int row = w * 16 + q4 * 4 + reg;
      int col = nt * 16 + r16;
      xn_lds[row * 64 + col] = f2b(vacc[nt][reg]);     // linear
    }
  }
  __syncthreads();
  {  // copy 8KB -> v_ws (linear)
    const uint4* src = (const uint4*)xn_lds;
    uint4* dst = (uint4*)(v_ws + (long)blockIdx.x * 4096);
    dst[t] = src[t];
    dst[t + 256] = src[t + 256];
  }
}

// ---------------------------------------------------------------------------
// K2: pure attention stream. grid (32,32), 128 thr. k AND v staged via gll16
// (38KB LDS -> 4 blocks/CU); PV reads v from LDS. (unchanged from R13)
// ---------------------------------------------------------------------------
__global__ __launch_bounds__(128) void k_attn(
    const float* __restrict__ q_ws, const u16* __restrict__ k_img,
    const u16* __restrict__ v_ws, float* __restrict__ S_part,
    float* __restrict__ U_part) {
  const int bx = blockIdx.x, by = blockIdx.y, t = threadIdx.x;
  const int l = t & 63, w = t >> 6;
  __shared__ __align__(16) u16 k_l[8192];        // 16KB swizzle tile
  __shared__ __align__(16) u16 v_l[8192];        // 16KB linear tile
  __shared__ float ql[512];
  __shared__ __align__(16) float attn_l[1024];
  __shared__ float sred[16];

  {
    const char* ksrc = (const char*)(k_img + ((long)(by * 32 + bx)) * 8192);
    const char* vsrc = (const char*)(v_ws + ((long)(by * 32 + bx)) * 8192);
    #pragma unroll
    for (int i = 0; i < 8; ++i) {
      int off = i * 2048 + t * 16;
      gll16(ksrc + off, (char*)k_l + off);
      gll16(vsrc + off, (char*)v_l + off);
    }
  }
  for (int i = t; i < 512; i += 128) ql[i] = q_ws[by * 512 + i];
  __syncthreads();

  short8 kw8[8];
  #pragma unroll
  for (int j = 0; j < 8; ++j)
    kw8[j] = *(const short8*)((const char*)k_l + ((t * 128 + 16 * j) ^ ((t & 7) << 4)));
  float lg[8];
  #pragma unroll
  for (int i = 0; i < 8; ++i) lg[i] = 0.f;
  #pragma unroll
  for (int c4 = 0; c4 < 16; ++c4) {
    int j = c4 >> 1, e0 = (c4 & 1) * 4;
    float f0 = b2f((u16)kw8[j][e0]);
    float f1 = b2f((u16)kw8[j][e0 + 1]);
    float f2v = b2f((u16)kw8[j][e0 + 2]);
    float f3 = b2f((u16)kw8[j][e0 + 3]);
    #pragma unroll
    for (int kk = 0; kk < 8; ++kk) {
      float4 qv = *(const float4*)(ql + kk * 64 + c4 * 4);
      lg[kk] += qv.x * f0 + qv.y * f1 + qv.z * f2v + qv.w * f3;
    }
  }
  float mx = lg[0];
  #pragma unroll
  for (int kk = 1; kk < 8; ++kk) mx = fmaxf(mx, lg[kk]);
  float e[8], ss = 0.f;
  #pragma unroll
  for (int kk = 0; kk < 8; ++kk) { e[kk] = __expf(lg[kk] - mx); ss += e[kk]; }
  float inv = 1.f / ss;
  #pragma unroll
  for (int kk = 0; kk < 8; ++kk) e[kk] *= inv;
  float4 A0 = {e[0], e[1], e[2], e[3]}, A1 = {e[4], e[5], e[6], e[7]};
  *(float4*)(attn_l + t * 8) = A0;
  *(float4*)(attn_l + t * 8 + 4) = A1;
  __syncthreads();

  float au[8][2];
  #pragma unroll
  for (int i = 0; i < 8; ++i) { au[i][0] = 0.f; au[i][1] = 0.f; }
  const int p = l & 31, g = l >> 5;
  const u32* vl32 = (const u32*)v_l;
  #pragma unroll 8
  for (int nn = 0; nn < 32; ++nn) {
    int n = nn * 2 + g;
    float4 a0 = *(const float4*)(attn_l + (w * 64 + n) * 8);
    float4 a1 = *(const float4*)(attn_l + (w * 64 + n) * 8 + 4);
    u32 vv = vl32[(w * 64 + n) * 32 + p];
    float vlo = b2f((u16)(vv & 0xffff)), vhi = b2f((u16)(vv >> 16));
    au[0][0] += a0.x * vlo; au[0][1] += a0.x * vhi;
    au[1][0] += a0.y * vlo; au[1][1] += a0.y * vhi;
    au[2][0] += a0.z * vlo; au[2][1] += a0.z * vhi;
    au[3][0] += a0.w * vlo; au[3][1] += a0.w * vhi;
    au[4][0] += a1.x * vlo; au[4][1] += a1.x * vhi;
    au[5][0] += a1.y * vlo; au[5][1] += a1.y * vhi;
    au[6][0] += a1.z * vlo; au[6][1] += a1.z * vhi;
    au[7][0] += a1.w * vlo; au[7][1] += a1.w * vhi;
  }
  #pragma unroll
  for (int kk = 0; kk < 8; ++kk) {
    au[kk][0] += __shfl_xor(au[kk][0], 32);
    au[kk][1] += __shfl_xor(au[kk][1], 32);
  }
  float s8[8];
  #pragma unroll
  for (int kk = 0; kk < 8; ++kk) {
    s8[kk] = e[kk];
    #pragma unroll
    for (int m = 1; m < 64; m <<= 1) s8[kk] += __shfl_xor(s8[kk], m);
  }
  __syncthreads();
  float* ured = attn_l;
  if (l < 32) {
    #pragma unroll
    for (int kk = 0; kk < 8; ++kk) {
      ured[w * 512 + kk * 64 + 2 * p]     = au[kk][0];
      ured[w * 512 + kk * 64 + 2 * p + 1] = au[kk][1];
    }
  }
  if (l == 0) {
    #pragma unroll
    for (int kk = 0; kk < 8; ++kk) sred[w * 8 + kk] = s8[kk];
  }
  __syncthreads();
  for (int i = t; i < 512; i += 128)
    U_part[((long)(by * 32 + bx)) * 512 + i] = ured[i] + ured[512 + i];
  if (t < 8)
    S_part[(by * 32 + bx) * 8 + t] = sred[t] + sred[8 + t];
}

// ---------------------------------------------------------------------------
// K3: reduce partials, GRU, MLP -> slots; LN+q -> q_ws. (unchanged from R13)
// ---------------------------------------------------------------------------
__global__ __launch_bounds__(256) void k_update(
    const float* __restrict__ S_part, const float* __restrict__ U_part,
    const float* __restrict__ slots_in, int init_slots,
    const float* __restrict__ noise, const float* __restrict__ mu,
    const float* __restrict__ ls, const u16* __restrict__ wupd_sw,
    const float* __restrict__ b_ih, const float* __restrict__ b_hh,
    const float* __restrict__ gm, const float* __restrict__ bm,
    const float* __restrict__ b1, const float* __restrict__ b2,
    const float* __restrict__ gs, const float* __restrict__ bs,
    float* __restrict__ slots_out, float* __restrict__ q_ws,
    float* __restrict__ out_slots, int write_out) {
  const int b = blockIdx.x, t = threadIdx.x;
  __shared__ __align__(16) u16 wupd[45056];
  __shared__ float u_l[512], sp[512], gi[1536], gh[1536], sn2[512], mi[512],
      h1[1024], Ssum[8];
  const u16* wih_l = wupd;
  const u16* whh_l = wupd + 12288;
  const u16* w1_l  = wupd + 24576;
  const u16* w2_l  = wupd + 32768;
  const u16* wq_l  = wupd + 40960;

  {
    #pragma unroll
    for (int c = 0; c < 22; ++c) {
      int off = c * 4096 + t * 16;
      gll16((const char*)wupd_sw + off, (char*)wupd + off);
    }
  }
  if (t < 8) {
    float s = 0.f;
    #pragma unroll
    for (int ch = 0; ch < 32; ++ch) s += S_part[(b * 32 + ch) * 8 + t];
    Ssum[t] = s;
  }
  for (int i = t; i < 512; i += 256) {
    float v;
    if (init_slots) { int d = i & 63; v = mu[d] + __expf(ls[d]) * noise[b * 512 + i]; }
    else v = slots_in[b * 512 + i];
    sp[i] = v;
  }
  __syncthreads();
  for (int i = t; i < 512; i += 256) {
    float s = 0.f;
    #pragma unroll
    for (int ch = 0; ch < 32; ++ch) s += U_part[((long)(b * 32 + ch)) * 512 + i];
    u_l[i] = s / (Ssum[i >> 6] + EPSc);
  }
  __syncthreads();
  for (int i = t; i < 1536; i += 256) {
    int kk = i / 192, j = i - kk * 192;
    gi[i] = b_ih[j] + dotL64(u_l + kk * 64, wih_l, j);
    gh[i] = b_hh[j] + dotL64(sp + kk * 64, whh_l, j);
  }
  __syncthreads();
  for (int i = t; i < 512; i += 256) {
    int kk = i >> 6, d = i & 63, base = kk * 192;
    float r = sigmoidf_(gi[base + d] + gh[base + d]);
    float z = sigmoidf_(gi[base + 64 + d] + gh[base + 64 + d]);
    float nn = tanhf(gi[base + 128 + d] + r * gh[base + 128 + d]);
    sn2[i] = (1.f - z) * nn + z * sp[i];
  }
  __syncthreads();
  ln8(sn2, mi, gm, bm, t);
  __syncthreads();
  for (int i = t; i < 1024; i += 256) {
    int kk = i >> 7, j = i & 127;
    h1[i] = fmaxf(b1[j] + dotL64(mi + kk * 64, w1_l, j), 0.f);
  }
  __syncthreads();
  for (int i = t; i < 512; i += 256) {
    int kk = i >> 6, d = i & 63;
    float s = sn2[i] + b2[d] + dotL128(h1 + kk * 128, w2_l, d);
    slots_out[b * 512 + i] = s;
    if (write_out) out_slots[b * 512 + i] = s;
    u_l[i] = s;
  }
  __syncthreads();
  ln8(u_l, mi, gs, bs, t);
  __syncthreads();
  for (int i = t; i < 512; i += 256)
    q_ws[b * 512 + i] = SCALEc * dotL64(mi + (i >> 6) * 64, wq_l, i & 63);
}

// ---------------------------------------------------------------------------
// K4: final attention map. grid (32,32), 128 thr. (unchanged from R13)
// ---------------------------------------------------------------------------
__global__ __launch_bounds__(128) void k_final(
    const float* __restrict__ q_ws, const u16* __restrict__ k_img,
    float* __restrict__ outA) {
  const int bx = blockIdx.x, by = blockIdx.y, t = threadIdx.x;
  __shared__ __align__(16) u16 k_l[8192];
  __shared__ float ql[512];
  {
    const char* gsrc = (const char*)(k_img + ((long)(by * 32 + bx)) * 8192);
    #pragma unroll
    for (int i = 0; i < 8; ++i) {
      int off = i * 2048 + t * 16;
      gll16(gsrc + off, (char*)k_l + off);
    }
  }
  for (int i = t; i < 512; i += 128) ql[i] = q_ws[by * 512 + i];
  __syncthreads();
  short8 kw8[8];
  #pragma unroll
  for (int j = 0; j < 8; ++j)
    kw8[j] = *(const short8*)((const char*)k_l + ((t * 128 + 16 * j) ^ ((t & 7) << 4)));
  float lg[8];
  #pragma unroll
  for (int i = 0; i < 8; ++i) lg[i] = 0.f;
  #pragma unroll
  for (int c4 = 0; c4 < 16; ++c4) {
    int j = c4 >> 1, e0 = (c4 & 1) * 4;
    float f0 = b2f((u16)kw8[j][e0]);
    float f1 = b2f((u16)kw8[j][e0 + 1]);
    float f2v = b2f((u16)kw8[j][e0 + 2]);
    float f3 = b2f((u16)kw8[j][e0 + 3]);
    #pragma unroll
    for (int kk = 0; kk < 8; ++kk) {
      float4 qv = *(const float4*)(ql + kk * 64 + c4 * 4);
      lg[kk] += qv.x * f0 + qv.y * f1 + qv.z * f2v + qv.w * f3;
    }
  }
  float mx = lg[0];
  #pragma unroll
  for (int kk = 1; kk < 8; ++kk) mx = fmaxf(mx, lg[kk]);
  float e[8], ss = 0.f;
  #pragma unroll
  for (int kk = 0; kk < 8; ++kk) { e[kk] = __expf(lg[kk] - mx); ss += e[kk]; }
  float inv = 1.f / ss;
  int n = bx * 128 + t;
  #pragma unroll
  for (int kk = 0; kk < 8; ++kk)
    outA[((long)by * 8 + kk) * 4096 + n] = e[kk] * inv;
}

extern "C" void kernel_launch(void* const* d_in, const int* in_sizes, int n_in,
                              void* d_out, int out_size, void* d_ws, size_t ws_size,
                              hipStream_t stream) {
  (void)in_sizes; (void)n_in; (void)out_size; (void)ws_size;
  const float* in    = (const float*)d_in[0];
  const float* noise = (const float*)d_in[1];
  const float* mu    = (const float*)d_in[2];
  const float* ls    = (const float*)d_in[3];
  const float* gpro  = (const float*)d_in[4];
  const float* bpro  = (const float*)d_in[5];
  const float* Wp    = (const float*)d_in[6];
  const float* bproj = (const float*)d_in[7];
  const float* Wq    = (const float*)d_in[8];
  const float* Wk    = (const float*)d_in[9];
  const float* Wv    = (const float*)d_in[10];
  const float* W_ih  = (const float*)d_in[11];
  const float* W_hh  = (const float*)d_in[12];
  const float* b_ih  = (const float*)d_in[13];
  const float* b_hh  = (const float*)d_in[14];
  const float* W1    = (const float*)d_in[15];
  const float* b1    = (const float*)d_in[16];
  const float* W2    = (const float*)d_in[17];
  const float* b2    = (const float*)d_in[18];
  const float* gin   = (const float*)d_in[19];
  const float* bin   = (const float*)d_in[20];
  const float* gs    = (const float*)d_in[21];
  const float* bs    = (const float*)d_in[22];
  const float* gm    = (const float*)d_in[23];
  const float* bm    = (const float*)d_in[24];

  char* ws = (char*)d_ws;
  u16* k_ws      = (u16*)ws;                                   // 16 MiB swizzle image
  u16* v_ws      = (u16*)(ws + 16777216);                      // 16 MiB linear
  float* S_part  = (float*)(ws + 33554432);                    // 32 KiB
  float* U_part  = (float*)(ws + 33554432 + 32768);            // 2 MiB
  float* slots_a = (float*)(ws + 33554432 + 32768 + 2097152);  // 64 KiB
  float* slots_b = (float*)(ws + 33554432 + 32768 + 2097152 + 65536);
  float* q_ws    = (float*)(ws + 33554432 + 32768 + 2097152 + 131072);
  u16* wp_sw     = (u16*)(ws + 33554432 + 32768 + 2097152 + 131072 + 65536);
  u16* wk_sw     = wp_sw + 16384;
  u16* wv_sw     = wk_sw + 4096;
  u16* wupd_sw   = wv_sw + 4096;                               // 45056 u16
  float* out = (float*)d_out;

  k_prep<<<dim3(272), dim3(256), 0, stream>>>(Wp, Wk, Wv, W_ih, W_hh, W1, W2, Wq,
                                              wp_sw, wk_sw, wv_sw, wupd_sw);
  k_proj_kv<<<dim3(2080), dim3(256), 0, stream>>>(in, gpro, bpro, wp_sw, bproj,
                                                  gin, bin, wk_sw, wv_sw, k_ws, v_ws,
                                                  wupd_sw, noise, mu, ls, gs, bs,
                                                  q_ws);
  dim3 ga(32, 32), ba(128);
  // iter 0
  k_attn<<<ga, ba, 0, stream>>>(q_ws, k_ws, v_ws, S_part, U_part);
  k_update<<<dim3(32), dim3(256), 0, stream>>>(S_part, U_part, slots_a, 1, noise,
                                               mu, ls, wupd_sw, b_ih, b_hh, gm, bm,
                                               b1, b2, gs, bs, slots_a, q_ws, out, 0);
  // iter 1
  k_attn<<<ga, ba, 0, stream>>>(q_ws, k_ws, v_ws, S_part, U_part);
  k_update<<<dim3(32), dim3(256), 0, stream>>>(S_part, U_part, slots_a, 0, noise,
                                               mu, ls, wupd_sw, b_ih, b_hh, gm, bm,
                                               b1, b2, gs, bs, slots_b, q_ws, out, 0);
  // iter 2 (slots -> d_out)
  k_attn<<<ga, ba, 0, stream>>>(q_ws, k_ws, v_ws, S_part, U_part);
  k_update<<<dim3(32), dim3(256), 0, stream>>>(S_part, U_part, slots_b, 0, noise,
                                               mu, ls, wupd_sw, b_ih, b_hh, gm, bm,
                                               b1, b2, gs, bs, slots_a, q_ws, out, 1);
  // final attention map
  k_final<<<ga, ba, 0, stream>>>(q_ws, k_ws, out + 16384);
}

// Round 16
// 150.119 us; speedup vs baseline: 2.2404x; 1.0038x over previous
//
#include <hip/hip_runtime.h>

typedef unsigned short u16;
typedef unsigned int   u32;
typedef __attribute__((ext_vector_type(8)))  short short8;
typedef __attribute__((ext_vector_type(4)))  float f32x4v;
typedef __attribute__((ext_vector_type(4)))  u32   u32x4;

#define DEVI __device__ __forceinline__

constexpr int   Bb = 32, Nn = 4096, Dd = 256, Kk = 8, SDd = 64, HDd = 128;
constexpr float EPSc = 1e-8f, LNEPS = 1e-5f, SCALEc = 0.125f;  // SD^-0.5

DEVI u16 f2b(float f) {            // f32 -> bf16 RNE
  u32 u = __builtin_bit_cast(u32, f);
  return (u16)((u + 0x7fffu + ((u >> 16) & 1u)) >> 16);
}
DEVI float b2f(u16 s) { return __builtin_bit_cast(float, ((u32)s) << 16); }
DEVI float sigmoidf_(float x) { return 1.f / (1.f + __expf(-x)); }
DEVI u32 cvtpk(float lo, float hi) {   // 2x f32 -> packed bf16 (RNE), 1 instr
  u32 r;
  asm("v_cvt_pk_bf16_f32 %0, %1, %2" : "=v"(r) : "v"(lo), "v"(hi));
  return r;
}

DEVI void gll16(const void* g, void* l) {   // async 16B/lane global->LDS
  __builtin_amdgcn_global_load_lds(
      (const __attribute__((address_space(1))) u32*)g,
      (__attribute__((address_space(3))) u32*)l, 16, 0, 0);
}

DEVI float dot64(const float* __restrict__ a, const float* __restrict__ w) {
  float s = 0.f;
  #pragma unroll
  for (int i = 0; i < 16; ++i) {
    float4 av = *(const float4*)(a + i * 4);
    float4 wv = *(const float4*)(w + i * 4);
    s += av.x * wv.x + av.y * wv.y + av.z * wv.z + av.w * wv.w;
  }
  return s;
}
// dot of 64 f32 (LDS) with bf16 LDS row j of a 64-col XOR-swizzled image
DEVI float dotL64(const float* __restrict__ x, const u16* __restrict__ wl, int j) {
  float s = 0.f;
  #pragma unroll
  for (int i = 0; i < 8; ++i) {
    short8 wv8 = *(const short8*)((const char*)wl + ((j * 128 + 16 * i) ^ ((j & 7) << 4)));
    #pragma unroll
    for (int e = 0; e < 8; ++e) s += x[i * 8 + e] * b2f((u16)wv8[e]);
  }
  return s;
}
// dot of 128 f32 (LDS) with bf16 LDS row j of a 128-col XOR-swizzled image
DEVI float dotL128(const float* __restrict__ x, const u16* __restrict__ wl, int j) {
  float s = 0.f;
  #pragma unroll
  for (int i = 0; i < 16; ++i) {
    short8 wv8 = *(const short8*)((const char*)wl + ((j * 256 + 16 * i) ^ ((j & 7) << 4)));
    #pragma unroll
    for (int e = 0; e < 8; ++e) s += x[i * 8 + e] * b2f((u16)wv8[e]);
  }
  return s;
}

// LayerNorm of 8 rows x 64 cols living in LDS (256 threads).
DEVI void ln8(const float* src, float* dst, const float* __restrict__ g,
              const float* __restrict__ b, int t) {
  int l = t & 63, w = t >> 6;
  int r = w * 2 + (l >> 5), c = l & 31;
  float x0 = src[r * 64 + c], x1 = src[r * 64 + c + 32];
  float s = x0 + x1, q2 = x0 * x0 + x1 * x1;
  #pragma unroll
  for (int m = 1; m < 32; m <<= 1) { s += __shfl_xor(s, m); q2 += __shfl_xor(q2, m); }
  float mean = s * (1.f / 64.f);
  float rs = rsqrtf(q2 * (1.f / 64.f) - mean * mean + LNEPS);
  dst[r * 64 + c]      = (x0 - mean) * rs * g[c]      + b[c];
  dst[r * 64 + c + 32] = (x1 - mean) * rs * g[c + 32] + b[c + 32];
}

// ---------------------------------------------------------------------------
// K0: weight -> bf16 XOR-swizzled images only (272 blocks).
// ---------------------------------------------------------------------------
__global__ __launch_bounds__(256) void k_prep(
    const float* __restrict__ Wp, const float* __restrict__ Wk,
    const float* __restrict__ Wv, const float* __restrict__ W_ih,
    const float* __restrict__ W_hh, const float* __restrict__ W1,
    const float* __restrict__ W2, const float* __restrict__ Wq,
    u16* __restrict__ wp_sw, u16* __restrict__ wk_sw, u16* __restrict__ wv_sw,
    u16* __restrict__ wupd_sw) {
  const int t = threadIdx.x;
  int i = blockIdx.x * 256 + t;
  if (i < 16384) {
    wp_sw[i ^ (((i >> 8) & 7) << 3)] = f2b(Wp[i]);
  } else if (i < 20480) {
    int j = i - 16384; wk_sw[j ^ (((j >> 6) & 7) << 3)] = f2b(Wk[j]);
  } else if (i < 24576) {
    int j = i - 20480; wv_sw[j ^ (((j >> 6) & 7) << 3)] = f2b(Wv[j]);
  } else if (i < 36864) {
    int j = i - 24576; wupd_sw[j ^ (((j >> 6) & 7) << 3)] = f2b(W_ih[j]);
  } else if (i < 49152) {
    int j = i - 36864; wupd_sw[12288 + (j ^ (((j >> 6) & 7) << 3))] = f2b(W_hh[j]);
  } else if (i < 57344) {
    int j = i - 49152; wupd_sw[24576 + (j ^ (((j >> 6) & 7) << 3))] = f2b(W1[j]);
  } else if (i < 65536) {
    int j = i - 57344; wupd_sw[32768 + (j ^ (((j >> 7) & 7) << 3))] = f2b(W2[j]);
  } else if (i < 69632) {
    int j = i - 65536; wupd_sw[40960 + (j ^ (((j >> 6) & 7) << 3))] = f2b(Wq[j]);
  }
}

// ---------------------------------------------------------------------------
// K1: proj, 256 thr / 64-row blocks (grid 2048, XCD-swizzled) + 32 q-init
// blocks. Rows f32 through LN; packs via v_cvt_pk_bf16_f32.
// k_ws: per-128-row swizzle image; v_ws linear.
// ---------------------------------------------------------------------------
__global__ __launch_bounds__(256) void k_proj_kv(
    const float* __restrict__ in, const float* __restrict__ gpro,
    const float* __restrict__ bpro, const u16* __restrict__ wp_sw,
    const float* __restrict__ bproj, const float* __restrict__ gin,
    const float* __restrict__ bin, const u16* __restrict__ wk_sw,
    const u16* __restrict__ wv_sw, u16* __restrict__ k_ws,
    u16* __restrict__ v_ws, const u16* __restrict__ wupd_sw,
    const float* __restrict__ noise, const float* __restrict__ mu,
    const float* __restrict__ ls, const float* __restrict__ gs,
    const float* __restrict__ bs, float* __restrict__ q_ws) {
  __shared__ __align__(16) u16 wp_lds[64 * 256];    // 32KB
  __shared__ __align__(16) u16 wk_lds[64 * 64];     // 8KB (q-init: wq image)
  __shared__ __align__(16) u16 wv_lds[64 * 64];     // 8KB
  __shared__ __align__(16) u16 xn_lds[64 * 64];     // 8KB (xn, then out tile)
  __shared__ float gp_l[256], bp_l[256], bj_l[64], gn_l[64], bn_l[64];

  const int t = threadIdx.x, l = t & 63, w = t >> 6;

  if (blockIdx.x >= 2048) {   // ---- initial-q blocks ----
    const int b = (int)blockIdx.x - 2048;
    // stage the full 8192B wq image: two 4096B chunks (byte offsets)
    gll16((const char*)wupd_sw + 81920 + t * 16, (char*)wk_lds + t * 16);
    gll16((const char*)wupd_sw + 81920 + 4096 + t * 16,
          (char*)wk_lds + 4096 + t * 16);
    float* snl = (float*)xn_lds;   // 512 floats
    #pragma unroll
    for (int h = 0; h < 2; ++h) {
      int idx = h * 256 + t, d = idx & 63;
      float x = mu[d] + __expf(ls[d]) * noise[b * 512 + idx];
      float s = x, q2 = x * x;
      #pragma unroll
      for (int m = 1; m < 64; m <<= 1) { s += __shfl_xor(s, m); q2 += __shfl_xor(q2, m); }
      float mean = s * (1.f / 64.f);
      float rs = rsqrtf(q2 * (1.f / 64.f) - mean * mean + LNEPS);
      snl[idx] = (x - mean) * rs * gs[d] + bs[d];
    }
    __syncthreads();   // snl ready + wq staged (barrier drains vmcnt)
    #pragma unroll
    for (int h = 0; h < 2; ++h) {
      int idx = h * 256 + t, d = idx & 63, row = idx >> 6;
      q_ws[b * 512 + idx] = SCALEc * dotL64(snl + row * 64, wk_lds, d);
    }
    return;
  }

  // XCD-aware bijective swizzle (nwg=2048, 8 XCDs, 2048%8==0):
  // xcd gets contiguous 256-block span of input rows -> L2 locality.
  const int blk = ((int)blockIdx.x & 7) * 256 + ((int)blockIdx.x >> 3);

  {  // weight staging: wp 8 instr/wave, wk/wv 2 instr/wave
    #pragma unroll
    for (int i = 0; i < 8; ++i) {
      int off = w * 8192 + i * 1024 + l * 16;
      gll16((const char*)wp_sw + off, (char*)wp_lds + off);
    }
    #pragma unroll
    for (int i = 0; i < 2; ++i) {
      int off = w * 2048 + i * 1024 + l * 16;
      gll16((const char*)wk_sw + off, (char*)wk_lds + off);
      gll16((const char*)wv_sw + off, (char*)wv_lds + off);
    }
  }
  gp_l[t] = gpro[t];
  bp_l[t] = bpro[t];
  if (t < 64) { bj_l[t] = bproj[t]; gn_l[t] = gin[t]; bn_l[t] = bin[t]; }

  const int r16 = l & 15, q4 = l >> 4;
  const long rowbase = (long)blk * 64 + w * 16;
  const float* rp = in + (rowbase + r16) * 256;

  // ---- Phase A: load rows as f32, stats, LN, pack via cvt_pk ----
  float4 x0[8], x1[8];
  float sum = 0.f, sq = 0.f;
  #pragma unroll
  for (int ks = 0; ks < 8; ++ks) {
    x0[ks] = *(const float4*)(rp + ks * 32 + q4 * 8);
    x1[ks] = *(const float4*)(rp + ks * 32 + q4 * 8 + 4);
    sum += x0[ks].x + x0[ks].y + x0[ks].z + x0[ks].w +
           x1[ks].x + x1[ks].y + x1[ks].z + x1[ks].w;
    sq += x0[ks].x * x0[ks].x + x0[ks].y * x0[ks].y + x0[ks].z * x0[ks].z +
          x0[ks].w * x0[ks].w + x1[ks].x * x1[ks].x + x1[ks].y * x1[ks].y +
          x1[ks].z * x1[ks].z + x1[ks].w * x1[ks].w;
  }
  __syncthreads();  // staging (vmcnt) + smalls complete

  sum += __shfl_xor(sum, 16); sum += __shfl_xor(sum, 32);
  sq  += __shfl_xor(sq, 16);  sq  += __shfl_xor(sq, 32);
  float mean = sum * (1.f / 256.f);
  float rs = rsqrtf(sq * (1.f / 256.f) - mean * mean + LNEPS);

  short8 a[8];
  #pragma unroll
  for (int ks = 0; ks < 8; ++ks) {
    int kb = ks * 32 + q4 * 8;
    float n0 = (x0[ks].x - mean) * rs * gp_l[kb + 0] + bp_l[kb + 0];
    float n1 = (x0[ks].y - mean) * rs * gp_l[kb + 1] + bp_l[kb + 1];
    float n2 = (x0[ks].z - mean) * rs * gp_l[kb + 2] + bp_l[kb + 2];
    float n3 = (x0[ks].w - mean) * rs * gp_l[kb + 3] + bp_l[kb + 3];
    float n4 = (x1[ks].x - mean) * rs * gp_l[kb + 4] + bp_l[kb + 4];
    float n5 = (x1[ks].y - mean) * rs * gp_l[kb + 5] + bp_l[kb + 5];
    float n6 = (x1[ks].z - mean) * rs * gp_l[kb + 6] + bp_l[kb + 6];
    float n7 = (x1[ks].w - mean) * rs * gp_l[kb + 7] + bp_l[kb + 7];
    u32x4 pv;
    pv.x = cvtpk(n0, n1); pv.y = cvtpk(n2, n3);
    pv.z = cvtpk(n4, n5); pv.w = cvtpk(n6, n7);
    a[ks] = __builtin_bit_cast(short8, pv);
  }

  // ---- Phase B: proj GEMM (16 rows x 64 cols, K=256) ----
  f32x4v acc[4];
  #pragma unroll
  for (int nt = 0; nt < 4; ++nt)
    #pragma unroll
    for (int i = 0; i < 4; ++i) acc[nt][i] = 0.f;
  #pragma unroll
  for (int ks = 0; ks < 8; ++ks) {
    #pragma unroll
    for (int nt = 0; nt < 4; ++nt) {
      int n = nt * 16 + r16;
      int byte = (n * 512 + 64 * ks + 16 * q4) ^ ((n & 7) << 4);
      short8 bf = *(const short8*)((const char*)wp_lds + byte);
      acc[nt] = __builtin_amdgcn_mfma_f32_16x16x32_bf16(a[ks], bf, acc[nt], 0, 0, 0);
    }
  }
  #pragma unroll
  for (int nt = 0; nt < 4; ++nt) {
    float bb = bj_l[nt * 16 + r16];
    #pragma unroll
    for (int reg = 0; reg < 4; ++reg) acc[nt][reg] += bb;
  }
  // ---- Phase C: LN(64) per output row -> swizzled xn ----
  #pragma unroll
  for (int reg = 0; reg < 4; ++reg) {
    float s = acc[0][reg] + acc[1][reg] + acc[2][reg] + acc[3][reg];
    float q2 = acc[0][reg] * acc[0][reg] + acc[1][reg] * acc[1][reg] +
               acc[2][reg] * acc[2][reg] + acc[3][reg] * acc[3][reg];
    #pragma unroll
    for (int m = 1; m < 16; m <<= 1) { s += __shfl_xor(s, m); q2 += __shfl_xor(q2, m); }
    float mn = s * (1.f / 64.f);
    float rr = rsqrtf(q2 * (1.f / 64.f) - mn * mn + LNEPS);
    int row = q4 * 4 + reg;
    int rowg = w * 16 + row;
    #pragma unroll
    for (int nt = 0; nt < 4; ++nt) {
      int col = nt * 16 + r16;
      float y = (acc[nt][reg] - mn) * rr * gn_l[col] + bn_l[col];
      int byte = (rowg * 128 + 2 * col) ^ ((row & 7) << 4);
      *(u16*)((char*)xn_lds + byte) = f2b(y);
    }
  }
  __syncthreads();

  // ---- Phase D: k,v GEMMs (K=64) ----
  f32x4v kacc[4], vacc[4];
  #pragma unroll
  for (int nt = 0; nt < 4; ++nt)
    #pragma unroll
    for (int i = 0; i < 4; ++i) { kacc[nt][i] = 0.f; vacc[nt][i] = 0.f; }
  #pragma unroll
  for (int ks = 0; ks < 2; ++ks) {
    int rowg2 = w * 16 + r16;
    int abyte = (rowg2 * 128 + 64 * ks + 16 * q4) ^ ((r16 & 7) << 4);
    short8 af = *(const short8*)((const char*)xn_lds + abyte);
    #pragma unroll
    for (int nt = 0; nt < 4; ++nt) {
      int n = nt * 16 + r16;
      int bbyte = (n * 128 + 64 * ks + 16 * q4) ^ ((n & 7) << 4);
      short8 bk = *(const short8*)((const char*)wk_lds + bbyte);
      short8 bv = *(const short8*)((const char*)wv_lds + bbyte);
      kacc[nt] = __builtin_amdgcn_mfma_f32_16x16x32_bf16(af, bk, kacc[nt], 0, 0, 0);
      vacc[nt] = __builtin_amdgcn_mfma_f32_16x16x32_bf16(af, bv, vacc[nt], 0, 0, 0);
    }
  }
  // ---- vectorized epilogue via LDS: k image slice then v linear slice ----
  __syncthreads();
  #pragma unroll
  for (int nt = 0; nt < 4; ++nt) {
    #pragma unroll
    for (int reg = 0; reg < 4; ++reg) {
      int row = w * 16 + q4 * 4 + reg;     // 0..63
      int col = nt * 16 + r16;
      int idx = (row * 64 + col) ^ ((row & 7) << 3);
      xn_lds[idx] = f2b(kacc[nt][reg]);
    }
  }
  __syncthreads();
  {  // copy 8KB image slice -> k_ws
    const uint4* src = (const uint4*)xn_lds;
    uint4* dst = (uint4*)(k_ws + (long)blk * 4096);
    dst[t] = src[t];
    dst[t + 256] = src[t + 256];
  }
  __syncthreads();
  #pragma unroll
  for (int nt = 0; nt < 4; ++nt) {
    #pragma unroll
    for (int reg = 0; reg < 4; ++reg) {
      int row = w * 16 + q4 * 4 + reg;
      int col = nt * 16 + r16;
      xn_lds[row * 64 + col] = f2b(vacc[nt][reg]);     // linear
    }
  }
  __syncthreads();
  {  // copy 8KB -> v_ws (linear)
    const uint4* src = (const uint4*)xn_lds;
    uint4* dst = (uint4*)(v_ws + (long)blk * 4096);
    dst[t] = src[t];
    dst[t + 256] = src[t + 256];
  }
}

// ---------------------------------------------------------------------------
// K2: pure attention stream. grid (32,32), 128 thr. k AND v staged via gll16
// (38KB LDS -> 4 blocks/CU); PV reads v from LDS. (unchanged from R15)
// ---------------------------------------------------------------------------
__global__ __launch_bounds__(128) void k_attn(
    const float* __restrict__ q_ws, const u16* __restrict__ k_img,
    const u16* __restrict__ v_ws, float* __restrict__ S_part,
    float* __restrict__ U_part) {
  const int bx = blockIdx.x, by = blockIdx.y, t = threadIdx.x;
  const int l = t & 63, w = t >> 6;
  __shared__ __align__(16) u16 k_l[8192];        // 16KB swizzle tile
  __shared__ __align__(16) u16 v_l[8192];        // 16KB linear tile
  __shared__ float ql[512];
  __shared__ __align__(16) float attn_l[1024];
  __shared__ float sred[16];

  {
    const char* ksrc = (const char*)(k_img + ((long)(by * 32 + bx)) * 8192);
    const char* vsrc = (const char*)(v_ws + ((long)(by * 32 + bx)) * 8192);
    #pragma unroll
    for (int i = 0; i < 8; ++i) {
      int off = i * 2048 + t * 16;
      gll16(ksrc + off, (char*)k_l + off);
      gll16(vsrc + off, (char*)v_l + off);
    }
  }
  for (int i = t; i < 512; i += 128) ql[i] = q_ws[by * 512 + i];
  __syncthreads();

  short8 kw8[8];
  #pragma unroll
  for (int j = 0; j < 8; ++j)
    kw8[j] = *(const short8*)((const char*)k_l + ((t * 128 + 16 * j) ^ ((t & 7) << 4)));
  float lg[8];
  #pragma unroll
  for (int i = 0; i < 8; ++i) lg[i] = 0.f;
  #pragma unroll
  for (int c4 = 0; c4 < 16; ++c4) {
    int j = c4 >> 1, e0 = (c4 & 1) * 4;
    float f0 = b2f((u16)kw8[j][e0]);
    float f1 = b2f((u16)kw8[j][e0 + 1]);
    float f2v = b2f((u16)kw8[j][e0 + 2]);
    float f3 = b2f((u16)kw8[j][e0 + 3]);
    #pragma unroll
    for (int kk = 0; kk < 8; ++kk) {
      float4 qv = *(const float4*)(ql + kk * 64 + c4 * 4);
      lg[kk] += qv.x * f0 + qv.y * f1 + qv.z * f2v + qv.w * f3;
    }
  }
  float mx = lg[0];
  #pragma unroll
  for (int kk = 1; kk < 8; ++kk) mx = fmaxf(mx, lg[kk]);
  float e[8], ss = 0.f;
  #pragma unroll
  for (int kk = 0; kk < 8; ++kk) { e[kk] = __expf(lg[kk] - mx); ss += e[kk]; }
  float inv = 1.f / ss;
  #pragma unroll
  for (int kk = 0; kk < 8; ++kk) e[kk] *= inv;
  float4 A0 = {e[0], e[1], e[2], e[3]}, A1 = {e[4], e[5], e[6], e[7]};
  *(float4*)(attn_l + t * 8) = A0;
  *(float4*)(attn_l + t * 8 + 4) = A1;
  __syncthreads();

  float au[8][2];
  #pragma unroll
  for (int i = 0; i < 8; ++i) { au[i][0] = 0.f; au[i][1] = 0.f; }
  const int p = l & 31, g = l >> 5;
  const u32* vl32 = (const u32*)v_l;
  #pragma unroll 8
  for (int nn = 0; nn < 32; ++nn) {
    int n = nn * 2 + g;
    float4 a0 = *(const float4*)(attn_l + (w * 64 + n) * 8);
    float4 a1 = *(const float4*)(attn_l + (w * 64 + n) * 8 + 4);
    u32 vv = vl32[(w * 64 + n) * 32 + p];
    float vlo = b2f((u16)(vv & 0xffff)), vhi = b2f((u16)(vv >> 16));
    au[0][0] += a0.x * vlo; au[0][1] += a0.x * vhi;
    au[1][0] += a0.y * vlo; au[1][1] += a0.y * vhi;
    au[2][0] += a0.z * vlo; au[2][1] += a0.z * vhi;
    au[3][0] += a0.w * vlo; au[3][1] += a0.w * vhi;
    au[4][0] += a1.x * vlo; au[4][1] += a1.x * vhi;
    au[5][0] += a1.y * vlo; au[5][1] += a1.y * vhi;
    au[6][0] += a1.z * vlo; au[6][1] += a1.z * vhi;
    au[7][0] += a1.w * vlo; au[7][1] += a1.w * vhi;
  }
  #pragma unroll
  for (int kk = 0; kk < 8; ++kk) {
    au[kk][0] += __shfl_xor(au[kk][0], 32);
    au[kk][1] += __shfl_xor(au[kk][1], 32);
  }
  float s8[8];
  #pragma unroll
  for (int kk = 0; kk < 8; ++kk) {
    s8[kk] = e[kk];
    #pragma unroll
    for (int m = 1; m < 64; m <<= 1) s8[kk] += __shfl_xor(s8[kk], m);
  }
  __syncthreads();
  float* ured = attn_l;
  if (l < 32) {
    #pragma unroll
    for (int kk = 0; kk < 8; ++kk) {
      ured[w * 512 + kk * 64 + 2 * p]     = au[kk][0];
      ured[w * 512 + kk * 64 + 2 * p + 1] = au[kk][1];
    }
  }
  if (l == 0) {
    #pragma unroll
    for (int kk = 0; kk < 8; ++kk) sred[w * 8 + kk] = s8[kk];
  }
  __syncthreads();
  for (int i = t; i < 512; i += 128)
    U_part[((long)(by * 32 + bx)) * 512 + i] = ured[i] + ured[512 + i];
  if (t < 8)
    S_part[(by * 32 + bx) * 8 + t] = sred[t] + sred[8 + t];
}

// ---------------------------------------------------------------------------
// K3: reduce partials, GRU, MLP -> slots; LN+q -> q_ws. (unchanged from R15)
// ---------------------------------------------------------------------------
__global__ __launch_bounds__(256) void k_update(
    const float* __restrict__ S_part, const float* __restrict__ U_part,
    const float* __restrict__ slots_in, int init_slots,
    const float* __restrict__ noise, const float* __restrict__ mu,
    const float* __restrict__ ls, const u16* __restrict__ wupd_sw,
    const float* __restrict__ b_ih, const float* __restrict__ b_hh,
    const float* __restrict__ gm, const float* __restrict__ bm,
    const float* __restrict__ b1, const float* __restrict__ b2,
    const float* __restrict__ gs, const float* __restrict__ bs,
    float* __restrict__ slots_out, float* __restrict__ q_ws,
    float* __restrict__ out_slots, int write_out) {
  const int b = blockIdx.x, t = threadIdx.x;
  __shared__ __align__(16) u16 wupd[45056];
  __shared__ float u_l[512], sp[512], gi[1536], gh[1536], sn2[512], mi[512],
      h1[1024], Ssum[8];
  const u16* wih_l = wupd;
  const u16* whh_l = wupd + 12288;
  const u16* w1_l  = wupd + 24576;
  const u16* w2_l  = wupd + 32768;
  const u16* wq_l  = wupd + 40960;

  {
    #pragma unroll
    for (int c = 0; c < 22; ++c) {
      int off = c * 4096 + t * 16;
      gll16((const char*)wupd_sw + off, (char*)wupd + off);
    }
  }
  if (t < 8) {
    float s = 0.f;
    #pragma unroll
    for (int ch = 0; ch < 32; ++ch) s += S_part[(b * 32 + ch) * 8 + t];
    Ssum[t] = s;
  }
  for (int i = t; i < 512; i += 256) {
    float v;
    if (init_slots) { int d = i & 63; v = mu[d] + __expf(ls[d]) * noise[b * 512 + i]; }
    else v = slots_in[b * 512 + i];
    sp[i] = v;
  }
  __syncthreads();
  for (int i = t; i < 512; i += 256) {
    float s = 0.f;
    #pragma unroll
    for (int ch = 0; ch < 32; ++ch) s += U_part[((long)(b * 32 + ch)) * 512 + i];
    u_l[i] = s / (Ssum[i >> 6] + EPSc);
  }
  __syncthreads();
  for (int i = t; i < 1536; i += 256) {
    int kk = i / 192, j = i - kk * 192;
    gi[i] = b_ih[j] + dotL64(u_l + kk * 64, wih_l, j);
    gh[i] = b_hh[j] + dotL64(sp + kk * 64, whh_l, j);
  }
  __syncthreads();
  for (int i = t; i < 512; i += 256) {
    int kk = i >> 6, d = i & 63, base = kk * 192;
    float r = sigmoidf_(gi[base + d] + gh[base + d]);
    float z = sigmoidf_(gi[base + 64 + d] + gh[base + 64 + d]);
    float nn = tanhf(gi[base + 128 + d] + r * gh[base + 128 + d]);
    sn2[i] = (1.f - z) * nn + z * sp[i];
  }
  __syncthreads();
  ln8(sn2, mi, gm, bm, t);
  __syncthreads();
  for (int i = t; i < 1024; i += 256) {
    int kk = i >> 7, j = i & 127;
    h1[i] = fmaxf(b1[j] + dotL64(mi + kk * 64, w1_l, j), 0.f);
  }
  __syncthreads();
  for (int i = t; i < 512; i += 256) {
    int kk = i >> 6, d = i & 63;
    float s = sn2[i] + b2[d] + dotL128(h1 + kk * 128, w2_l, d);
    slots_out[b * 512 + i] = s;
    if (write_out) out_slots[b * 512 + i] = s;
    u_l[i] = s;
  }
  __syncthreads();
  ln8(u_l, mi, gs, bs, t);
  __syncthreads();
  for (int i = t; i < 512; i += 256)
    q_ws[b * 512 + i] = SCALEc * dotL64(mi + (i >> 6) * 64, wq_l, i & 63);
}

// ---------------------------------------------------------------------------
// K4: final attention map. grid (32,32), 128 thr. (unchanged from R15)
// ---------------------------------------------------------------------------
__global__ __launch_bounds__(128) void k_final(
    const float* __restrict__ q_ws, const u16* __restrict__ k_img,
    float* __restrict__ outA) {
  const int bx = blockIdx.x, by = blockIdx.y, t = threadIdx.x;
  __shared__ __align__(16) u16 k_l[8192];
  __shared__ float ql[512];
  {
    const char* gsrc = (const char*)(k_img + ((long)(by * 32 + bx)) * 8192);
    #pragma unroll
    for (int i = 0; i < 8; ++i) {
      int off = i * 2048 + t * 16;
      gll16(gsrc + off, (char*)k_l + off);
    }
  }
  for (int i = t; i < 512; i += 128) ql[i] = q_ws[by * 512 + i];
  __syncthreads();
  short8 kw8[8];
  #pragma unroll
  for (int j = 0; j < 8; ++j)
    kw8[j] = *(const short8*)((const char*)k_l + ((t * 128 + 16 * j) ^ ((t & 7) << 4)));
  float lg[8];
  #pragma unroll
  for (int i = 0; i < 8; ++i) lg[i] = 0.f;
  #pragma unroll
  for (int c4 = 0; c4 < 16; ++c4) {
    int j = c4 >> 1, e0 = (c4 & 1) * 4;
    float f0 = b2f((u16)kw8[j][e0]);
    float f1 = b2f((u16)kw8[j][e0 + 1]);
    float f2v = b2f((u16)kw8[j][e0 + 2]);
    float f3 = b2f((u16)kw8[j][e0 + 3]);
    #pragma unroll
    for (int kk = 0; kk < 8; ++kk) {
      float4 qv = *(const float4*)(ql + kk * 64 + c4 * 4);
      lg[kk] += qv.x * f0 + qv.y * f1 + qv.z * f2v + qv.w * f3;
    }
  }
  float mx = lg[0];
  #pragma unroll
  for (int kk = 1; kk < 8; ++kk) mx = fmaxf(mx, lg[kk]);
  float e[8], ss = 0.f;
  #pragma unroll
  for (int kk = 0; kk < 8; ++kk) { e[kk] = __expf(lg[kk] - mx); ss += e[kk]; }
  float inv = 1.f / ss;
  int n = bx * 128 + t;
  #pragma unroll
  for (int kk = 0; kk < 8; ++kk)
    outA[((long)by * 8 + kk) * 4096 + n] = e[kk] * inv;
}

extern "C" void kernel_launch(void* const* d_in, const int* in_sizes, int n_in,
                              void* d_out, int out_size, void* d_ws, size_t ws_size,
                              hipStream_t stream) {
  (void)in_sizes; (void)n_in; (void)out_size; (void)ws_size;
  const float* in    = (const float*)d_in[0];
  const float* noise = (const float*)d_in[1];
  const float* mu    = (const float*)d_in[2];
  const float* ls    = (const float*)d_in[3];
  const float* gpro  = (const float*)d_in[4];
  const float* bpro  = (const float*)d_in[5];
  const float* Wp    = (const float*)d_in[6];
  const float* bproj = (const float*)d_in[7];
  const float* Wq    = (const float*)d_in[8];
  const float* Wk    = (const float*)d_in[9];
  const float* Wv    = (const float*)d_in[10];
  const float* W_ih  = (const float*)d_in[11];
  const float* W_hh  = (const float*)d_in[12];
  const float* b_ih  = (const float*)d_in[13];
  const float* b_hh  = (const float*)d_in[14];
  const float* W1    = (const float*)d_in[15];
  const float* b1    = (const float*)d_in[16];
  const float* W2    = (const float*)d_in[17];
  const float* b2    = (const float*)d_in[18];
  const float* gin   = (const float*)d_in[19];
  const float* bin   = (const float*)d_in[20];
  const float* gs    = (const float*)d_in[21];
  const float* bs    = (const float*)d_in[22];
  const float* gm    = (const float*)d_in[23];
  const float* bm    = (const float*)d_in[24];

  char* ws = (char*)d_ws;
  u16* k_ws      = (u16*)ws;                                   // 16 MiB swizzle image
  u16* v_ws      = (u16*)(ws + 16777216);                      // 16 MiB linear
  float* S_part  = (float*)(ws + 33554432);                    // 32 KiB
  float* U_part  = (float*)(ws + 33554432 + 32768);            // 2 MiB
  float* slots_a = (float*)(ws + 33554432 + 32768 + 2097152);  // 64 KiB
  float* slots_b = (float*)(ws + 33554432 + 32768 + 2097152 + 65536);
  float* q_ws    = (float*)(ws + 33554432 + 32768 + 2097152 + 131072);
  u16* wp_sw     = (u16*)(ws + 33554432 + 32768 + 2097152 + 131072 + 65536);
  u16* wk_sw     = wp_sw + 16384;
  u16* wv_sw     = wk_sw + 4096;
  u16* wupd_sw   = wv_sw + 4096;                               // 45056 u16
  float* out = (float*)d_out;

  k_prep<<<dim3(272), dim3(256), 0, stream>>>(Wp, Wk, Wv, W_ih, W_hh, W1, W2, Wq,
                                              wp_sw, wk_sw, wv_sw, wupd_sw);
  k_proj_kv<<<dim3(2080), dim3(256), 0, stream>>>(in, gpro, bpro, wp_sw, bproj,
                                                  gin, bin, wk_sw, wv_sw, k_ws, v_ws,
                                                  wupd_sw, noise, mu, ls, gs, bs,
                                                  q_ws);
  dim3 ga(32, 32), ba(128);
  // iter 0
  k_attn<<<ga, ba, 0, stream>>>(q_ws, k_ws, v_ws, S_part, U_part);
  k_update<<<dim3(32), dim3(256), 0, stream>>>(S_part, U_part, slots_a, 1, noise,
                                               mu, ls, wupd_sw, b_ih, b_hh, gm, bm,
                                               b1, b2, gs, bs, slots_a, q_ws, out, 0);
  // iter 1
  k_attn<<<ga, ba, 0, stream>>>(q_ws, k_ws, v_ws, S_part, U_part);
  k_update<<<dim3(32), dim3(256), 0, stream>>>(S_part, U_part, slots_a, 0, noise,
                                               mu, ls, wupd_sw, b_ih, b_hh, gm, bm,
                                               b1, b2, gs, bs, slots_b, q_ws, out, 0);
  // iter 2 (slots -> d_out)
  k_attn<<<ga, ba, 0, stream>>>(q_ws, k_ws, v_ws, S_part, U_part);
  k_update<<<dim3(32), dim3(256), 0, stream>>>(S_part, U_part, slots_b, 0, noise,
                                               mu, ls, wupd_sw, b_ih, b_hh, gm, bm,
                                               b1, b2, gs, bs, slots_a, q_ws, out, 1);
  // final attention map
  k_final<<<ga, ba, 0, stream>>>(q_ws, k_ws, out + 16384);
}